// Round 3
// baseline (8009.806 us; speedup 1.0000x reference)
//
#include <hip/hip_runtime.h>

// ---------------------------------------------------------------------------
// VQ-VAE forward, round 3: emulate per-op fp32-correctly-rounded reference.
// Every reference op = fl32(float64-exact op on fp32 operands).
// d computed in fp32 (ties common at ulp(|z|^2)!) with first-index argmin.
//
// d_out (float32): recon[786432] | commit_loss[1] | indices[16384]
//
// Workspace (BYTE offsets), ~73.1 MB total:
#define OFF_H1   ((size_t)0)           // f32 4x128x128x128 (33.55M)  -> d2 reuse
#define OFF_H2   ((size_t)33554432)    // f32 4x128x64x64   (8.39M)   -> qbuf reuse
#define OFF_H3   ((size_t)41943040)    // f32 4x128x64x64   (8.39M)   -> d1 reuse
#define OFF_ZF   ((size_t)50331648)    // f32 [16384][256]  (16.78M)
#define OFF_ZN   ((size_t)67108864)    // f32 [16384]
#define OFF_CN   ((size_t)67174400)    // f32 [8192]
#define OFF_CAND ((size_t)67207168)    // i32 [16384][24]
#define OFF_CNT  ((size_t)68780032)    // i32 [16384]
#define OFF_IDX  ((size_t)68845568)    // i32 [16384]
#define OFF_ACC  ((size_t)68911104)    // f32 [1]
#define OFF_PC   ((size_t)68911168)    // f32 [8192][128]
// ---------------------------------------------------------------------------

// ---------- conv k=4 s=2 p=1, f64 accumulate, fp32-rounded out, ReLU ----------
template<int CIN, int LOGWO>
__global__ __launch_bounds__(256) void conv4s2_relu_pr_k(
    const float* __restrict__ x, const float* __restrict__ w,
    const float* __restrict__ bias, float* __restrict__ y) {
  constexpr int WO = 1 << LOGWO;
  constexpr int WI = WO * 2;
  int tid = blockIdx.x * 256 + threadIdx.x;
  int wo = tid & (WO - 1);
  int ho = (tid >> LOGWO) & (WO - 1);
  int co = (tid >> (2 * LOGWO)) & 127;
  int n  = tid >> (2 * LOGWO + 7);
  double acc = (double)bias[co];
  const float* xb = x + (size_t)n * CIN * WI * WI;
  const float* wb = w + (size_t)co * CIN * 16;
  for (int ci = 0; ci < CIN; ++ci) {
    const float* xp = xb + (size_t)ci * WI * WI;
    const float* wp = wb + ci * 16;
#pragma unroll
    for (int kh = 0; kh < 4; ++kh) {
      int hi = 2 * ho - 1 + kh;
      if ((unsigned)hi < (unsigned)WI) {
        const float* row = xp + (size_t)hi * WI;
#pragma unroll
        for (int kw = 0; kw < 4; ++kw) {
          int wi = 2 * wo - 1 + kw;
          if ((unsigned)wi < (unsigned)WI)
            acc = fma((double)row[wi], (double)wp[kh * 4 + kw], acc);
        }
      }
    }
  }
  float r = (float)acc;          // per-op fp32 rounding
  y[tid] = fmaxf(r, 0.0f);
}

// ---------- conv k=3 s=1 p=1, f64 acc, fp32-rounded (no relu: enc conv3) ----------
__global__ __launch_bounds__(256) void conv3s1_pr_k(
    const float* __restrict__ x, const float* __restrict__ w,
    const float* __restrict__ bias, float* __restrict__ y) {
  int tid = blockIdx.x * 256 + threadIdx.x;
  int wo = tid & 63;
  int ho = (tid >> 6) & 63;
  int co = (tid >> 12) & 127;
  int n  = tid >> 19;
  double acc = (double)bias[co];
  const float* xb = x + (size_t)n * 128 * 4096;
  const float* wb = w + (size_t)co * 1152;
  for (int ci = 0; ci < 128; ++ci) {
    const float* xp = xb + (size_t)ci * 4096;
    const float* wp = wb + ci * 9;
#pragma unroll
    for (int kh = 0; kh < 3; ++kh) {
      int hi = ho - 1 + kh;
      if ((unsigned)hi < 64u) {
        const float* row = xp + hi * 64;
#pragma unroll
        for (int kw2 = 0; kw2 < 3; ++kw2) {
          int wi = wo - 1 + kw2;
          if ((unsigned)wi < 64u)
            acc = fma((double)row[wi], (double)wp[kh * 3 + kw2], acc);
        }
      }
    }
  }
  y[tid] = (float)acc;
}

// ---------- 1x1 conv 128->256, f64 acc, writes fp32 z transposed [p][256] ----------
__global__ __launch_bounds__(256) void qconv_z_pr_k(
    const float* __restrict__ h3, const float* __restrict__ w,
    const float* __restrict__ bias, float* __restrict__ zf) {
  int tid = blockIdx.x * 256 + threadIdx.x;  // p*256 + co
  int co = tid & 255;
  int p  = tid >> 8;
  int n  = p >> 12;
  int hw = p & 4095;
  const float* xp = h3 + ((size_t)n * 128) * 4096 + hw;
  const float* wp = w + (size_t)co * 128;
  double acc = (double)bias[co];
#pragma unroll 8
  for (int ci = 0; ci < 128; ++ci)
    acc = fma((double)xp[(size_t)ci * 4096], (double)wp[ci], acc);
  zf[tid] = (float)acc;
}

// ---------- row norms: fl32( f64-sum of fl32(v^2) ) ----------
__global__ __launch_bounds__(256) void rownorm_k(const float* __restrict__ src,
                                                 float* __restrict__ dst) {
  int lane = threadIdx.x & 63;
  int r = blockIdx.x * 4 + (threadIdx.x >> 6);
  const float* v = src + (size_t)r * 256;
  double s = 0.0;
#pragma unroll
  for (int j = 0; j < 4; ++j) {
    float x = v[lane + (j << 6)];
    float xx = x * x;            // elementwise multiply op: fp32-rounded
    s += (double)xx;             // sum op: f64-exact, rounded once below
  }
#pragma unroll
  for (int off = 32; off > 0; off >>= 1) s += __shfl_down(s, off, 64);
  if (lane == 0) dst[r] = (float)s;
}

// ---------- order-preserving float<->uint for shared atomicMin ----------
__device__ __forceinline__ unsigned fkey(float f) {
  unsigned u = __float_as_uint(f);
  return (u & 0x80000000u) ? ~u : (u | 0x80000000u);
}
__device__ __forceinline__ float funkey(unsigned k) {
  unsigned u = (k & 0x80000000u) ? (k ^ 0x80000000u) : ~k;
  return __uint_as_float(u);
}

// ---------- VQ filter: single-pass fp32 GEMM, running-min candidate collect ----------
// s(k) = cn_k - 2 z.c_k  (row-constant |z|^2 cancels for filtering).
// margin >= 4*ulp(zn) + fp32 dot error ensures the fp32-d argmin and all its
// fp32 ties are collected. Over-collection is harmless; overflow -> rescan.
__global__ __launch_bounds__(256, 2) void vq_filter_k(
    const float* __restrict__ zf, const float* __restrict__ cb,
    const float* __restrict__ cnArr, const float* __restrict__ znArr,
    int* __restrict__ candOut, int* __restrict__ cntOut) {
  __shared__ __align__(16) float a_sh[32 * 260];
  __shared__ __align__(16) float b_sh[128 * 68];
  __shared__ unsigned minkey_sh[32];
  __shared__ int cand_sh[32 * 24];
  __shared__ int cnt_sh[32];
  __shared__ float marg_sh[32];
  const int t = threadIdx.x;
  const int r0 = blockIdx.x * 32;
  for (int q = t; q < 2048; q += 256) {
    int row = q >> 6, col = (q & 63) << 2;
    *(float4*)(a_sh + row * 260 + col) =
        *(const float4*)(zf + (size_t)(r0 + row) * 256 + col);
  }
  if (t < 32) {
    minkey_sh[t] = 0xFFFFFFFFu;
    cnt_sh[t] = 0;
    marg_sh[t] = 1e-5f + znArr[r0 + t] * 6e-7f;
  }
  const int ty = t >> 5, tx = t & 31;
  for (int kt = 0; kt < 64; ++kt) {
    const int k0 = kt << 7;
    float dots[4][4];
#pragma unroll
    for (int i = 0; i < 4; ++i)
#pragma unroll
      for (int j = 0; j < 4; ++j) dots[i][j] = 0.0f;
    for (int ec = 0; ec < 4; ++ec) {
      __syncthreads();
      for (int q = t; q < 2048; q += 256) {
        int row = q >> 4, col = (q & 15) << 2;
        *(float4*)(b_sh + row * 68 + col) =
            *(const float4*)(cb + (size_t)(k0 + row) * 256 + (ec << 6) + col);
      }
      __syncthreads();
#pragma unroll 4
      for (int e4 = 0; e4 < 16; ++e4) {
        float4 av[4], bv[4];
#pragma unroll
        for (int i = 0; i < 4; ++i)
          av[i] = *(const float4*)(a_sh + (ty * 4 + i) * 260 + (ec << 6) + (e4 << 2));
#pragma unroll
        for (int j = 0; j < 4; ++j)
          bv[j] = *(const float4*)(b_sh + (tx + 32 * j) * 68 + (e4 << 2));
#pragma unroll
        for (int i = 0; i < 4; ++i)
#pragma unroll
          for (int j = 0; j < 4; ++j) {
            dots[i][j] = fmaf(av[i].x, bv[j].x, dots[i][j]);
            dots[i][j] = fmaf(av[i].y, bv[j].y, dots[i][j]);
            dots[i][j] = fmaf(av[i].z, bv[j].z, dots[i][j]);
            dots[i][j] = fmaf(av[i].w, bv[j].w, dots[i][j]);
          }
      }
    }
    float sv[4][4];
    float rowmin[4] = {3.4e38f, 3.4e38f, 3.4e38f, 3.4e38f};
#pragma unroll
    for (int j = 0; j < 4; ++j) {
      const float cnk = cnArr[k0 + tx + 32 * j];
#pragma unroll
      for (int i = 0; i < 4; ++i) {
        float s = fmaf(-2.0f, dots[i][j], cnk);
        sv[i][j] = s;
        rowmin[i] = fminf(rowmin[i], s);
      }
    }
#pragma unroll
    for (int i = 0; i < 4; ++i)
      atomicMin(&minkey_sh[ty * 4 + i], fkey(rowmin[i]));
    __syncthreads();
#pragma unroll
    for (int i = 0; i < 4; ++i) {
      const int rr = ty * 4 + i;
      const float thr = funkey(minkey_sh[rr]) + marg_sh[rr];
#pragma unroll
      for (int j = 0; j < 4; ++j) {
        if (sv[i][j] <= thr) {
          int slot = atomicAdd(&cnt_sh[rr], 1);
          if (slot < 24) cand_sh[rr * 24 + slot] = k0 + tx + 32 * j;
        }
      }
    }
  }
  __syncthreads();
  if (t < 32) {
    int c = cnt_sh[t];
    cntOut[r0 + t] = c;
    int cc = c < 24 ? c : 24;
    for (int s = 0; s < cc; ++s) candOut[(r0 + t) * 24 + s] = cand_sh[t * 24 + s];
  }
}

// ---------- VQ final: fp32-faithful d, lexicographic (d,k) argmin ----------
__global__ __launch_bounds__(256) void vq_phase3_k(
    const float* __restrict__ zf, const float* __restrict__ cb,
    const float* __restrict__ znArr, const float* __restrict__ cnArr,
    const int* __restrict__ cand, const int* __restrict__ cnt,
    int* __restrict__ idxOut) {
  const int lane = threadIdx.x & 63;
  const int r = blockIdx.x * 4 + (threadIdx.x >> 6);
  const float* zr = zf + (size_t)r * 256;
  double z4[4];
#pragma unroll
  for (int j = 0; j < 4; ++j) z4[j] = (double)zr[lane + (j << 6)];
  const float znr = znArr[r];
  const int c = cnt[r];
  const bool ovf = (c > 24);
  const int nscan = ovf ? 8192 : c;
  float bestd = 3.4e38f;
  int bestk = 0x7fffffff;
  for (int s = 0; s < nscan; ++s) {
    const int k = ovf ? s : cand[r * 24 + s];
    const float* ck = cb + (size_t)k * 256;
    double p = 0.0;
#pragma unroll
    for (int j = 0; j < 4; ++j)
      p = fma(z4[j], (double)ck[lane + (j << 6)], p);
#pragma unroll
    for (int off = 32; off > 0; off >>= 1) p += __shfl_down(p, off, 64);
    if (lane == 0) {
      float mm2 = (float)(2.0 * p);     // matmul op (x2 folded): fp32-rounded
      float t1 = znr + cnArr[k];        // fp32 add op
      float d = t1 - mm2;               // fp32 sub op
      if (d < bestd || (d == bestd && k < bestk)) { bestd = d; bestk = k; }
    }
  }
  if (lane == 0) idxOut[r] = bestk;
}

// ---------- commit loss partials + indices-as-float output ----------
__global__ __launch_bounds__(256) void commit_k(
    const float* __restrict__ zf, const float* __restrict__ cb,
    const int* __restrict__ idxArr, float* __restrict__ accum,
    float* __restrict__ outIdxF) {
  __shared__ float wsum[4];
  const int p = blockIdx.x;
  const int t = threadIdx.x;
  const int k = idxArr[p];
  float d = cb[(size_t)k * 256 + t] - zf[(size_t)p * 256 + t];
  float v = d * d;
#pragma unroll
  for (int off = 32; off > 0; off >>= 1) v += __shfl_down(v, off, 64);
  if ((t & 63) == 0) wsum[t >> 6] = v;
  __syncthreads();
  if (t == 0) {
    atomicAdd(accum, wsum[0] + wsum[1] + wsum[2] + wsum[3]);
    outIdxF[p] = (float)k;
  }
}

__global__ void init_k(float* accum) { *accum = 0.0f; }
__global__ void fin_k(const float* __restrict__ accum, float* __restrict__ out) {
  *out = *accum * (1.0f / 4194304.0f);
}

// ---------- projected codebook PC[k][co] = sum_ci cb[k][ci]*pw[co][ci] ----------
__global__ __launch_bounds__(256) void pc_k(const float* __restrict__ cb,
                                            const float* __restrict__ pw,
                                            float* __restrict__ PC) {
  int tid = blockIdx.x * 256 + threadIdx.x;  // k*128 + co
  int co = tid & 127, k = tid >> 7;
  const float* c = cb + (size_t)k * 256;
  const float* w = pw + (size_t)co * 256;
  float acc = 0.0f;
#pragma unroll 8
  for (int ci = 0; ci < 256; ++ci) acc = fmaf(c[ci], w[ci], acc);
  PC[tid] = acc;
}

// ---------- q = gather(PC, idx) + bias, NCHW fp32 ----------
__global__ __launch_bounds__(256) void gather_pc_k(
    const float* __restrict__ PC, const int* __restrict__ idxArr,
    const float* __restrict__ pb, float* __restrict__ q) {
  int tid = blockIdx.x * 256 + threadIdx.x;
  int hw = tid & 4095;
  int co = (tid >> 12) & 127;
  int n  = tid >> 19;
  int p  = (n << 12) + hw;
  q[tid] = PC[(size_t)idxArr[p] * 128 + co] + pb[co];
}

// ---------- fp32 conv k=3 s=1 p=1 + relu (dec conv1) ----------
__global__ __launch_bounds__(256) void conv3s1_relu_f32_k(
    const float* __restrict__ x, const float* __restrict__ w,
    const float* __restrict__ bias, float* __restrict__ y) {
  int tid = blockIdx.x * 256 + threadIdx.x;
  int wo = tid & 63;
  int ho = (tid >> 6) & 63;
  int co = (tid >> 12) & 127;
  int n  = tid >> 19;
  float acc = bias[co];
  const float* xb = x + (size_t)n * 128 * 4096;
  const float* wb = w + (size_t)co * 1152;
  for (int ci = 0; ci < 128; ++ci) {
    const float* xp = xb + (size_t)ci * 4096;
    const float* wp = wb + ci * 9;
#pragma unroll
    for (int kh = 0; kh < 3; ++kh) {
      int hi = ho - 1 + kh;
      if ((unsigned)hi < 64u) {
        const float* row = xp + hi * 64;
#pragma unroll
        for (int kw2 = 0; kw2 < 3; ++kw2) {
          int wi = wo - 1 + kw2;
          if ((unsigned)wi < 64u)
            acc = fmaf(row[wi], wp[kh * 3 + kw2], acc);
        }
      }
    }
  }
  y[tid] = fmaxf(acc, 0.0f);
}

// ---------- ConvTranspose2d k=4 s=2 p=1 (torch weight layout [Ci][Co][4][4]) ----------
template<bool RELU, int CO, int LOGHO>
__global__ __launch_bounds__(256) void convt4s2_k(
    const float* __restrict__ x, const float* __restrict__ w,
    const float* __restrict__ bias, float* __restrict__ y) {
  constexpr int HO = 1 << LOGHO;
  constexpr int HI = HO / 2;
  constexpr int CI = 128;
  int tid = blockIdx.x * 256 + threadIdx.x;
  int wo = tid & (HO - 1);
  int ho = (tid >> LOGHO) & (HO - 1);
  int rest = tid >> (2 * LOGHO);
  int co = rest % CO;
  int n  = rest / CO;
  int kh[2], hi[2], nh = 0;
#pragma unroll
  for (int kk = 0; kk < 4; ++kk) {
    int tt = ho + 1 - kk;
    if (tt >= 0 && (tt & 1) == 0 && (tt >> 1) < HI) { kh[nh] = kk; hi[nh] = tt >> 1; ++nh; }
  }
  int kw[2], wi[2], nw = 0;
#pragma unroll
  for (int kk = 0; kk < 4; ++kk) {
    int tt = wo + 1 - kk;
    if (tt >= 0 && (tt & 1) == 0 && (tt >> 1) < HI) { kw[nw] = kk; wi[nw] = tt >> 1; ++nw; }
  }
  float acc = bias[co];
  const float* xb = x + (size_t)n * CI * HI * HI;
  for (int ci = 0; ci < CI; ++ci) {
    const float* xp = xb + (size_t)ci * HI * HI;
    const float* wp = w + ((size_t)ci * CO + co) * 16;
    for (int a = 0; a < nh; ++a)
      for (int b2 = 0; b2 < nw; ++b2)
        acc = fmaf(xp[hi[a] * HI + wi[b2]], wp[kh[a] * 4 + kw[b2]], acc);
  }
  y[tid] = RELU ? fmaxf(acc, 0.0f) : acc;
}

// ---------------------------------------------------------------------------
extern "C" void kernel_launch(void* const* d_in, const int* in_sizes, int n_in,
                              void* d_out, int out_size, void* d_ws, size_t ws_size,
                              hipStream_t stream) {
  const float* x    = (const float*)d_in[0];
  const float* ew1  = (const float*)d_in[1];
  const float* eb1  = (const float*)d_in[2];
  const float* ew2  = (const float*)d_in[3];
  const float* eb2  = (const float*)d_in[4];
  const float* ew3  = (const float*)d_in[5];
  const float* eb3  = (const float*)d_in[6];
  const float* qw   = (const float*)d_in[7];
  const float* qb   = (const float*)d_in[8];
  const float* cb   = (const float*)d_in[9];
  const float* pw   = (const float*)d_in[10];
  const float* pb   = (const float*)d_in[11];
  const float* dw1  = (const float*)d_in[12];
  const float* db1  = (const float*)d_in[13];
  const float* dtw2 = (const float*)d_in[14];
  const float* dtb2 = (const float*)d_in[15];
  const float* dtw3 = (const float*)d_in[16];
  const float* dtb3 = (const float*)d_in[17];

  char* wsb = (char*)d_ws;
  float* h1   = (float*)(wsb + OFF_H1);
  float* h2   = (float*)(wsb + OFF_H2);
  float* h3   = (float*)(wsb + OFF_H3);
  float* zff  = (float*)(wsb + OFF_ZF);
  float* znb  = (float*)(wsb + OFF_ZN);
  float* cnb  = (float*)(wsb + OFF_CN);
  int*   cand = (int*)(wsb + OFF_CAND);
  int*   cntb = (int*)(wsb + OFF_CNT);
  int*   idxb = (int*)(wsb + OFF_IDX);
  float* accum= (float*)(wsb + OFF_ACC);
  float* PC   = (float*)(wsb + OFF_PC);
  float* qbuf = h2;   // reuse (h2 dead after conv3)
  float* d1   = h3;   // reuse (h3 dead after qconv)
  float* d2   = h1;   // reuse (h1 dead after conv2)

  float* out      = (float*)d_out;
  float* outLoss  = out + 786432;
  float* outIdxF  = out + 786433;

  // encoder: per-op fp32-rounded (f64-exact inside each op)
  hipLaunchKernelGGL((conv4s2_relu_pr_k<3, 7>),   dim3(32768), dim3(256), 0, stream, x,  ew1, eb1, h1);
  hipLaunchKernelGGL((conv4s2_relu_pr_k<128, 6>), dim3(8192),  dim3(256), 0, stream, h1, ew2, eb2, h2);
  hipLaunchKernelGGL(conv3s1_pr_k,                dim3(8192),  dim3(256), 0, stream, h2, ew3, eb3, h3);
  hipLaunchKernelGGL(qconv_z_pr_k,                dim3(16384), dim3(256), 0, stream, h3, qw, qb, zff);

  // vector quantize: fp32-faithful d with first-index tie-break
  hipLaunchKernelGGL(rownorm_k,   dim3(4096),  dim3(256), 0, stream, zff, znb);
  hipLaunchKernelGGL(rownorm_k,   dim3(2048),  dim3(256), 0, stream, cb, cnb);
  hipLaunchKernelGGL(vq_filter_k, dim3(512),   dim3(256), 0, stream, zff, cb, cnb, znb, cand, cntb);
  hipLaunchKernelGGL(vq_phase3_k, dim3(4096),  dim3(256), 0, stream, zff, cb, znb, cnb, cand, cntb, idxb);
  hipLaunchKernelGGL(init_k,      dim3(1),     dim3(1),   0, stream, accum);
  hipLaunchKernelGGL(commit_k,    dim3(16384), dim3(256), 0, stream, zff, cb, idxb, accum, outIdxF);
  hipLaunchKernelGGL(fin_k,       dim3(1),     dim3(1),   0, stream, accum, outLoss);

  // decoder fp32 (pqconv folded through codebook: q = PC[idx] + b)
  hipLaunchKernelGGL(pc_k,        dim3(4096),  dim3(256), 0, stream, cb, pw, PC);
  hipLaunchKernelGGL(gather_pc_k, dim3(8192),  dim3(256), 0, stream, PC, idxb, pb, qbuf);
  hipLaunchKernelGGL(conv3s1_relu_f32_k,        dim3(8192),  dim3(256), 0, stream, qbuf, dw1, db1, d1);
  hipLaunchKernelGGL((convt4s2_k<true, 128, 7>),dim3(32768), dim3(256), 0, stream, d1, dtw2, dtb2, d2);
  hipLaunchKernelGGL((convt4s2_k<false, 3, 8>), dim3(3072),  dim3(256), 0, stream, d2, dtw3, dtb3, out);
}

// Round 4
// 6616.417 us; speedup vs baseline: 1.2106x; 1.2106x over previous
//
#include <hip/hip_runtime.h>

// ---------------------------------------------------------------------------
// VQ-VAE forward, round 4: MFMA (bf16-split K=768) VQ filter + ILP-unrolled
// f64 encoder convs. Numerics contract (validated round 3): every reference
// op = fl32(f64-exact op on fp32 operands); d in fp32; first-index argmin.
//
// d_out (float32): recon[786432] | commit_loss[1] | indices[16384]
//
// Workspace (BYTE offsets), ~88.2 MB peak:
#define OFF_H1   ((size_t)0)           // f32 4x128x128x128 (33.55M); later A' then d2
#define OFF_AP   ((size_t)0)           // bf16 A' [16384][768] (25.17M)
#define OFF_D2   ((size_t)0)           // f32 decoder d2 (33.55M)
#define OFF_H2   ((size_t)33554432)    // f32 (8.39M); later cand / qbuf
#define OFF_H3   ((size_t)41943040)    // f32 (8.39M); later cand / d1
#define OFF_CAND ((size_t)33554432)    // i32 [16384][64][4] (16.78M)
#define OFF_QBUF ((size_t)33554432)
#define OFF_D1   ((size_t)41943040)
#define OFF_ZF   ((size_t)50331648)    // f32 [16384][256] (16.78M)
#define OFF_BP   ((size_t)67108864)    // bf16 B' [8192][768] (12.58M)
#define OFF_CNT  ((size_t)79691776)    // i32 [16384][64] (4.19M)
#define OFF_ZN   ((size_t)83886080)    // f32 [16384]
#define OFF_CN   ((size_t)83951616)    // f32 [8192]
#define OFF_IDX  ((size_t)83984384)    // i32 [16384]
#define OFF_ACC  ((size_t)84049920)    // f32 [1]
#define OFF_PC   ((size_t)84049984)    // f32 [8192][128] (4.19M)

#define VQ_MARGIN 6e-5f

typedef __attribute__((ext_vector_type(8))) short bf16x8;
typedef __attribute__((ext_vector_type(4))) float f32x4;

// ---------- helpers ----------
__device__ __forceinline__ unsigned short f2bf(float f) {
  unsigned u = __float_as_uint(f);
  u += 0x7FFFu + ((u >> 16) & 1u);
  return (unsigned short)(u >> 16);
}
__device__ __forceinline__ float bf2f(unsigned short h) {
  return __uint_as_float(((unsigned)h) << 16);
}
__device__ __forceinline__ unsigned fkey(float f) {
  unsigned u = __float_as_uint(f);
  return (u & 0x80000000u) ? ~u : (u | 0x80000000u);
}
__device__ __forceinline__ float funkey(unsigned k) {
  unsigned u = (k & 0x80000000u) ? (k ^ 0x80000000u) : ~k;
  return __uint_as_float(u);
}

// ---------- conv k=4 s=2 p=1, f64 acc (4-way ILP), fp32-rounded out, ReLU ----------
template<int CIN, int LOGWO>
__global__ __launch_bounds__(256) void conv4s2_relu_pr_k(
    const float* __restrict__ x, const float* __restrict__ w,
    const float* __restrict__ bias, float* __restrict__ y) {
  constexpr int WO = 1 << LOGWO;
  constexpr int WI = WO * 2;
  int tid = blockIdx.x * 256 + threadIdx.x;
  int wo = tid & (WO - 1);
  int ho = (tid >> LOGWO) & (WO - 1);
  int co = (tid >> (2 * LOGWO)) & 127;
  int n  = tid >> (2 * LOGWO + 7);
  const float* xb = x + (size_t)n * CIN * WI * WI;
  const float* wb = w + (size_t)co * CIN * 16;
  int hv[4], wv[4];
#pragma unroll
  for (int kh = 0; kh < 4; ++kh) { int hi = 2 * ho - 1 + kh; hv[kh] = ((unsigned)hi < (unsigned)WI) ? hi : -1; }
#pragma unroll
  for (int kw = 0; kw < 4; ++kw) { int wi = 2 * wo - 1 + kw; wv[kw] = ((unsigned)wi < (unsigned)WI) ? wi : -1; }
  double acc;
  if constexpr (CIN % 4 == 0) {
    double a[4] = {0.0, 0.0, 0.0, 0.0};
    for (int ci = 0; ci < CIN; ci += 4) {
#pragma unroll
      for (int u = 0; u < 4; ++u) {
        const float* xp = xb + (size_t)(ci + u) * WI * WI;
        const float* wp = wb + (ci + u) * 16;
#pragma unroll
        for (int kh = 0; kh < 4; ++kh) if (hv[kh] >= 0) {
          const float* row = xp + (size_t)hv[kh] * WI;
#pragma unroll
          for (int kw = 0; kw < 4; ++kw) if (wv[kw] >= 0)
            a[u] = fma((double)row[wv[kw]], (double)wp[kh * 4 + kw], a[u]);
        }
      }
    }
    acc = (double)bias[co] + ((a[0] + a[1]) + (a[2] + a[3]));
  } else {
    acc = (double)bias[co];
    for (int ci = 0; ci < CIN; ++ci) {
      const float* xp = xb + (size_t)ci * WI * WI;
      const float* wp = wb + ci * 16;
#pragma unroll
      for (int kh = 0; kh < 4; ++kh) if (hv[kh] >= 0) {
        const float* row = xp + (size_t)hv[kh] * WI;
#pragma unroll
        for (int kw = 0; kw < 4; ++kw) if (wv[kw] >= 0)
          acc = fma((double)row[wv[kw]], (double)wp[kh * 4 + kw], acc);
      }
    }
  }
  float r = (float)acc;
  y[tid] = fmaxf(r, 0.0f);
}

// ---------- conv k=3 s=1 p=1, f64 acc (4-way ILP), fp32-rounded ----------
__global__ __launch_bounds__(256) void conv3s1_pr_k(
    const float* __restrict__ x, const float* __restrict__ w,
    const float* __restrict__ bias, float* __restrict__ y) {
  int tid = blockIdx.x * 256 + threadIdx.x;
  int wo = tid & 63;
  int ho = (tid >> 6) & 63;
  int co = (tid >> 12) & 127;
  int n  = tid >> 19;
  const float* xb = x + (size_t)n * 128 * 4096;
  const float* wb = w + (size_t)co * 1152;
  int hv[3], wv[3];
#pragma unroll
  for (int kh = 0; kh < 3; ++kh) { int hi = ho - 1 + kh; hv[kh] = ((unsigned)hi < 64u) ? hi : -1; }
#pragma unroll
  for (int kw = 0; kw < 3; ++kw) { int wi = wo - 1 + kw; wv[kw] = ((unsigned)wi < 64u) ? wi : -1; }
  double a[4] = {0.0, 0.0, 0.0, 0.0};
  for (int ci = 0; ci < 128; ci += 4) {
#pragma unroll
    for (int u = 0; u < 4; ++u) {
      const float* xp = xb + (size_t)(ci + u) * 4096;
      const float* wp = wb + (ci + u) * 9;
#pragma unroll
      for (int kh = 0; kh < 3; ++kh) if (hv[kh] >= 0) {
        const float* row = xp + hv[kh] * 64;
#pragma unroll
        for (int kw = 0; kw < 3; ++kw) if (wv[kw] >= 0)
          a[u] = fma((double)row[wv[kw]], (double)wp[kh * 3 + kw], a[u]);
      }
    }
  }
  double acc = (double)bias[co] + ((a[0] + a[1]) + (a[2] + a[3]));
  y[tid] = (float)acc;
}

// ---------- 1x1 conv 128->256, f64 acc (4-way ILP), fp32 z transposed ----------
__global__ __launch_bounds__(256) void qconv_z_pr_k(
    const float* __restrict__ h3, const float* __restrict__ w,
    const float* __restrict__ bias, float* __restrict__ zf) {
  int tid = blockIdx.x * 256 + threadIdx.x;  // p*256 + co
  int co = tid & 255;
  int p  = tid >> 8;
  int n  = p >> 12;
  int hw = p & 4095;
  const float* xp = h3 + ((size_t)n * 128) * 4096 + hw;
  const float* wp = w + (size_t)co * 128;
  double a[4] = {0.0, 0.0, 0.0, 0.0};
  for (int ci = 0; ci < 128; ci += 4) {
#pragma unroll
    for (int u = 0; u < 4; ++u)
      a[u] = fma((double)xp[(size_t)(ci + u) * 4096], (double)wp[ci + u], a[u]);
  }
  double acc = (double)bias[co] + ((a[0] + a[1]) + (a[2] + a[3]));
  zf[tid] = (float)acc;
}

// ---------- row norms: fl32( f64-sum of fl32(v^2) ) ----------
__global__ __launch_bounds__(256) void rownorm_k(const float* __restrict__ src,
                                                 float* __restrict__ dst) {
  int lane = threadIdx.x & 63;
  int r = blockIdx.x * 4 + (threadIdx.x >> 6);
  const float* v = src + (size_t)r * 256;
  double s = 0.0;
#pragma unroll
  for (int j = 0; j < 4; ++j) {
    float x = v[lane + (j << 6)];
    float xx = x * x;
    s += (double)xx;
  }
#pragma unroll
  for (int off = 32; off > 0; off >>= 1) s += __shfl_down(s, off, 64);
  if (lane == 0) dst[r] = (float)s;
}

// ---------- bf16 split builders: A' = [hi|hi|lo], B' = [hi|lo|hi] ----------
template<int MODE>  // 0 = A, 1 = B
__global__ __launch_bounds__(256) void build_split_k(
    const float* __restrict__ src, short* __restrict__ dst) {
  int tid = blockIdx.x * 256 + threadIdx.x;
  int e = tid & 255, row = tid >> 8;
  float v = src[tid];
  unsigned short hi = f2bf(v);
  unsigned short lo = f2bf(v - bf2f(hi));
  short* d = dst + (size_t)row * 768;
  if (MODE == 0) { d[e] = (short)hi; d[256 + e] = (short)hi; d[512 + e] = (short)lo; }
  else           { d[e] = (short)hi; d[256 + e] = (short)lo; d[512 + e] = (short)hi; }
}

// ---------- VQ filter GEMM: 128x128 tile, 16x16x32 bf16 MFMA, K=768 ----------
// s~(p,k) = cn[k] - 2*dot~; per-block local row-min + margin candidate collect.
__global__ __launch_bounds__(256, 2) void vq_gemm_k(
    const short* __restrict__ Ab, const short* __restrict__ Bb,
    const float* __restrict__ cnArr,
    int* __restrict__ cnt, int* __restrict__ cand) {
  __shared__ __align__(16) short As[128 * 32];
  __shared__ __align__(16) short Bs[128 * 32];
  __shared__ unsigned loc[128];
  const int t = threadIdx.x;
  const int w = t >> 6, L = t & 63;
  const int mb = blockIdx.x >> 6;
  const int nb = blockIdx.x & 63;
  const int m0 = mb << 7, n0 = nb << 7;
  if (t < 128) loc[t] = 0xFFFFFFFFu;
  f32x4 acc[4][4] = {};
  const int wr = (w >> 1) << 6, wc = (w & 1) << 6;
  const int srow = L >> 2, kg = L & 3;
  const int q = L >> 4, ln = L & 15;
  for (int kk = 0; kk < 768; kk += 32) {
    __syncthreads();
#pragma unroll
    for (int c = 0; c < 2; ++c) {
      const int row = (w << 5) + (c << 4) + srow;
      const bf16x8 av = *(const bf16x8*)(Ab + (size_t)(m0 + row) * 768 + kk + kg * 8);
      *(bf16x8*)(&As[row * 32 + kg * 8]) = av;
      const bf16x8 bv = *(const bf16x8*)(Bb + (size_t)(n0 + row) * 768 + kk + kg * 8);
      *(bf16x8*)(&Bs[row * 32 + kg * 8]) = bv;
    }
    __syncthreads();
    bf16x8 af[4], bf[4];
#pragma unroll
    for (int i = 0; i < 4; ++i)
      af[i] = *(const bf16x8*)(&As[(wr + 16 * i + ln) * 32 + q * 8]);
#pragma unroll
    for (int j = 0; j < 4; ++j)
      bf[j] = *(const bf16x8*)(&Bs[(wc + 16 * j + ln) * 32 + q * 8]);
#pragma unroll
    for (int i = 0; i < 4; ++i)
#pragma unroll
      for (int j = 0; j < 4; ++j)
        acc[i][j] = __builtin_amdgcn_mfma_f32_16x16x32_bf16(af[i], bf[j], acc[i][j], 0, 0, 0);
  }
  // epilogue: local row-min then margin collect
  float cnv[4];
#pragma unroll
  for (int j = 0; j < 4; ++j) cnv[j] = cnArr[n0 + wc + 16 * j + ln];
#pragma unroll
  for (int i = 0; i < 4; ++i)
#pragma unroll
    for (int r = 0; r < 4; ++r) {
      float mn = 3.4e38f;
#pragma unroll
      for (int j = 0; j < 4; ++j) mn = fminf(mn, fmaf(-2.0f, acc[i][j][r], cnv[j]));
      atomicMin(&loc[wr + 16 * i + 4 * q + r], fkey(mn));
    }
  __syncthreads();
#pragma unroll
  for (int i = 0; i < 4; ++i)
#pragma unroll
    for (int r = 0; r < 4; ++r) {
      const int rib = wr + 16 * i + 4 * q + r;
      const float thr = funkey(loc[rib]) + VQ_MARGIN;
      const int p = m0 + rib;
#pragma unroll
      for (int j = 0; j < 4; ++j) {
        float s = fmaf(-2.0f, acc[i][j][r], cnv[j]);
        if (s <= thr) {
          int slot = atomicAdd(&cnt[p * 64 + nb], 1);
          if (slot < 4) cand[(size_t)p * 256 + nb * 4 + slot] = n0 + wc + 16 * j + ln;
        }
      }
    }
}

// ---------- VQ final: fp32-faithful d, lexicographic (d,k) argmin ----------
__global__ __launch_bounds__(256) void vq_phase3_k(
    const float* __restrict__ zf, const float* __restrict__ cb,
    const float* __restrict__ znArr, const float* __restrict__ cnArr,
    const int* __restrict__ cnt, const int* __restrict__ cand,
    int* __restrict__ idxOut) {
  const int lane = threadIdx.x & 63;
  const int r = blockIdx.x * 4 + (threadIdx.x >> 6);
  const float* zr = zf + (size_t)r * 256;
  double z4[4];
#pragma unroll
  for (int j = 0; j < 4; ++j) z4[j] = (double)zr[lane + (j << 6)];
  const float znr = znArr[r];
  float bestd = 3.4e38f;
  int bestk = 0x7fffffff;
  for (int nb = 0; nb < 64; ++nb) {
    const int c = cnt[r * 64 + nb];
    const int nsc = (c <= 4) ? c : 128;
    for (int s2 = 0; s2 < nsc; ++s2) {
      const int k = (c <= 4) ? cand[(size_t)r * 256 + nb * 4 + s2] : (nb * 128 + s2);
      const float* ck = cb + (size_t)k * 256;
      double p = 0.0;
#pragma unroll
      for (int j = 0; j < 4; ++j)
        p = fma(z4[j], (double)ck[lane + (j << 6)], p);
#pragma unroll
      for (int off = 32; off > 0; off >>= 1) p += __shfl_down(p, off, 64);
      if (lane == 0) {
        float mm2 = (float)(2.0 * p);   // matmul op (x2 folded): fp32-rounded
        float t1 = znr + cnArr[k];      // fp32 add op
        float d = t1 - mm2;             // fp32 sub op
        if (d < bestd || (d == bestd && k < bestk)) { bestd = d; bestk = k; }
      }
    }
  }
  if (lane == 0) idxOut[r] = bestk;
}

// ---------- commit loss partials + indices-as-float output ----------
__global__ __launch_bounds__(256) void commit_k(
    const float* __restrict__ zf, const float* __restrict__ cb,
    const int* __restrict__ idxArr, float* __restrict__ accum,
    float* __restrict__ outIdxF) {
  __shared__ float wsum[4];
  const int p = blockIdx.x;
  const int t = threadIdx.x;
  const int k = idxArr[p];
  float d = cb[(size_t)k * 256 + t] - zf[(size_t)p * 256 + t];
  float v = d * d;
#pragma unroll
  for (int off = 32; off > 0; off >>= 1) v += __shfl_down(v, off, 64);
  if ((t & 63) == 0) wsum[t >> 6] = v;
  __syncthreads();
  if (t == 0) {
    atomicAdd(accum, wsum[0] + wsum[1] + wsum[2] + wsum[3]);
    outIdxF[p] = (float)k;
  }
}

__global__ void init_k(float* accum) { *accum = 0.0f; }
__global__ void fin_k(const float* __restrict__ accum, float* __restrict__ out) {
  *out = *accum * (1.0f / 4194304.0f);
}

// ---------- projected codebook PC[k][co] = sum_ci cb[k][ci]*pw[co][ci] ----------
__global__ __launch_bounds__(256) void pc_k(const float* __restrict__ cb,
                                            const float* __restrict__ pw,
                                            float* __restrict__ PC) {
  int tid = blockIdx.x * 256 + threadIdx.x;  // k*128 + co
  int co = tid & 127, k = tid >> 7;
  const float* c = cb + (size_t)k * 256;
  const float* w = pw + (size_t)co * 256;
  float a0 = 0.0f, a1 = 0.0f, a2 = 0.0f, a3 = 0.0f;
  for (int ci = 0; ci < 256; ci += 4) {
    a0 = fmaf(c[ci], w[ci], a0);
    a1 = fmaf(c[ci + 1], w[ci + 1], a1);
    a2 = fmaf(c[ci + 2], w[ci + 2], a2);
    a3 = fmaf(c[ci + 3], w[ci + 3], a3);
  }
  PC[tid] = (a0 + a1) + (a2 + a3);
}

// ---------- q = gather(PC, idx) + bias, NCHW fp32 ----------
__global__ __launch_bounds__(256) void gather_pc_k(
    const float* __restrict__ PC, const int* __restrict__ idxArr,
    const float* __restrict__ pb, float* __restrict__ q) {
  int tid = blockIdx.x * 256 + threadIdx.x;
  int hw = tid & 4095;
  int co = (tid >> 12) & 127;
  int n  = tid >> 19;
  int p  = (n << 12) + hw;
  q[tid] = PC[(size_t)idxArr[p] * 128 + co] + pb[co];
}

// ---------- fp32 conv k=3 s=1 p=1 + relu (dec conv1), 4-way ILP ----------
__global__ __launch_bounds__(256) void conv3s1_relu_f32_k(
    const float* __restrict__ x, const float* __restrict__ w,
    const float* __restrict__ bias, float* __restrict__ y) {
  int tid = blockIdx.x * 256 + threadIdx.x;
  int wo = tid & 63;
  int ho = (tid >> 6) & 63;
  int co = (tid >> 12) & 127;
  int n  = tid >> 19;
  const float* xb = x + (size_t)n * 128 * 4096;
  const float* wb = w + (size_t)co * 1152;
  int hv[3], wv[3];
#pragma unroll
  for (int kh = 0; kh < 3; ++kh) { int hi = ho - 1 + kh; hv[kh] = ((unsigned)hi < 64u) ? hi : -1; }
#pragma unroll
  for (int kw = 0; kw < 3; ++kw) { int wi = wo - 1 + kw; wv[kw] = ((unsigned)wi < 64u) ? wi : -1; }
  float a[4] = {0.0f, 0.0f, 0.0f, 0.0f};
  for (int ci = 0; ci < 128; ci += 4) {
#pragma unroll
    for (int u = 0; u < 4; ++u) {
      const float* xp = xb + (size_t)(ci + u) * 4096;
      const float* wp = wb + (ci + u) * 9;
#pragma unroll
      for (int kh = 0; kh < 3; ++kh) if (hv[kh] >= 0) {
        const float* row = xp + hv[kh] * 64;
#pragma unroll
        for (int kw = 0; kw < 3; ++kw) if (wv[kw] >= 0)
          a[u] = fmaf(row[wv[kw]], wp[kh * 3 + kw], a[u]);
      }
    }
  }
  float acc = bias[co] + ((a[0] + a[1]) + (a[2] + a[3]));
  y[tid] = fmaxf(acc, 0.0f);
}

// ---------- ConvTranspose2d k=4 s=2 p=1 (torch weight [Ci][Co][4][4]), 2-way ILP ----------
template<bool RELU, int CO, int LOGHO>
__global__ __launch_bounds__(256) void convt4s2_k(
    const float* __restrict__ x, const float* __restrict__ w,
    const float* __restrict__ bias, float* __restrict__ y) {
  constexpr int HO = 1 << LOGHO;
  constexpr int HI = HO / 2;
  constexpr int CI = 128;
  int tid = blockIdx.x * 256 + threadIdx.x;
  int wo = tid & (HO - 1);
  int ho = (tid >> LOGHO) & (HO - 1);
  int rest = tid >> (2 * LOGHO);
  int co = rest % CO;
  int n  = rest / CO;
  int kh[2], hi[2], nh = 0;
#pragma unroll
  for (int kk = 0; kk < 4; ++kk) {
    int tt = ho + 1 - kk;
    if (tt >= 0 && (tt & 1) == 0 && (tt >> 1) < HI) { kh[nh] = kk; hi[nh] = tt >> 1; ++nh; }
  }
  int kw[2], wi[2], nw = 0;
#pragma unroll
  for (int kk = 0; kk < 4; ++kk) {
    int tt = wo + 1 - kk;
    if (tt >= 0 && (tt & 1) == 0 && (tt >> 1) < HI) { kw[nw] = kk; wi[nw] = tt >> 1; ++nw; }
  }
  float a0 = 0.0f, a1 = 0.0f;
  const float* xb = x + (size_t)n * CI * HI * HI;
  for (int ci = 0; ci < CI; ci += 2) {
    const float* xp0 = xb + (size_t)ci * HI * HI;
    const float* wp0 = w + ((size_t)ci * CO + co) * 16;
    const float* xp1 = xp0 + HI * HI;
    const float* wp1 = wp0 + CO * 16;
    for (int a = 0; a < nh; ++a)
      for (int b2 = 0; b2 < nw; ++b2) {
        a0 = fmaf(xp0[hi[a] * HI + wi[b2]], wp0[kh[a] * 4 + kw[b2]], a0);
        a1 = fmaf(xp1[hi[a] * HI + wi[b2]], wp1[kh[a] * 4 + kw[b2]], a1);
      }
  }
  float acc = bias[co] + (a0 + a1);
  y[tid] = RELU ? fmaxf(acc, 0.0f) : acc;
}

// ---------------------------------------------------------------------------
extern "C" void kernel_launch(void* const* d_in, const int* in_sizes, int n_in,
                              void* d_out, int out_size, void* d_ws, size_t ws_size,
                              hipStream_t stream) {
  const float* x    = (const float*)d_in[0];
  const float* ew1  = (const float*)d_in[1];
  const float* eb1  = (const float*)d_in[2];
  const float* ew2  = (const float*)d_in[3];
  const float* eb2  = (const float*)d_in[4];
  const float* ew3  = (const float*)d_in[5];
  const float* eb3  = (const float*)d_in[6];
  const float* qw   = (const float*)d_in[7];
  const float* qb   = (const float*)d_in[8];
  const float* cb   = (const float*)d_in[9];
  const float* pw   = (const float*)d_in[10];
  const float* pb   = (const float*)d_in[11];
  const float* dw1  = (const float*)d_in[12];
  const float* db1  = (const float*)d_in[13];
  const float* dtw2 = (const float*)d_in[14];
  const float* dtb2 = (const float*)d_in[15];
  const float* dtw3 = (const float*)d_in[16];
  const float* dtb3 = (const float*)d_in[17];

  char* wsb = (char*)d_ws;
  float* h1   = (float*)(wsb + OFF_H1);
  float* h2   = (float*)(wsb + OFF_H2);
  float* h3   = (float*)(wsb + OFF_H3);
  short* Ap   = (short*)(wsb + OFF_AP);
  short* Bp   = (short*)(wsb + OFF_BP);
  float* zff  = (float*)(wsb + OFF_ZF);
  float* znb  = (float*)(wsb + OFF_ZN);
  float* cnb  = (float*)(wsb + OFF_CN);
  int*   cand = (int*)(wsb + OFF_CAND);
  int*   cntb = (int*)(wsb + OFF_CNT);
  int*   idxb = (int*)(wsb + OFF_IDX);
  float* accum= (float*)(wsb + OFF_ACC);
  float* PC   = (float*)(wsb + OFF_PC);
  float* qbuf = (float*)(wsb + OFF_QBUF);
  float* d1   = (float*)(wsb + OFF_D1);
  float* d2   = (float*)(wsb + OFF_D2);

  float* out      = (float*)d_out;
  float* outLoss  = out + 786432;
  float* outIdxF  = out + 786433;

  // encoder: per-op fp32-rounded (f64-exact inside each op), 4-way ILP
  hipLaunchKernelGGL((conv4s2_relu_pr_k<3, 7>),   dim3(32768), dim3(256), 0, stream, x,  ew1, eb1, h1);
  hipLaunchKernelGGL((conv4s2_relu_pr_k<128, 6>), dim3(8192),  dim3(256), 0, stream, h1, ew2, eb2, h2);
  hipLaunchKernelGGL(conv3s1_pr_k,                dim3(8192),  dim3(256), 0, stream, h2, ew3, eb3, h3);
  hipLaunchKernelGGL(qconv_z_pr_k,                dim3(16384), dim3(256), 0, stream, h3, qw, qb, zff);

  // VQ: bf16-split MFMA filter + exact fp32-faithful rescore
  hipLaunchKernelGGL(rownorm_k,          dim3(4096),  dim3(256), 0, stream, zff, znb);
  hipLaunchKernelGGL(rownorm_k,          dim3(2048),  dim3(256), 0, stream, cb, cnb);
  hipLaunchKernelGGL((build_split_k<0>), dim3(16384), dim3(256), 0, stream, zff, Ap);
  hipLaunchKernelGGL((build_split_k<1>), dim3(8192),  dim3(256), 0, stream, cb, Bp);
  hipMemsetAsync((void*)cntb, 0, (size_t)16384 * 64 * 4, stream);
  hipLaunchKernelGGL(vq_gemm_k,   dim3(8192),  dim3(256), 0, stream, Ap, Bp, cnb, cntb, cand);
  hipLaunchKernelGGL(vq_phase3_k, dim3(4096),  dim3(256), 0, stream, zff, cb, znb, cnb, cntb, cand, idxb);
  hipLaunchKernelGGL(init_k,      dim3(1),     dim3(1),   0, stream, accum);
  hipLaunchKernelGGL(commit_k,    dim3(16384), dim3(256), 0, stream, zff, cb, idxb, accum, outIdxF);
  hipLaunchKernelGGL(fin_k,       dim3(1),     dim3(1),   0, stream, accum, outLoss);

  // decoder fp32 (pqconv folded through codebook: q = PC[idx] + b)
  hipLaunchKernelGGL(pc_k,        dim3(4096),  dim3(256), 0, stream, cb, pw, PC);
  hipLaunchKernelGGL(gather_pc_k, dim3(8192),  dim3(256), 0, stream, PC, idxb, pb, qbuf);
  hipLaunchKernelGGL(conv3s1_relu_f32_k,        dim3(8192),  dim3(256), 0, stream, qbuf, dw1, db1, d1);
  hipLaunchKernelGGL((convt4s2_k<true, 128, 7>),dim3(32768), dim3(256), 0, stream, d1, dtw2, dtb2, d2);
  hipLaunchKernelGGL((convt4s2_k<false, 3, 8>), dim3(3072),  dim3(256), 0, stream, d2, dtw3, dtb3, out);
}

// Round 5
// 5854.921 us; speedup vs baseline: 1.3680x; 1.1301x over previous
//
#include <hip/hip_runtime.h>

// ---------------------------------------------------------------------------
// VQ-VAE forward, round 5: predicate-free convs via zero-padded buffers.
// Numerics contract (validated r3/r4): every reference op = fl32(f64-exact op
// on fp32 operands); d in fp32; first-index argmin. f64 association freedom
// is tolerated (flip prob ~1e-7/elem, validated empirically r3 vs r4).
//
// d_out (float32): recon[786432] | commit_loss[1] | indices[16384]
//
// Workspace regions (BYTE offsets), total ~82 MB:
//  A [0,34.61M):      h1p f32[4][128][130][130] -> Ap bf16[16384][768] -> d2p
//  B [34.61M,43.53M): h2p f32[4][128][66][66]   -> cand i32[16384][64][2] -> qbufp
//  C [43.53M,52.45M): xpad f32[4][3][258][258] -> h3 f32[4][128][64][64]
//                      -> cnt i32[16384][64] -> d1p f32[4][128][66][66]
//  D [52.45M,69.23M): zf f32[16384][256]
//  E [69.23M,81.81M): Bp bf16[8192][768] -> PC f32[8192][128]
//  G small: zn, cn, idx, acc
#define OFF_A    ((size_t)0)
#define OFF_B    ((size_t)34611200)
#define OFF_C    ((size_t)43532288)
#define OFF_D    ((size_t)52453376)
#define OFF_E    ((size_t)69230592)
#define OFF_ZN   ((size_t)81813504)
#define OFF_CN   ((size_t)81879040)
#define OFF_IDX  ((size_t)81911808)
#define OFF_ACC  ((size_t)81977344)

#define VQ_MARGIN 6e-5f

typedef __attribute__((ext_vector_type(8))) short bf16x8;
typedef __attribute__((ext_vector_type(4))) float f32x4;

// ---------- helpers ----------
__device__ __forceinline__ unsigned short f2bf(float f) {
  unsigned u = __float_as_uint(f);
  u += 0x7FFFu + ((u >> 16) & 1u);
  return (unsigned short)(u >> 16);
}
__device__ __forceinline__ float bf2f(unsigned short h) {
  return __uint_as_float(((unsigned)h) << 16);
}
__device__ __forceinline__ unsigned fkey(float f) {
  unsigned u = __float_as_uint(f);
  return (u & 0x80000000u) ? ~u : (u | 0x80000000u);
}
__device__ __forceinline__ float funkey(unsigned k) {
  unsigned u = (k & 0x80000000u) ? (k ^ 0x80000000u) : ~k;
  return __uint_as_float(u);
}

// ---------- pad-copy x into [4][3][258][258] ----------
__global__ __launch_bounds__(256) void padx_k(const float* __restrict__ x,
                                              float* __restrict__ xp) {
  int tid = blockIdx.x * 256 + threadIdx.x;
  int wo = tid & 255, ho = (tid >> 8) & 255, c = tid >> 16;  // c = n*3+ci
  xp[((size_t)c * 258 + ho + 1) * 258 + wo + 1] = x[tid];
}

// ---------- enc conv1: k=4 s=2 p=1 + ReLU, 3ci, padded in/out, f64 acc ----------
__global__ __launch_bounds__(256) void conv1_k(
    const float* __restrict__ xp, const float* __restrict__ w,
    const float* __restrict__ bias, float* __restrict__ h1p) {
  int tid = blockIdx.x * 256 + threadIdx.x;
  int wo = tid & 127, ho = (tid >> 7) & 127, co = (tid >> 14) & 127, n = tid >> 21;
  const float* xb = xp + (size_t)n * 3 * 66564 + (size_t)(2 * ho) * 258 + 2 * wo;
  const float* wb = w + (size_t)co * 48;
  double a[4] = {0.0, 0.0, 0.0, 0.0};
  for (int ci = 0; ci < 3; ++ci) {
    const float* xc = xb + (size_t)ci * 66564;
    const float* wp = wb + ci * 16;
#pragma unroll
    for (int kh = 0; kh < 4; ++kh)
#pragma unroll
      for (int kw = 0; kw < 4; ++kw)
        a[(kh * 4 + kw) & 3] = fma((double)xc[kh * 258 + kw],
                                   (double)wp[kh * 4 + kw], a[(kh * 4 + kw) & 3]);
  }
  double acc = (double)bias[co] + ((a[0] + a[1]) + (a[2] + a[3]));
  float r = (float)acc;
  h1p[(((size_t)n * 128 + co) * 130 + ho + 1) * 130 + wo + 1] = fmaxf(r, 0.0f);
}

// ---------- enc conv2: k=4 s=2 p=1 + ReLU, 128ci, padded in/out, f64 acc ----------
__global__ __launch_bounds__(256) void conv2_k(
    const float* __restrict__ h1p, const float* __restrict__ w,
    const float* __restrict__ bias, float* __restrict__ h2p) {
  int tid = blockIdx.x * 256 + threadIdx.x;
  int wo = tid & 63, ho = (tid >> 6) & 63, co = (tid >> 12) & 127, n = tid >> 19;
  const float* xb = h1p + (size_t)n * 128 * 16900 + (size_t)(2 * ho) * 130 + 2 * wo;
  const float* wb = w + (size_t)co * 2048;
  double a[4] = {0.0, 0.0, 0.0, 0.0};
  for (int ci = 0; ci < 128; ci += 4) {
#pragma unroll
    for (int u = 0; u < 4; ++u) {
      const float* xc = xb + (size_t)(ci + u) * 16900;
      const float* wp = wb + (ci + u) * 16;
#pragma unroll
      for (int kh = 0; kh < 4; ++kh)
#pragma unroll
        for (int kw = 0; kw < 4; ++kw)
          a[u] = fma((double)xc[kh * 130 + kw], (double)wp[kh * 4 + kw], a[u]);
    }
  }
  double acc = (double)bias[co] + ((a[0] + a[1]) + (a[2] + a[3]));
  float r = (float)acc;
  h2p[(((size_t)n * 128 + co) * 66 + ho + 1) * 66 + wo + 1] = fmaxf(r, 0.0f);
}

// ---------- enc conv3: k=3 s=1 p=1 (no relu), padded in, plain out, f64 acc ----------
__global__ __launch_bounds__(256) void conv3_k(
    const float* __restrict__ h2p, const float* __restrict__ w,
    const float* __restrict__ bias, float* __restrict__ h3) {
  int tid = blockIdx.x * 256 + threadIdx.x;
  int wo = tid & 63, ho = (tid >> 6) & 63, co = (tid >> 12) & 127, n = tid >> 19;
  const float* xb = h2p + (size_t)n * 128 * 4356 + (size_t)ho * 66 + wo;
  const float* wb = w + (size_t)co * 1152;
  double a[4] = {0.0, 0.0, 0.0, 0.0};
  for (int ci = 0; ci < 128; ci += 4) {
#pragma unroll
    for (int u = 0; u < 4; ++u) {
      const float* xc = xb + (size_t)(ci + u) * 4356;
      const float* wp = wb + (ci + u) * 9;
#pragma unroll
      for (int kh = 0; kh < 3; ++kh)
#pragma unroll
        for (int kw = 0; kw < 3; ++kw)
          a[u] = fma((double)xc[kh * 66 + kw], (double)wp[kh * 3 + kw], a[u]);
    }
  }
  double acc = (double)bias[co] + ((a[0] + a[1]) + (a[2] + a[3]));
  h3[tid] = (float)acc;
}

// ---------- 1x1 conv 128->256, f64 acc, fp32 z transposed [p][256] ----------
__global__ __launch_bounds__(256) void qconv_z_pr_k(
    const float* __restrict__ h3, const float* __restrict__ w,
    const float* __restrict__ bias, float* __restrict__ zf) {
  int tid = blockIdx.x * 256 + threadIdx.x;  // p*256 + co
  int co = tid & 255;
  int p  = tid >> 8;
  int n  = p >> 12;
  int hw = p & 4095;
  const float* xp = h3 + ((size_t)n * 128) * 4096 + hw;
  const float* wp = w + (size_t)co * 128;
  double a[4] = {0.0, 0.0, 0.0, 0.0};
  for (int ci = 0; ci < 128; ci += 4) {
#pragma unroll
    for (int u = 0; u < 4; ++u)
      a[u] = fma((double)xp[(size_t)(ci + u) * 4096], (double)wp[ci + u], a[u]);
  }
  double acc = (double)bias[co] + ((a[0] + a[1]) + (a[2] + a[3]));
  zf[tid] = (float)acc;
}

// ---------- row norms: fl32( f64-sum of fl32(v^2) ) ----------
__global__ __launch_bounds__(256) void rownorm_k(const float* __restrict__ src,
                                                 float* __restrict__ dst) {
  int lane = threadIdx.x & 63;
  int r = blockIdx.x * 4 + (threadIdx.x >> 6);
  const float* v = src + (size_t)r * 256;
  double s = 0.0;
#pragma unroll
  for (int j = 0; j < 4; ++j) {
    float x = v[lane + (j << 6)];
    float xx = x * x;
    s += (double)xx;
  }
#pragma unroll
  for (int off = 32; off > 0; off >>= 1) s += __shfl_down(s, off, 64);
  if (lane == 0) dst[r] = (float)s;
}

// ---------- bf16 split builders: A' = [hi|hi|lo], B' = [hi|lo|hi] ----------
template<int MODE>  // 0 = A, 1 = B
__global__ __launch_bounds__(256) void build_split_k(
    const float* __restrict__ src, short* __restrict__ dst) {
  int tid = blockIdx.x * 256 + threadIdx.x;
  int e = tid & 255, row = tid >> 8;
  float v = src[tid];
  unsigned short hi = f2bf(v);
  unsigned short lo = f2bf(v - bf2f(hi));
  short* d = dst + (size_t)row * 768;
  if (MODE == 0) { d[e] = (short)hi; d[256 + e] = (short)hi; d[512 + e] = (short)lo; }
  else           { d[e] = (short)hi; d[256 + e] = (short)lo; d[512 + e] = (short)hi; }
}

// ---------- VQ filter GEMM: 128x128 tile, 16x16x32 bf16 MFMA, K=768 ----------
__global__ __launch_bounds__(256, 2) void vq_gemm_k(
    const short* __restrict__ Ab, const short* __restrict__ Bb,
    const float* __restrict__ cnArr,
    int* __restrict__ cnt, int* __restrict__ cand) {
  __shared__ __align__(16) short As[128 * 32];
  __shared__ __align__(16) short Bs[128 * 32];
  __shared__ unsigned loc[128];
  const int t = threadIdx.x;
  const int w = t >> 6, L = t & 63;
  const int mb = blockIdx.x >> 6;
  const int nb = blockIdx.x & 63;
  const int m0 = mb << 7, n0 = nb << 7;
  if (t < 128) loc[t] = 0xFFFFFFFFu;
  f32x4 acc[4][4] = {};
  const int wr = (w >> 1) << 6, wc = (w & 1) << 6;
  const int srow = L >> 2, kg = L & 3;
  const int q = L >> 4, ln = L & 15;
  for (int kk = 0; kk < 768; kk += 32) {
    __syncthreads();
#pragma unroll
    for (int c = 0; c < 2; ++c) {
      const int row = (w << 5) + (c << 4) + srow;
      const bf16x8 av = *(const bf16x8*)(Ab + (size_t)(m0 + row) * 768 + kk + kg * 8);
      *(bf16x8*)(&As[row * 32 + kg * 8]) = av;
      const bf16x8 bv = *(const bf16x8*)(Bb + (size_t)(n0 + row) * 768 + kk + kg * 8);
      *(bf16x8*)(&Bs[row * 32 + kg * 8]) = bv;
    }
    __syncthreads();
    bf16x8 af[4], bf[4];
#pragma unroll
    for (int i = 0; i < 4; ++i)
      af[i] = *(const bf16x8*)(&As[(wr + 16 * i + ln) * 32 + q * 8]);
#pragma unroll
    for (int j = 0; j < 4; ++j)
      bf[j] = *(const bf16x8*)(&Bs[(wc + 16 * j + ln) * 32 + q * 8]);
#pragma unroll
    for (int i = 0; i < 4; ++i)
#pragma unroll
      for (int j = 0; j < 4; ++j)
        acc[i][j] = __builtin_amdgcn_mfma_f32_16x16x32_bf16(af[i], bf[j], acc[i][j], 0, 0, 0);
  }
  float cnv[4];
#pragma unroll
  for (int j = 0; j < 4; ++j) cnv[j] = cnArr[n0 + wc + 16 * j + ln];
#pragma unroll
  for (int i = 0; i < 4; ++i)
#pragma unroll
    for (int r = 0; r < 4; ++r) {
      float mn = 3.4e38f;
#pragma unroll
      for (int j = 0; j < 4; ++j) mn = fminf(mn, fmaf(-2.0f, acc[i][j][r], cnv[j]));
      atomicMin(&loc[wr + 16 * i + 4 * q + r], fkey(mn));
    }
  __syncthreads();
#pragma unroll
  for (int i = 0; i < 4; ++i)
#pragma unroll
    for (int r = 0; r < 4; ++r) {
      const int rib = wr + 16 * i + 4 * q + r;
      const float thr = funkey(loc[rib]) + VQ_MARGIN;
      const int p = m0 + rib;
#pragma unroll
      for (int j = 0; j < 4; ++j) {
        float s = fmaf(-2.0f, acc[i][j][r], cnv[j]);
        if (s <= thr) {
          int slot = atomicAdd(&cnt[p * 64 + nb], 1);
          if (slot < 2) cand[(size_t)p * 128 + nb * 2 + slot] = n0 + wc + 16 * j + ln;
        }
      }
    }
}

// ---------- VQ final: fp32-faithful d, lexicographic (d,k) argmin ----------
__global__ __launch_bounds__(256) void vq_phase3_k(
    const float* __restrict__ zf, const float* __restrict__ cb,
    const float* __restrict__ znArr, const float* __restrict__ cnArr,
    const int* __restrict__ cnt, const int* __restrict__ cand,
    int* __restrict__ idxOut) {
  const int lane = threadIdx.x & 63;
  const int r = blockIdx.x * 4 + (threadIdx.x >> 6);
  const float* zr = zf + (size_t)r * 256;
  double z4[4];
#pragma unroll
  for (int j = 0; j < 4; ++j) z4[j] = (double)zr[lane + (j << 6)];
  const float znr = znArr[r];
  float bestd = 3.4e38f;
  int bestk = 0x7fffffff;
  for (int nb = 0; nb < 64; ++nb) {
    const int c = cnt[r * 64 + nb];
    const int nsc = (c <= 2) ? c : 128;
    for (int s2 = 0; s2 < nsc; ++s2) {
      const int k = (c <= 2) ? cand[(size_t)r * 128 + nb * 2 + s2] : (nb * 128 + s2);
      const float* ck = cb + (size_t)k * 256;
      double p = 0.0;
#pragma unroll
      for (int j = 0; j < 4; ++j)
        p = fma(z4[j], (double)ck[lane + (j << 6)], p);
#pragma unroll
      for (int off = 32; off > 0; off >>= 1) p += __shfl_down(p, off, 64);
      if (lane == 0) {
        float mm2 = (float)(2.0 * p);   // matmul op (x2 folded): fp32-rounded
        float t1 = znr + cnArr[k];      // fp32 add op
        float d = t1 - mm2;             // fp32 sub op
        if (d < bestd || (d == bestd && k < bestk)) { bestd = d; bestk = k; }
      }
    }
  }
  if (lane == 0) idxOut[r] = bestk;
}

// ---------- commit loss partials + indices-as-float output ----------
__global__ __launch_bounds__(256) void commit_k(
    const float* __restrict__ zf, const float* __restrict__ cb,
    const int* __restrict__ idxArr, float* __restrict__ accum,
    float* __restrict__ outIdxF) {
  __shared__ float wsum[4];
  const int p = blockIdx.x;
  const int t = threadIdx.x;
  const int k = idxArr[p];
  float d = cb[(size_t)k * 256 + t] - zf[(size_t)p * 256 + t];
  float v = d * d;
#pragma unroll
  for (int off = 32; off > 0; off >>= 1) v += __shfl_down(v, off, 64);
  if ((t & 63) == 0) wsum[t >> 6] = v;
  __syncthreads();
  if (t == 0) {
    atomicAdd(accum, wsum[0] + wsum[1] + wsum[2] + wsum[3]);
    outIdxF[p] = (float)k;
  }
}

__global__ void init_k(float* accum) { *accum = 0.0f; }
__global__ void fin_k(const float* __restrict__ accum, float* __restrict__ out) {
  *out = *accum * (1.0f / 4194304.0f);
}

// ---------- projected codebook PC[k][co] = sum_ci cb[k][ci]*pw[co][ci] ----------
__global__ __launch_bounds__(256) void pc_k(const float* __restrict__ cb,
                                            const float* __restrict__ pw,
                                            float* __restrict__ PC) {
  int tid = blockIdx.x * 256 + threadIdx.x;  // k*128 + co
  int co = tid & 127, k = tid >> 7;
  const float* c = cb + (size_t)k * 256;
  const float* w = pw + (size_t)co * 256;
  float a0 = 0.0f, a1 = 0.0f, a2 = 0.0f, a3 = 0.0f;
  for (int ci = 0; ci < 256; ci += 4) {
    a0 = fmaf(c[ci], w[ci], a0);
    a1 = fmaf(c[ci + 1], w[ci + 1], a1);
    a2 = fmaf(c[ci + 2], w[ci + 2], a2);
    a3 = fmaf(c[ci + 3], w[ci + 3], a3);
  }
  PC[tid] = (a0 + a1) + (a2 + a3);
}

// ---------- q = gather(PC, idx) + bias, padded NCHW [66][66] ----------
__global__ __launch_bounds__(256) void gather_pc_k(
    const float* __restrict__ PC, const int* __restrict__ idxArr,
    const float* __restrict__ pb, float* __restrict__ qp) {
  int tid = blockIdx.x * 256 + threadIdx.x;
  int hw = tid & 4095;
  int co = (tid >> 12) & 127;
  int n  = tid >> 19;
  int p  = (n << 12) + hw;
  int h = hw >> 6, w2 = hw & 63;
  qp[(((size_t)n * 128 + co) * 66 + h + 1) * 66 + w2 + 1] =
      PC[(size_t)idxArr[p] * 128 + co] + pb[co];
}

// ---------- dec conv1: fp32 k=3 s=1 p=1 + relu, padded in/out ----------
__global__ __launch_bounds__(256) void dconv1_k(
    const float* __restrict__ qp, const float* __restrict__ w,
    const float* __restrict__ bias, float* __restrict__ d1p) {
  int tid = blockIdx.x * 256 + threadIdx.x;
  int wo = tid & 63, ho = (tid >> 6) & 63, co = (tid >> 12) & 127, n = tid >> 19;
  const float* xb = qp + (size_t)n * 128 * 4356 + (size_t)ho * 66 + wo;
  const float* wb = w + (size_t)co * 1152;
  float a[4] = {0.0f, 0.0f, 0.0f, 0.0f};
  for (int ci = 0; ci < 128; ci += 4) {
#pragma unroll
    for (int u = 0; u < 4; ++u) {
      const float* xc = xb + (size_t)(ci + u) * 4356;
      const float* wp = wb + (ci + u) * 9;
#pragma unroll
      for (int kh = 0; kh < 3; ++kh)
#pragma unroll
        for (int kw = 0; kw < 3; ++kw)
          a[u] = fmaf(xc[kh * 66 + kw], wp[kh * 3 + kw], a[u]);
    }
  }
  float acc = bias[co] + ((a[0] + a[1]) + (a[2] + a[3]));
  d1p[(((size_t)n * 128 + co) * 66 + ho + 1) * 66 + wo + 1] = fmaxf(acc, 0.0f);
}

// ---------- convt2: k=4 s=2 p=1 + relu, 128->128, in d1p[66], out d2p[130] ----------
__global__ __launch_bounds__(256) void convt2_k(
    const float* __restrict__ xp, const float* __restrict__ w,
    const float* __restrict__ bias, float* __restrict__ y) {
  int tid = blockIdx.x * 256 + threadIdx.x;
  int wo = tid & 127, ho = (tid >> 7) & 127, co = (tid >> 14) & 127, n = tid >> 21;
  const int ph = (ho + 1) & 1, pw_ = (wo + 1) & 1;
  const int kh0 = ph, kh1 = ph + 2;
  const int kw0 = pw_, kw1 = pw_ + 2;
  const int r0 = ((ho + 1 - kh0) >> 1) + 1;   // padded rows, in [0,65]
  const int r1 = r0 - 1;
  const int c0 = ((wo + 1 - kw0) >> 1) + 1;
  const int c1 = c0 - 1;
  const float* xb = xp + (size_t)n * 128 * 4356;
  float a0 = 0.0f, a1 = 0.0f;
  for (int ci = 0; ci < 128; ci += 2) {
    const float* x0 = xb + (size_t)ci * 4356;
    const float* x1 = x0 + 4356;
    const float* w0 = w + ((size_t)ci * 128 + co) * 16;
    const float* w1 = w0 + 128 * 16;
    a0 = fmaf(x0[r0 * 66 + c0], w0[kh0 * 4 + kw0], a0);
    a0 = fmaf(x0[r0 * 66 + c1], w0[kh0 * 4 + kw1], a0);
    a0 = fmaf(x0[r1 * 66 + c0], w0[kh1 * 4 + kw0], a0);
    a0 = fmaf(x0[r1 * 66 + c1], w0[kh1 * 4 + kw1], a0);
    a1 = fmaf(x1[r0 * 66 + c0], w1[kh0 * 4 + kw0], a1);
    a1 = fmaf(x1[r0 * 66 + c1], w1[kh0 * 4 + kw1], a1);
    a1 = fmaf(x1[r1 * 66 + c0], w1[kh1 * 4 + kw0], a1);
    a1 = fmaf(x1[r1 * 66 + c1], w1[kh1 * 4 + kw1], a1);
  }
  float acc = bias[co] + (a0 + a1);
  y[(((size_t)n * 128 + co) * 130 + ho + 1) * 130 + wo + 1] = fmaxf(acc, 0.0f);
}

// ---------- convt3: k=4 s=2 p=1 (no relu), 128->3, in d2p[130], plain out ----------
__global__ __launch_bounds__(256) void convt3_k(
    const float* __restrict__ xp, const float* __restrict__ w,
    const float* __restrict__ bias, float* __restrict__ y) {
  int tid = blockIdx.x * 256 + threadIdx.x;
  int wo = tid & 255, ho = (tid >> 8) & 255;
  int rest = tid >> 16;
  int co = rest % 3, n = rest / 3;
  const int ph = (ho + 1) & 1, pw_ = (wo + 1) & 1;
  const int kh0 = ph, kh1 = ph + 2;
  const int kw0 = pw_, kw1 = pw_ + 2;
  const int r0 = ((ho + 1 - kh0) >> 1) + 1;   // padded rows, in [0,129]
  const int r1 = r0 - 1;
  const int c0 = ((wo + 1 - kw0) >> 1) + 1;
  const int c1 = c0 - 1;
  const float* xb = xp + (size_t)n * 128 * 16900;
  float a0 = 0.0f, a1 = 0.0f;
  for (int ci = 0; ci < 128; ci += 2) {
    const float* x0 = xb + (size_t)ci * 16900;
    const float* x1 = x0 + 16900;
    const float* w0 = w + ((size_t)ci * 3 + co) * 16;
    const float* w1 = w0 + 48;
    a0 = fmaf(x0[r0 * 130 + c0], w0[kh0 * 4 + kw0], a0);
    a0 = fmaf(x0[r0 * 130 + c1], w0[kh0 * 4 + kw1], a0);
    a0 = fmaf(x0[r1 * 130 + c0], w0[kh1 * 4 + kw0], a0);
    a0 = fmaf(x0[r1 * 130 + c1], w0[kh1 * 4 + kw1], a0);
    a1 = fmaf(x1[r0 * 130 + c0], w1[kh0 * 4 + kw0], a1);
    a1 = fmaf(x1[r0 * 130 + c1], w1[kh0 * 4 + kw1], a1);
    a1 = fmaf(x1[r1 * 130 + c0], w1[kh1 * 4 + kw0], a1);
    a1 = fmaf(x1[r1 * 130 + c1], w1[kh1 * 4 + kw1], a1);
  }
  y[tid] = bias[co] + (a0 + a1);
}

// ---------------------------------------------------------------------------
extern "C" void kernel_launch(void* const* d_in, const int* in_sizes, int n_in,
                              void* d_out, int out_size, void* d_ws, size_t ws_size,
                              hipStream_t stream) {
  const float* x    = (const float*)d_in[0];
  const float* ew1  = (const float*)d_in[1];
  const float* eb1  = (const float*)d_in[2];
  const float* ew2  = (const float*)d_in[3];
  const float* eb2  = (const float*)d_in[4];
  const float* ew3  = (const float*)d_in[5];
  const float* eb3  = (const float*)d_in[6];
  const float* qw   = (const float*)d_in[7];
  const float* qb   = (const float*)d_in[8];
  const float* cb   = (const float*)d_in[9];
  const float* pw   = (const float*)d_in[10];
  const float* pb   = (const float*)d_in[11];
  const float* dw1  = (const float*)d_in[12];
  const float* db1  = (const float*)d_in[13];
  const float* dtw2 = (const float*)d_in[14];
  const float* dtb2 = (const float*)d_in[15];
  const float* dtw3 = (const float*)d_in[16];
  const float* dtb3 = (const float*)d_in[17];

  char* wsb = (char*)d_ws;
  float* h1p  = (float*)(wsb + OFF_A);
  short* Ap   = (short*)(wsb + OFF_A);
  float* d2p  = (float*)(wsb + OFF_A);
  float* h2p  = (float*)(wsb + OFF_B);
  int*   cand = (int*)(wsb + OFF_B);
  float* qbufp= (float*)(wsb + OFF_B);
  float* xpad = (float*)(wsb + OFF_C);
  float* h3   = (float*)(wsb + OFF_C);
  int*   cntb = (int*)(wsb + OFF_C);
  float* d1p  = (float*)(wsb + OFF_C);
  float* zff  = (float*)(wsb + OFF_D);
  short* Bp   = (short*)(wsb + OFF_E);
  float* PC   = (float*)(wsb + OFF_E);
  float* znb  = (float*)(wsb + OFF_ZN);
  float* cnb  = (float*)(wsb + OFF_CN);
  int*   idxb = (int*)(wsb + OFF_IDX);
  float* accum= (float*)(wsb + OFF_ACC);

  float* out      = (float*)d_out;
  float* outLoss  = out + 786432;
  float* outIdxF  = out + 786433;

  // zero pads for encoder buffers
  hipMemsetAsync((void*)h1p,  0, 34611200, stream);
  hipMemsetAsync((void*)h2p,  0, 8921088,  stream);
  hipMemsetAsync((void*)xpad, 0, 3195072,  stream);

  // encoder: per-op fp32-rounded (f64-exact inside each op), predicate-free
  hipLaunchKernelGGL(padx_k,       dim3(3072),  dim3(256), 0, stream, x, xpad);
  hipLaunchKernelGGL(conv1_k,      dim3(32768), dim3(256), 0, stream, xpad, ew1, eb1, h1p);
  hipLaunchKernelGGL(conv2_k,      dim3(8192),  dim3(256), 0, stream, h1p, ew2, eb2, h2p);
  hipLaunchKernelGGL(conv3_k,      dim3(8192),  dim3(256), 0, stream, h2p, ew3, eb3, h3);
  hipLaunchKernelGGL(qconv_z_pr_k, dim3(16384), dim3(256), 0, stream, h3, qw, qb, zff);

  // VQ: bf16-split MFMA filter + exact fp32-faithful rescore
  hipLaunchKernelGGL(rownorm_k,          dim3(4096),  dim3(256), 0, stream, zff, znb);
  hipLaunchKernelGGL(rownorm_k,          dim3(2048),  dim3(256), 0, stream, cb, cnb);
  hipLaunchKernelGGL((build_split_k<0>), dim3(16384), dim3(256), 0, stream, zff, Ap);
  hipLaunchKernelGGL((build_split_k<1>), dim3(8192),  dim3(256), 0, stream, cb, Bp);
  hipMemsetAsync((void*)cntb, 0, (size_t)16384 * 64 * 4, stream);
  hipLaunchKernelGGL(vq_gemm_k,   dim3(8192),  dim3(256), 0, stream, Ap, Bp, cnb, cntb, cand);
  hipLaunchKernelGGL(vq_phase3_k, dim3(4096),  dim3(256), 0, stream, zff, cb, znb, cnb, cntb, cand, idxb);
  hipLaunchKernelGGL(init_k,      dim3(1),     dim3(1),   0, stream, accum);
  hipLaunchKernelGGL(commit_k,    dim3(16384), dim3(256), 0, stream, zff, cb, idxb, accum, outIdxF);
  hipLaunchKernelGGL(fin_k,       dim3(1),     dim3(1),   0, stream, accum, outLoss);

  // decoder fp32 (pqconv folded through codebook: q = PC[idx] + b)
  hipLaunchKernelGGL(pc_k, dim3(4096), dim3(256), 0, stream, cb, pw, PC);
  hipMemsetAsync((void*)qbufp, 0, 8921088,  stream);   // cand dead after phase3
  hipMemsetAsync((void*)d1p,   0, 8921088,  stream);   // cnt dead after phase3
  hipMemsetAsync((void*)d2p,   0, 34611200, stream);   // Ap dead after vq_gemm
  hipLaunchKernelGGL(gather_pc_k, dim3(8192),  dim3(256), 0, stream, PC, idxb, pb, qbufp);
  hipLaunchKernelGGL(dconv1_k,    dim3(8192),  dim3(256), 0, stream, qbufp, dw1, db1, d1p);
  hipLaunchKernelGGL(convt2_k,    dim3(32768), dim3(256), 0, stream, d1p, dtw2, dtb2, d2p);
  hipLaunchKernelGGL(convt3_k,    dim3(3072),  dim3(256), 0, stream, d2p, dtw3, dtb3, out);
}

// Round 6
// 2964.531 us; speedup vs baseline: 2.7019x; 1.9750x over previous
//
#include <hip/hip_runtime.h>

// ---------------------------------------------------------------------------
// VQ-VAE forward, round 6: scalar-weight + co-blocked convs (L1-load-bound fix).
// Numerics contract (validated r3-r5): every reference op = fl32(f64-exact op
// on fp32 operands); d in fp32; first-index argmin; f64 assoc freedom OK.
//
// d_out (float32): recon[786432] | commit_loss[1] | indices[16384]
//
// Workspace regions (BYTE offsets), total ~83.1 MB:
//  A [0,34.61M):      h1p f32[4][128][130][130] -> Ap bf16[16384][768] -> d2p
//  B [34.61M,43.53M): h2p f32[4][128][66][66]   -> cand i32[16384][64][2] -> qbufp
//  C [43.53M,52.45M): xpad f32[4][3][258][258] -> h3 f32[4][128][64][64]
//                      -> cnt i32[16384][64] -> d1p f32[4][128][66][66]
//  D [52.45M,69.23M): zf f32[16384][256]
//  E [69.23M,81.81M): Bp bf16[8192][768] -> PC f32[8192][128]
//  tail: zn, cn, idx, acc, wr2 (1MB), wr3 (24KB)
#define OFF_A    ((size_t)0)
#define OFF_B    ((size_t)34611200)
#define OFF_C    ((size_t)43532288)
#define OFF_D    ((size_t)52453376)
#define OFF_E    ((size_t)69230592)
#define OFF_ZN   ((size_t)81813504)
#define OFF_CN   ((size_t)81879040)
#define OFF_IDX  ((size_t)81911808)
#define OFF_ACC  ((size_t)81977344)
#define OFF_WR2  ((size_t)81977600)
#define OFF_WR3  ((size_t)83026176)

#define VQ_MARGIN 6e-5f

typedef __attribute__((ext_vector_type(8))) short bf16x8;
typedef __attribute__((ext_vector_type(4))) float f32x4;

// ---------- helpers ----------
__device__ __forceinline__ unsigned short f2bf(float f) {
  unsigned u = __float_as_uint(f);
  u += 0x7FFFu + ((u >> 16) & 1u);
  return (unsigned short)(u >> 16);
}
__device__ __forceinline__ float bf2f(unsigned short h) {
  return __uint_as_float(((unsigned)h) << 16);
}
__device__ __forceinline__ unsigned fkey(float f) {
  unsigned u = __float_as_uint(f);
  return (u & 0x80000000u) ? ~u : (u | 0x80000000u);
}
__device__ __forceinline__ float funkey(unsigned k) {
  unsigned u = (k & 0x80000000u) ? (k ^ 0x80000000u) : ~k;
  return __uint_as_float(u);
}

// ---------- pad-copy x into [4][3][258][258] ----------
__global__ __launch_bounds__(256) void padx_k(const float* __restrict__ x,
                                              float* __restrict__ xp) {
  int tid = blockIdx.x * 256 + threadIdx.x;
  int wo = tid & 255, ho = (tid >> 8) & 255, c = tid >> 16;  // c = n*3+ci
  xp[((size_t)c * 258 + ho + 1) * 258 + wo + 1] = x[tid];
}

// ---------- enc conv1: k=4 s=2 + ReLU, 3ci, co x4, f64 acc ----------
__global__ __launch_bounds__(256) void conv1_k(
    const float* __restrict__ xp, const float* __restrict__ w,
    const float* __restrict__ bias, float* __restrict__ h1p) {
  int b = blockIdx.x;
  int chunk = b & 63, cog = (b >> 6) & 31, n = b >> 11;
  int t = threadIdx.x;
  int wo = t & 127, ho = chunk * 2 + (t >> 7);
  int co0 = cog * 4;
  const float* xb = xp + (size_t)n * 3 * 66564 + (size_t)(2 * ho) * 258 + 2 * wo;
  double acc[4] = {0.0, 0.0, 0.0, 0.0};
  for (int ci = 0; ci < 3; ++ci) {
    const float* xc = xb + (size_t)ci * 66564;
    float xv[16];
#pragma unroll
    for (int kh = 0; kh < 4; ++kh)
#pragma unroll
      for (int kw = 0; kw < 4; ++kw) xv[kh * 4 + kw] = xc[kh * 258 + kw];
#pragma unroll
    for (int cc = 0; cc < 4; ++cc) {
      const float* wp = w + (size_t)(co0 + cc) * 48 + ci * 16;
#pragma unroll
      for (int tp = 0; tp < 16; ++tp)
        acc[cc] = fma((double)xv[tp], (double)wp[tp], acc[cc]);
    }
  }
#pragma unroll
  for (int cc = 0; cc < 4; ++cc) {
    float r = (float)((double)bias[co0 + cc] + acc[cc]);
    h1p[(((size_t)n * 128 + co0 + cc) * 130 + ho + 1) * 130 + wo + 1] = fmaxf(r, 0.0f);
  }
}

// ---------- enc conv2: k=4 s=2 + ReLU, 128ci, co x4, f64 acc ----------
__global__ __launch_bounds__(256) void conv2_k(
    const float* __restrict__ h1p, const float* __restrict__ w,
    const float* __restrict__ bias, float* __restrict__ h2p) {
  int b = blockIdx.x;
  int chunk = b & 15, cog = (b >> 4) & 31, n = b >> 9;
  int t = threadIdx.x;
  int wo = t & 63, ho = chunk * 4 + (t >> 6);
  int co0 = cog * 4;
  const float* xb = h1p + (size_t)n * 128 * 16900 + (size_t)(2 * ho) * 130 + 2 * wo;
  double acc[4] = {0.0, 0.0, 0.0, 0.0};
  for (int ci = 0; ci < 128; ++ci) {
    const float* xc = xb + (size_t)ci * 16900;
    float xv[16];
#pragma unroll
    for (int kh = 0; kh < 4; ++kh)
#pragma unroll
      for (int kw = 0; kw < 4; ++kw) xv[kh * 4 + kw] = xc[kh * 130 + kw];
#pragma unroll
    for (int cc = 0; cc < 4; ++cc) {
      const float* wp = w + (size_t)(co0 + cc) * 2048 + ci * 16;
#pragma unroll
      for (int tp = 0; tp < 16; ++tp)
        acc[cc] = fma((double)xv[tp], (double)wp[tp], acc[cc]);
    }
  }
#pragma unroll
  for (int cc = 0; cc < 4; ++cc) {
    float r = (float)((double)bias[co0 + cc] + acc[cc]);
    h2p[(((size_t)n * 128 + co0 + cc) * 66 + ho + 1) * 66 + wo + 1] = fmaxf(r, 0.0f);
  }
}

// ---------- enc conv3: k=3 s=1 (no relu), co x4, f64 acc ----------
__global__ __launch_bounds__(256) void conv3_k(
    const float* __restrict__ h2p, const float* __restrict__ w,
    const float* __restrict__ bias, float* __restrict__ h3) {
  int b = blockIdx.x;
  int chunk = b & 15, cog = (b >> 4) & 31, n = b >> 9;
  int t = threadIdx.x;
  int wo = t & 63, ho = chunk * 4 + (t >> 6);
  int co0 = cog * 4;
  const float* xb = h2p + (size_t)n * 128 * 4356 + (size_t)ho * 66 + wo;
  double acc[4] = {0.0, 0.0, 0.0, 0.0};
  for (int ci = 0; ci < 128; ++ci) {
    const float* xc = xb + (size_t)ci * 4356;
    float xv[9];
#pragma unroll
    for (int kh = 0; kh < 3; ++kh)
#pragma unroll
      for (int kw = 0; kw < 3; ++kw) xv[kh * 3 + kw] = xc[kh * 66 + kw];
#pragma unroll
    for (int cc = 0; cc < 4; ++cc) {
      const float* wp = w + (size_t)(co0 + cc) * 1152 + ci * 9;
#pragma unroll
      for (int tp = 0; tp < 9; ++tp)
        acc[cc] = fma((double)xv[tp], (double)wp[tp], acc[cc]);
    }
  }
#pragma unroll
  for (int cc = 0; cc < 4; ++cc)
    h3[(((size_t)n * 128 + co0 + cc) << 12) + (ho << 6) + wo] =
        (float)((double)bias[co0 + cc] + acc[cc]);
}

// ---------- 1x1 conv 128->256, f64 acc, fp32 z transposed [p][256] ----------
__global__ __launch_bounds__(256) void qconv_z_pr_k(
    const float* __restrict__ h3, const float* __restrict__ w,
    const float* __restrict__ bias, float* __restrict__ zf) {
  int tid = blockIdx.x * 256 + threadIdx.x;  // p*256 + co
  int co = tid & 255;
  int p  = tid >> 8;
  int n  = p >> 12;
  int hw = p & 4095;
  const float* xp = h3 + ((size_t)n * 128) * 4096 + hw;
  const float* wp = w + (size_t)co * 128;
  double a[4] = {0.0, 0.0, 0.0, 0.0};
  for (int ci = 0; ci < 128; ci += 4) {
#pragma unroll
    for (int u = 0; u < 4; ++u)
      a[u] = fma((double)xp[(size_t)(ci + u) * 4096], (double)wp[ci + u], a[u]);
  }
  double acc = (double)bias[co] + ((a[0] + a[1]) + (a[2] + a[3]));
  zf[tid] = (float)acc;
}

// ---------- row norms: fl32( f64-sum of fl32(v^2) ) ----------
__global__ __launch_bounds__(256) void rownorm_k(const float* __restrict__ src,
                                                 float* __restrict__ dst) {
  int lane = threadIdx.x & 63;
  int r = blockIdx.x * 4 + (threadIdx.x >> 6);
  const float* v = src + (size_t)r * 256;
  double s = 0.0;
#pragma unroll
  for (int j = 0; j < 4; ++j) {
    float x = v[lane + (j << 6)];
    float xx = x * x;
    s += (double)xx;
  }
#pragma unroll
  for (int off = 32; off > 0; off >>= 1) s += __shfl_down(s, off, 64);
  if (lane == 0) dst[r] = (float)s;
}

// ---------- bf16 split builders: A' = [hi|hi|lo], B' = [hi|lo|hi] ----------
template<int MODE>
__global__ __launch_bounds__(256) void build_split_k(
    const float* __restrict__ src, short* __restrict__ dst) {
  int tid = blockIdx.x * 256 + threadIdx.x;
  int e = tid & 255, row = tid >> 8;
  float v = src[tid];
  unsigned short hi = f2bf(v);
  unsigned short lo = f2bf(v - bf2f(hi));
  short* d = dst + (size_t)row * 768;
  if (MODE == 0) { d[e] = (short)hi; d[256 + e] = (short)hi; d[512 + e] = (short)lo; }
  else           { d[e] = (short)hi; d[256 + e] = (short)lo; d[512 + e] = (short)hi; }
}

// ---------- VQ filter GEMM: 128x128 tile, 16x16x32 bf16 MFMA, K=768 ----------
__global__ __launch_bounds__(256, 2) void vq_gemm_k(
    const short* __restrict__ Ab, const short* __restrict__ Bb,
    const float* __restrict__ cnArr,
    int* __restrict__ cnt, int* __restrict__ cand) {
  __shared__ __align__(16) short As[128 * 32];
  __shared__ __align__(16) short Bs[128 * 32];
  __shared__ unsigned loc[128];
  const int t = threadIdx.x;
  const int w = t >> 6, L = t & 63;
  const int mb = blockIdx.x >> 6;
  const int nb = blockIdx.x & 63;
  const int m0 = mb << 7, n0 = nb << 7;
  if (t < 128) loc[t] = 0xFFFFFFFFu;
  f32x4 acc[4][4] = {};
  const int wr = (w >> 1) << 6, wc = (w & 1) << 6;
  const int srow = L >> 2, kg = L & 3;
  const int q = L >> 4, ln = L & 15;
  for (int kk = 0; kk < 768; kk += 32) {
    __syncthreads();
#pragma unroll
    for (int c = 0; c < 2; ++c) {
      const int row = (w << 5) + (c << 4) + srow;
      const bf16x8 av = *(const bf16x8*)(Ab + (size_t)(m0 + row) * 768 + kk + kg * 8);
      *(bf16x8*)(&As[row * 32 + kg * 8]) = av;
      const bf16x8 bv = *(const bf16x8*)(Bb + (size_t)(n0 + row) * 768 + kk + kg * 8);
      *(bf16x8*)(&Bs[row * 32 + kg * 8]) = bv;
    }
    __syncthreads();
    bf16x8 af[4], bf[4];
#pragma unroll
    for (int i = 0; i < 4; ++i)
      af[i] = *(const bf16x8*)(&As[(wr + 16 * i + ln) * 32 + q * 8]);
#pragma unroll
    for (int j = 0; j < 4; ++j)
      bf[j] = *(const bf16x8*)(&Bs[(wc + 16 * j + ln) * 32 + q * 8]);
#pragma unroll
    for (int i = 0; i < 4; ++i)
#pragma unroll
      for (int j = 0; j < 4; ++j)
        acc[i][j] = __builtin_amdgcn_mfma_f32_16x16x32_bf16(af[i], bf[j], acc[i][j], 0, 0, 0);
  }
  float cnv[4];
#pragma unroll
  for (int j = 0; j < 4; ++j) cnv[j] = cnArr[n0 + wc + 16 * j + ln];
#pragma unroll
  for (int i = 0; i < 4; ++i)
#pragma unroll
    for (int r = 0; r < 4; ++r) {
      float mn = 3.4e38f;
#pragma unroll
      for (int j = 0; j < 4; ++j) mn = fminf(mn, fmaf(-2.0f, acc[i][j][r], cnv[j]));
      atomicMin(&loc[wr + 16 * i + 4 * q + r], fkey(mn));
    }
  __syncthreads();
#pragma unroll
  for (int i = 0; i < 4; ++i)
#pragma unroll
    for (int r = 0; r < 4; ++r) {
      const int rib = wr + 16 * i + 4 * q + r;
      const float thr = funkey(loc[rib]) + VQ_MARGIN;
      const int p = m0 + rib;
#pragma unroll
      for (int j = 0; j < 4; ++j) {
        float s = fmaf(-2.0f, acc[i][j][r], cnv[j]);
        if (s <= thr) {
          int slot = atomicAdd(&cnt[p * 64 + nb], 1);
          if (slot < 2) cand[(size_t)p * 128 + nb * 2 + slot] = n0 + wc + 16 * j + ln;
        }
      }
    }
}

// ---------- VQ final: fp32-faithful d, lexicographic (d,k) argmin ----------
__global__ __launch_bounds__(256) void vq_phase3_k(
    const float* __restrict__ zf, const float* __restrict__ cb,
    const float* __restrict__ znArr, const float* __restrict__ cnArr,
    const int* __restrict__ cnt, const int* __restrict__ cand,
    int* __restrict__ idxOut) {
  const int lane = threadIdx.x & 63;
  const int r = blockIdx.x * 4 + (threadIdx.x >> 6);
  const float* zr = zf + (size_t)r * 256;
  double z4[4];
#pragma unroll
  for (int j = 0; j < 4; ++j) z4[j] = (double)zr[lane + (j << 6)];
  const float znr = znArr[r];
  float bestd = 3.4e38f;
  int bestk = 0x7fffffff;
  for (int nb = 0; nb < 64; ++nb) {
    const int c = cnt[r * 64 + nb];
    const int nsc = (c <= 2) ? c : 128;
    for (int s2 = 0; s2 < nsc; ++s2) {
      const int k = (c <= 2) ? cand[(size_t)r * 128 + nb * 2 + s2] : (nb * 128 + s2);
      const float* ck = cb + (size_t)k * 256;
      double p = 0.0;
#pragma unroll
      for (int j = 0; j < 4; ++j)
        p = fma(z4[j], (double)ck[lane + (j << 6)], p);
#pragma unroll
      for (int off = 32; off > 0; off >>= 1) p += __shfl_down(p, off, 64);
      if (lane == 0) {
        float mm2 = (float)(2.0 * p);
        float t1 = znr + cnArr[k];
        float d = t1 - mm2;
        if (d < bestd || (d == bestd && k < bestk)) { bestd = d; bestk = k; }
      }
    }
  }
  if (lane == 0) idxOut[r] = bestk;
}

// ---------- commit loss partials + indices-as-float output ----------
__global__ __launch_bounds__(256) void commit_k(
    const float* __restrict__ zf, const float* __restrict__ cb,
    const int* __restrict__ idxArr, float* __restrict__ accum,
    float* __restrict__ outIdxF) {
  __shared__ float wsum[4];
  const int p = blockIdx.x;
  const int t = threadIdx.x;
  const int k = idxArr[p];
  float d = cb[(size_t)k * 256 + t] - zf[(size_t)p * 256 + t];
  float v = d * d;
#pragma unroll
  for (int off = 32; off > 0; off >>= 1) v += __shfl_down(v, off, 64);
  if ((t & 63) == 0) wsum[t >> 6] = v;
  __syncthreads();
  if (t == 0) {
    atomicAdd(accum, wsum[0] + wsum[1] + wsum[2] + wsum[3]);
    outIdxF[p] = (float)k;
  }
}

__global__ void init_k(float* accum) { *accum = 0.0f; }
__global__ void fin_k(const float* __restrict__ accum, float* __restrict__ out) {
  *out = *accum * (1.0f / 4194304.0f);
}

// ---------- projected codebook PC[k][co] = sum_ci cb[k][ci]*pw[co][ci] ----------
__global__ __launch_bounds__(256) void pc_k(const float* __restrict__ cb,
                                            const float* __restrict__ pw,
                                            float* __restrict__ PC) {
  int tid = blockIdx.x * 256 + threadIdx.x;
  int co = tid & 127, k = tid >> 7;
  const float* c = cb + (size_t)k * 256;
  const float* w = pw + (size_t)co * 256;
  float a0 = 0.0f, a1 = 0.0f, a2 = 0.0f, a3 = 0.0f;
  for (int ci = 0; ci < 256; ci += 4) {
    a0 = fmaf(c[ci], w[ci], a0);
    a1 = fmaf(c[ci + 1], w[ci + 1], a1);
    a2 = fmaf(c[ci + 2], w[ci + 2], a2);
    a3 = fmaf(c[ci + 3], w[ci + 3], a3);
  }
  PC[tid] = (a0 + a1) + (a2 + a3);
}

// ---------- q = gather(PC, idx) + bias, padded NCHW [66][66] ----------
__global__ __launch_bounds__(256) void gather_pc_k(
    const float* __restrict__ PC, const int* __restrict__ idxArr,
    const float* __restrict__ pb, float* __restrict__ qp) {
  int tid = blockIdx.x * 256 + threadIdx.x;
  int hw = tid & 4095;
  int co = (tid >> 12) & 127;
  int n  = tid >> 19;
  int p  = (n << 12) + hw;
  int h = hw >> 6, w2 = hw & 63;
  qp[(((size_t)n * 128 + co) * 66 + h + 1) * 66 + w2 + 1] =
      PC[(size_t)idxArr[p] * 128 + co] + pb[co];
}

// ---------- dec conv1: fp32 k=3 s=1 + relu, co x4 ----------
__global__ __launch_bounds__(256) void dconv1_k(
    const float* __restrict__ qp, const float* __restrict__ w,
    const float* __restrict__ bias, float* __restrict__ d1p) {
  int b = blockIdx.x;
  int chunk = b & 15, cog = (b >> 4) & 31, n = b >> 9;
  int t = threadIdx.x;
  int wo = t & 63, ho = chunk * 4 + (t >> 6);
  int co0 = cog * 4;
  const float* xb = qp + (size_t)n * 128 * 4356 + (size_t)ho * 66 + wo;
  float acc[4] = {0.0f, 0.0f, 0.0f, 0.0f};
  for (int ci = 0; ci < 128; ++ci) {
    const float* xc = xb + (size_t)ci * 4356;
    float xv[9];
#pragma unroll
    for (int kh = 0; kh < 3; ++kh)
#pragma unroll
      for (int kw = 0; kw < 3; ++kw) xv[kh * 3 + kw] = xc[kh * 66 + kw];
#pragma unroll
    for (int cc = 0; cc < 4; ++cc) {
      const float* wp = w + (size_t)(co0 + cc) * 1152 + ci * 9;
#pragma unroll
      for (int tp = 0; tp < 9; ++tp)
        acc[cc] = fmaf(xv[tp], wp[tp], acc[cc]);
    }
  }
#pragma unroll
  for (int cc = 0; cc < 4; ++cc)
    d1p[(((size_t)n * 128 + co0 + cc) * 66 + ho + 1) * 66 + wo + 1] =
        fmaxf(bias[co0 + cc] + acc[cc], 0.0f);
}

// ---------- convt2 weight reshape: [ci][co][16] -> wr2[cls][co][ci][4] ----------
__global__ __launch_bounds__(256) void wresh2_k(const float* __restrict__ w,
                                                float* __restrict__ wr) {
  int tid = blockIdx.x * 256 + threadIdx.x;   // cls*128co*128ci
  int ci = tid & 127, co = (tid >> 7) & 127, cls = tid >> 14;
  int cph = cls >> 1, cpw = cls & 1;
  int kh0 = 1 - cph, kw0 = 1 - cpw;
  const float* s = w + ((size_t)ci * 128 + co) * 16;
  float* d = wr + (size_t)tid * 4;
  d[0] = s[kh0 * 4 + kw0];
  d[1] = s[kh0 * 4 + kw0 + 2];
  d[2] = s[(kh0 + 2) * 4 + kw0];
  d[3] = s[(kh0 + 2) * 4 + kw0 + 2];
}

// ---------- convt3 weight reshape: [ci][3][16] -> wr3[cls][co][ci][4] ----------
__global__ __launch_bounds__(256) void wresh3_k(const float* __restrict__ w,
                                                float* __restrict__ wr) {
  int tid = blockIdx.x * 256 + threadIdx.x;   // cls*3co*128ci = 1536
  if (tid >= 1536) return;
  int ci = tid & 127, co = (tid >> 7) % 3, cls = tid / 384;
  int cph = cls >> 1, cpw = cls & 1;
  int kh0 = 1 - cph, kw0 = 1 - cpw;
  const float* s = w + ((size_t)ci * 3 + co) * 16;
  float* d = wr + (size_t)tid * 4;
  d[0] = s[kh0 * 4 + kw0];
  d[1] = s[kh0 * 4 + kw0 + 2];
  d[2] = s[(kh0 + 2) * 4 + kw0];
  d[3] = s[(kh0 + 2) * 4 + kw0 + 2];
}

// ---------- convt2: parity-specialized, co x4, in d1p[66], out d2p[130] ----------
__global__ __launch_bounds__(256) void convt2_k(
    const float* __restrict__ xp, const float* __restrict__ wr,
    const float* __restrict__ bias, float* __restrict__ y) {
  int b = blockIdx.x;
  int chunk = b & 15, cls = (b >> 4) & 3, cog = (b >> 6) & 31, n = b >> 11;
  int cph = cls >> 1, cpw = cls & 1;
  int t = threadIdx.x;
  int wb = t & 63, i = chunk * 4 + (t >> 6);
  int co0 = cog * 4;
  int ho = 2 * i + cph, wo = 2 * wb + cpw;
  int r0 = i + 1 + cph, r1 = r0 - 1;
  int c0 = wb + 1 + cpw, c1 = c0 - 1;
  const float* xb = xp + (size_t)n * 128 * 4356;
  float acc[4] = {0.0f, 0.0f, 0.0f, 0.0f};
  for (int ci = 0; ci < 128; ++ci) {
    const float* xc = xb + (size_t)ci * 4356;
    float x00 = xc[r0 * 66 + c0], x01 = xc[r0 * 66 + c1];
    float x10 = xc[r1 * 66 + c0], x11 = xc[r1 * 66 + c1];
#pragma unroll
    for (int cc = 0; cc < 4; ++cc) {
      const float* w4 = wr + (((size_t)cls * 128 + co0 + cc) * 128 + ci) * 4;
      acc[cc] = fmaf(x00, w4[0], acc[cc]);
      acc[cc] = fmaf(x01, w4[1], acc[cc]);
      acc[cc] = fmaf(x10, w4[2], acc[cc]);
      acc[cc] = fmaf(x11, w4[3], acc[cc]);
    }
  }
#pragma unroll
  for (int cc = 0; cc < 4; ++cc)
    y[(((size_t)n * 128 + co0 + cc) * 130 + ho + 1) * 130 + wo + 1] =
        fmaxf(bias[co0 + cc] + acc[cc], 0.0f);
}

// ---------- convt3: parity-specialized, 3 co per thread, in d2p[130] ----------
__global__ __launch_bounds__(256) void convt3_k(
    const float* __restrict__ xp, const float* __restrict__ wr,
    const float* __restrict__ bias, float* __restrict__ y) {
  int b = blockIdx.x;
  int chunk = b & 63, cls = (b >> 6) & 3, n = b >> 8;
  int cph = cls >> 1, cpw = cls & 1;
  int t = threadIdx.x;
  int wb = t & 127, i = chunk * 2 + (t >> 7);
  int ho = 2 * i + cph, wo = 2 * wb + cpw;
  int r0 = i + 1 + cph, r1 = r0 - 1;
  int c0 = wb + 1 + cpw, c1 = c0 - 1;
  const float* xb = xp + (size_t)n * 128 * 16900;
  float acc[3] = {0.0f, 0.0f, 0.0f};
  for (int ci = 0; ci < 128; ++ci) {
    const float* xc = xb + (size_t)ci * 16900;
    float x00 = xc[r0 * 130 + c0], x01 = xc[r0 * 130 + c1];
    float x10 = xc[r1 * 130 + c0], x11 = xc[r1 * 130 + c1];
#pragma unroll
    for (int cc = 0; cc < 3; ++cc) {
      const float* w4 = wr + (((size_t)cls * 3 + cc) * 128 + ci) * 4;
      acc[cc] = fmaf(x00, w4[0], acc[cc]);
      acc[cc] = fmaf(x01, w4[1], acc[cc]);
      acc[cc] = fmaf(x10, w4[2], acc[cc]);
      acc[cc] = fmaf(x11, w4[3], acc[cc]);
    }
  }
#pragma unroll
  for (int cc = 0; cc < 3; ++cc)
    y[(((size_t)n * 3 + cc) << 16) + (ho << 8) + wo] = bias[cc] + acc[cc];
}

// ---------------------------------------------------------------------------
extern "C" void kernel_launch(void* const* d_in, const int* in_sizes, int n_in,
                              void* d_out, int out_size, void* d_ws, size_t ws_size,
                              hipStream_t stream) {
  const float* x    = (const float*)d_in[0];
  const float* ew1  = (const float*)d_in[1];
  const float* eb1  = (const float*)d_in[2];
  const float* ew2  = (const float*)d_in[3];
  const float* eb2  = (const float*)d_in[4];
  const float* ew3  = (const float*)d_in[5];
  const float* eb3  = (const float*)d_in[6];
  const float* qw   = (const float*)d_in[7];
  const float* qb   = (const float*)d_in[8];
  const float* cb   = (const float*)d_in[9];
  const float* pw   = (const float*)d_in[10];
  const float* pb   = (const float*)d_in[11];
  const float* dw1  = (const float*)d_in[12];
  const float* db1  = (const float*)d_in[13];
  const float* dtw2 = (const float*)d_in[14];
  const float* dtb2 = (const float*)d_in[15];
  const float* dtw3 = (const float*)d_in[16];
  const float* dtb3 = (const float*)d_in[17];

  char* wsb = (char*)d_ws;
  float* h1p  = (float*)(wsb + OFF_A);
  short* Ap   = (short*)(wsb + OFF_A);
  float* d2p  = (float*)(wsb + OFF_A);
  float* h2p  = (float*)(wsb + OFF_B);
  int*   cand = (int*)(wsb + OFF_B);
  float* qbufp= (float*)(wsb + OFF_B);
  float* xpad = (float*)(wsb + OFF_C);
  float* h3   = (float*)(wsb + OFF_C);
  int*   cntb = (int*)(wsb + OFF_C);
  float* d1p  = (float*)(wsb + OFF_C);
  float* zff  = (float*)(wsb + OFF_D);
  short* Bp   = (short*)(wsb + OFF_E);
  float* PC   = (float*)(wsb + OFF_E);
  float* znb  = (float*)(wsb + OFF_ZN);
  float* cnb  = (float*)(wsb + OFF_CN);
  int*   idxb = (int*)(wsb + OFF_IDX);
  float* accum= (float*)(wsb + OFF_ACC);
  float* wr2  = (float*)(wsb + OFF_WR2);
  float* wr3  = (float*)(wsb + OFF_WR3);

  float* out      = (float*)d_out;
  float* outLoss  = out + 786432;
  float* outIdxF  = out + 786433;

  // zero pads + weight reshapes (independent of encoder chain)
  hipMemsetAsync((void*)h1p,  0, 34611200, stream);
  hipMemsetAsync((void*)h2p,  0, 8921088,  stream);
  hipMemsetAsync((void*)xpad, 0, 3195072,  stream);
  hipLaunchKernelGGL(wresh2_k, dim3(256), dim3(256), 0, stream, dtw2, wr2);
  hipLaunchKernelGGL(wresh3_k, dim3(6),   dim3(256), 0, stream, dtw3, wr3);

  // encoder: per-op fp32-rounded (f64-exact inside each op)
  hipLaunchKernelGGL(padx_k,       dim3(3072),  dim3(256), 0, stream, x, xpad);
  hipLaunchKernelGGL(conv1_k,      dim3(8192),  dim3(256), 0, stream, xpad, ew1, eb1, h1p);
  hipLaunchKernelGGL(conv2_k,      dim3(2048),  dim3(256), 0, stream, h1p, ew2, eb2, h2p);
  hipLaunchKernelGGL(conv3_k,      dim3(2048),  dim3(256), 0, stream, h2p, ew3, eb3, h3);
  hipLaunchKernelGGL(qconv_z_pr_k, dim3(16384), dim3(256), 0, stream, h3, qw, qb, zff);

  // VQ: bf16-split MFMA filter + exact fp32-faithful rescore
  hipLaunchKernelGGL(rownorm_k,          dim3(4096),  dim3(256), 0, stream, zff, znb);
  hipLaunchKernelGGL(rownorm_k,          dim3(2048),  dim3(256), 0, stream, cb, cnb);
  hipLaunchKernelGGL((build_split_k<0>), dim3(16384), dim3(256), 0, stream, zff, Ap);
  hipLaunchKernelGGL((build_split_k<1>), dim3(8192),  dim3(256), 0, stream, cb, Bp);
  hipMemsetAsync((void*)cntb, 0, (size_t)16384 * 64 * 4, stream);
  hipLaunchKernelGGL(vq_gemm_k,   dim3(8192),  dim3(256), 0, stream, Ap, Bp, cnb, cntb, cand);
  hipLaunchKernelGGL(vq_phase3_k, dim3(4096),  dim3(256), 0, stream, zff, cb, znb, cnb, cntb, cand, idxb);
  hipLaunchKernelGGL(init_k,      dim3(1),     dim3(1),   0, stream, accum);
  hipLaunchKernelGGL(commit_k,    dim3(16384), dim3(256), 0, stream, zff, cb, idxb, accum, outIdxF);
  hipLaunchKernelGGL(fin_k,       dim3(1),     dim3(1),   0, stream, accum, outLoss);

  // decoder fp32 (pqconv folded through codebook: q = PC[idx] + b)
  hipLaunchKernelGGL(pc_k, dim3(4096), dim3(256), 0, stream, cb, pw, PC);
  hipMemsetAsync((void*)qbufp, 0, 8921088,  stream);   // cand dead after phase3
  hipMemsetAsync((void*)d1p,   0, 8921088,  stream);   // cnt dead after phase3
  hipMemsetAsync((void*)d2p,   0, 34611200, stream);   // Ap dead after vq_gemm
  hipLaunchKernelGGL(gather_pc_k, dim3(8192),  dim3(256), 0, stream, PC, idxb, pb, qbufp);
  hipLaunchKernelGGL(dconv1_k,    dim3(2048),  dim3(256), 0, stream, qbufp, dw1, db1, d1p);
  hipLaunchKernelGGL(convt2_k,    dim3(8192),  dim3(256), 0, stream, d1p, dtw2 ? wr2 : wr2, dtb2, d2p);
  hipLaunchKernelGGL(convt3_k,    dim3(1024),  dim3(256), 0, stream, d2p, wr3, dtb3, out);
}

// Round 7
// 1874.533 us; speedup vs baseline: 4.2730x; 1.5815x over previous
//
#include <hip/hip_runtime.h>

// ---------------------------------------------------------------------------
// VQ-VAE forward, round 7: phase3 block-min pruning (bmin array) + transposed
// qconv weights. Numerics contract (validated r3-r6): every reference op =
// fl32(f64-exact op on fp32 operands); d in fp32; first-index argmin.
//
// d_out (float32): recon[786432] | commit_loss[1] | indices[16384]
//
// Workspace regions (BYTE offsets), total ~83.2 MB:
//  A [0,34.61M):      h1p f32[4][128][130][130] -> Ap bf16[16384][768] -> d2p
//  B [34.61M,43.53M): h2p f32[4][128][66][66]   -> cand i32[16384][64][2] -> qbufp
//  C [43.53M,52.45M): xpad f32[4][3][258][258] -> h3 f32[4][128][64][64]
//                      -> {cnt i32[16384][64] | bmin f32[16384][64]} -> d1p
//  D [52.45M,69.23M): zf f32[16384][256]
//  E [69.23M,81.81M): Bp bf16[8192][768] -> PC f32[8192][128]
//  tail: zn, cn, idx, acc, wr2 (1MB), wr3 (24KB), qwT (128KB)
#define OFF_A    ((size_t)0)
#define OFF_B    ((size_t)34611200)
#define OFF_C    ((size_t)43532288)
#define OFF_BMIN ((size_t)47726592)   // OFF_C + 4 MB
#define OFF_D    ((size_t)52453376)
#define OFF_E    ((size_t)69230592)
#define OFF_ZN   ((size_t)81813504)
#define OFF_CN   ((size_t)81879040)
#define OFF_IDX  ((size_t)81911808)
#define OFF_ACC  ((size_t)81977344)
#define OFF_WR2  ((size_t)81977600)
#define OFF_WR3  ((size_t)83026176)
#define OFF_QWT  ((size_t)83050752)

#define VQ_MARGIN 6e-5f

typedef __attribute__((ext_vector_type(8))) short bf16x8;
typedef __attribute__((ext_vector_type(4))) float f32x4;

// ---------- helpers ----------
__device__ __forceinline__ unsigned short f2bf(float f) {
  unsigned u = __float_as_uint(f);
  u += 0x7FFFu + ((u >> 16) & 1u);
  return (unsigned short)(u >> 16);
}
__device__ __forceinline__ float bf2f(unsigned short h) {
  return __uint_as_float(((unsigned)h) << 16);
}
__device__ __forceinline__ unsigned fkey(float f) {
  unsigned u = __float_as_uint(f);
  return (u & 0x80000000u) ? ~u : (u | 0x80000000u);
}
__device__ __forceinline__ float funkey(unsigned k) {
  unsigned u = (k & 0x80000000u) ? (k ^ 0x80000000u) : ~k;
  return __uint_as_float(u);
}

// ---------- pad-copy x into [4][3][258][258] ----------
__global__ __launch_bounds__(256) void padx_k(const float* __restrict__ x,
                                              float* __restrict__ xp) {
  int tid = blockIdx.x * 256 + threadIdx.x;
  int wo = tid & 255, ho = (tid >> 8) & 255, c = tid >> 16;
  xp[((size_t)c * 258 + ho + 1) * 258 + wo + 1] = x[tid];
}

// ---------- enc conv1: k=4 s=2 + ReLU, 3ci, co x4, f64 acc ----------
__global__ __launch_bounds__(256) void conv1_k(
    const float* __restrict__ xp, const float* __restrict__ w,
    const float* __restrict__ bias, float* __restrict__ h1p) {
  int b = blockIdx.x;
  int chunk = b & 63, cog = (b >> 6) & 31, n = b >> 11;
  int t = threadIdx.x;
  int wo = t & 127, ho = chunk * 2 + (t >> 7);
  int co0 = cog * 4;
  const float* xb = xp + (size_t)n * 3 * 66564 + (size_t)(2 * ho) * 258 + 2 * wo;
  double acc[4] = {0.0, 0.0, 0.0, 0.0};
  for (int ci = 0; ci < 3; ++ci) {
    const float* xc = xb + (size_t)ci * 66564;
    float xv[16];
#pragma unroll
    for (int kh = 0; kh < 4; ++kh)
#pragma unroll
      for (int kw = 0; kw < 4; ++kw) xv[kh * 4 + kw] = xc[kh * 258 + kw];
#pragma unroll
    for (int cc = 0; cc < 4; ++cc) {
      const float* wp = w + (size_t)(co0 + cc) * 48 + ci * 16;
#pragma unroll
      for (int tp = 0; tp < 16; ++tp)
        acc[cc] = fma((double)xv[tp], (double)wp[tp], acc[cc]);
    }
  }
#pragma unroll
  for (int cc = 0; cc < 4; ++cc) {
    float r = (float)((double)bias[co0 + cc] + acc[cc]);
    h1p[(((size_t)n * 128 + co0 + cc) * 130 + ho + 1) * 130 + wo + 1] = fmaxf(r, 0.0f);
  }
}

// ---------- enc conv2: k=4 s=2 + ReLU, 128ci, co x4, f64 acc ----------
__global__ __launch_bounds__(256) void conv2_k(
    const float* __restrict__ h1p, const float* __restrict__ w,
    const float* __restrict__ bias, float* __restrict__ h2p) {
  int b = blockIdx.x;
  int chunk = b & 15, cog = (b >> 4) & 31, n = b >> 9;
  int t = threadIdx.x;
  int wo = t & 63, ho = chunk * 4 + (t >> 6);
  int co0 = cog * 4;
  const float* xb = h1p + (size_t)n * 128 * 16900 + (size_t)(2 * ho) * 130 + 2 * wo;
  double acc[4] = {0.0, 0.0, 0.0, 0.0};
  for (int ci = 0; ci < 128; ++ci) {
    const float* xc = xb + (size_t)ci * 16900;
    float xv[16];
#pragma unroll
    for (int kh = 0; kh < 4; ++kh)
#pragma unroll
      for (int kw = 0; kw < 4; ++kw) xv[kh * 4 + kw] = xc[kh * 130 + kw];
#pragma unroll
    for (int cc = 0; cc < 4; ++cc) {
      const float* wp = w + (size_t)(co0 + cc) * 2048 + ci * 16;
#pragma unroll
      for (int tp = 0; tp < 16; ++tp)
        acc[cc] = fma((double)xv[tp], (double)wp[tp], acc[cc]);
    }
  }
#pragma unroll
  for (int cc = 0; cc < 4; ++cc) {
    float r = (float)((double)bias[co0 + cc] + acc[cc]);
    h2p[(((size_t)n * 128 + co0 + cc) * 66 + ho + 1) * 66 + wo + 1] = fmaxf(r, 0.0f);
  }
}

// ---------- enc conv3: k=3 s=1 (no relu), co x4, f64 acc ----------
__global__ __launch_bounds__(256) void conv3_k(
    const float* __restrict__ h2p, const float* __restrict__ w,
    const float* __restrict__ bias, float* __restrict__ h3) {
  int b = blockIdx.x;
  int chunk = b & 15, cog = (b >> 4) & 31, n = b >> 9;
  int t = threadIdx.x;
  int wo = t & 63, ho = chunk * 4 + (t >> 6);
  int co0 = cog * 4;
  const float* xb = h2p + (size_t)n * 128 * 4356 + (size_t)ho * 66 + wo;
  double acc[4] = {0.0, 0.0, 0.0, 0.0};
  for (int ci = 0; ci < 128; ++ci) {
    const float* xc = xb + (size_t)ci * 4356;
    float xv[9];
#pragma unroll
    for (int kh = 0; kh < 3; ++kh)
#pragma unroll
      for (int kw = 0; kw < 3; ++kw) xv[kh * 3 + kw] = xc[kh * 66 + kw];
#pragma unroll
    for (int cc = 0; cc < 4; ++cc) {
      const float* wp = w + (size_t)(co0 + cc) * 1152 + ci * 9;
#pragma unroll
      for (int tp = 0; tp < 9; ++tp)
        acc[cc] = fma((double)xv[tp], (double)wp[tp], acc[cc]);
    }
  }
#pragma unroll
  for (int cc = 0; cc < 4; ++cc)
    h3[(((size_t)n * 128 + co0 + cc) << 12) + (ho << 6) + wo] =
        (float)((double)bias[co0 + cc] + acc[cc]);
}

// ---------- qconv weight transpose: qw[co][ci] -> qwT[ci][co] ----------
__global__ __launch_bounds__(256) void qwT_k(const float* __restrict__ qw,
                                             float* __restrict__ wT) {
  int tid = blockIdx.x * 256 + threadIdx.x;  // 32768
  int co = tid & 255, ci = tid >> 8;
  wT[(size_t)ci * 256 + co] = qw[(size_t)co * 128 + ci];
}

// ---------- 1x1 conv 128->256, f64 acc, coalesced wT, z transposed [p][256] ----------
__global__ __launch_bounds__(256) void qconv_z_pr_k(
    const float* __restrict__ h3, const float* __restrict__ wT,
    const float* __restrict__ bias, float* __restrict__ zf) {
  int p  = blockIdx.x;               // one spatial position per block
  int co = threadIdx.x;              // 256 output channels
  int n  = p >> 12;
  int hw = p & 4095;
  const float* xp = h3 + ((size_t)n * 128) * 4096 + hw;
  double a[4] = {0.0, 0.0, 0.0, 0.0};
  for (int ci = 0; ci < 128; ci += 4) {
#pragma unroll
    for (int u = 0; u < 4; ++u) {
      float xv = xp[(size_t)(ci + u) * 4096];          // wave-uniform broadcast
      a[u] = fma((double)xv, (double)wT[(size_t)(ci + u) * 256 + co], a[u]);
    }
  }
  double acc = (double)bias[co] + ((a[0] + a[1]) + (a[2] + a[3]));
  zf[(size_t)p * 256 + co] = (float)acc;
}

// ---------- row norms: fl32( f64-sum of fl32(v^2) ) ----------
__global__ __launch_bounds__(256) void rownorm_k(const float* __restrict__ src,
                                                 float* __restrict__ dst) {
  int lane = threadIdx.x & 63;
  int r = blockIdx.x * 4 + (threadIdx.x >> 6);
  const float* v = src + (size_t)r * 256;
  double s = 0.0;
#pragma unroll
  for (int j = 0; j < 4; ++j) {
    float x = v[lane + (j << 6)];
    float xx = x * x;
    s += (double)xx;
  }
#pragma unroll
  for (int off = 32; off > 0; off >>= 1) s += __shfl_down(s, off, 64);
  if (lane == 0) dst[r] = (float)s;
}

// ---------- bf16 split builders: A' = [hi|hi|lo], B' = [hi|lo|hi] ----------
template<int MODE>
__global__ __launch_bounds__(256) void build_split_k(
    const float* __restrict__ src, short* __restrict__ dst) {
  int tid = blockIdx.x * 256 + threadIdx.x;
  int e = tid & 255, row = tid >> 8;
  float v = src[tid];
  unsigned short hi = f2bf(v);
  unsigned short lo = f2bf(v - bf2f(hi));
  short* d = dst + (size_t)row * 768;
  if (MODE == 0) { d[e] = (short)hi; d[256 + e] = (short)hi; d[512 + e] = (short)lo; }
  else           { d[e] = (short)hi; d[256 + e] = (short)lo; d[512 + e] = (short)hi; }
}

// ---------- VQ filter GEMM: 128x128 tile, 16x16x32 bf16 MFMA, K=768 ----------
// Writes per-(row, col-block) local min to bmin for phase-3 pruning.
__global__ __launch_bounds__(256, 2) void vq_gemm_k(
    const short* __restrict__ Ab, const short* __restrict__ Bb,
    const float* __restrict__ cnArr,
    int* __restrict__ cnt, int* __restrict__ cand, float* __restrict__ bmin) {
  __shared__ __align__(16) short As[128 * 32];
  __shared__ __align__(16) short Bs[128 * 32];
  __shared__ unsigned loc[128];
  const int t = threadIdx.x;
  const int w = t >> 6, L = t & 63;
  const int mb = blockIdx.x >> 6;
  const int nb = blockIdx.x & 63;
  const int m0 = mb << 7, n0 = nb << 7;
  if (t < 128) loc[t] = 0xFFFFFFFFu;
  f32x4 acc[4][4] = {};
  const int wr = (w >> 1) << 6, wc = (w & 1) << 6;
  const int srow = L >> 2, kg = L & 3;
  const int q = L >> 4, ln = L & 15;
  for (int kk = 0; kk < 768; kk += 32) {
    __syncthreads();
#pragma unroll
    for (int c = 0; c < 2; ++c) {
      const int row = (w << 5) + (c << 4) + srow;
      const bf16x8 av = *(const bf16x8*)(Ab + (size_t)(m0 + row) * 768 + kk + kg * 8);
      *(bf16x8*)(&As[row * 32 + kg * 8]) = av;
      const bf16x8 bv = *(const bf16x8*)(Bb + (size_t)(n0 + row) * 768 + kk + kg * 8);
      *(bf16x8*)(&Bs[row * 32 + kg * 8]) = bv;
    }
    __syncthreads();
    bf16x8 af[4], bf[4];
#pragma unroll
    for (int i = 0; i < 4; ++i)
      af[i] = *(const bf16x8*)(&As[(wr + 16 * i + ln) * 32 + q * 8]);
#pragma unroll
    for (int j = 0; j < 4; ++j)
      bf[j] = *(const bf16x8*)(&Bs[(wc + 16 * j + ln) * 32 + q * 8]);
#pragma unroll
    for (int i = 0; i < 4; ++i)
#pragma unroll
      for (int j = 0; j < 4; ++j)
        acc[i][j] = __builtin_amdgcn_mfma_f32_16x16x32_bf16(af[i], bf[j], acc[i][j], 0, 0, 0);
  }
  float cnv[4];
#pragma unroll
  for (int j = 0; j < 4; ++j) cnv[j] = cnArr[n0 + wc + 16 * j + ln];
#pragma unroll
  for (int i = 0; i < 4; ++i)
#pragma unroll
    for (int r = 0; r < 4; ++r) {
      float mn = 3.4e38f;
#pragma unroll
      for (int j = 0; j < 4; ++j) mn = fminf(mn, fmaf(-2.0f, acc[i][j][r], cnv[j]));
      atomicMin(&loc[wr + 16 * i + 4 * q + r], fkey(mn));
    }
  __syncthreads();
  if (t < 128) bmin[(size_t)(m0 + t) * 64 + nb] = funkey(loc[t]);
#pragma unroll
  for (int i = 0; i < 4; ++i)
#pragma unroll
    for (int r = 0; r < 4; ++r) {
      const int rib = wr + 16 * i + 4 * q + r;
      const float thr = funkey(loc[rib]) + VQ_MARGIN;
      const int p = m0 + rib;
#pragma unroll
      for (int j = 0; j < 4; ++j) {
        float s = fmaf(-2.0f, acc[i][j][r], cnv[j]);
        if (s <= thr) {
          int slot = atomicAdd(&cnt[p * 64 + nb], 1);
          if (slot < 2) cand[(size_t)p * 128 + nb * 2 + slot] = n0 + wc + 16 * j + ln;
        }
      }
    }
}

// ---------- VQ final: bmin-pruned, fp32-faithful d, lexicographic argmin ----------
__global__ __launch_bounds__(256) void vq_phase3_k(
    const float* __restrict__ zf, const float* __restrict__ cb,
    const float* __restrict__ znArr, const float* __restrict__ cnArr,
    const float* __restrict__ bmin, const int* __restrict__ cnt,
    const int* __restrict__ cand, int* __restrict__ idxOut) {
  const int lane = threadIdx.x & 63;
  const int r = blockIdx.x * 4 + (threadIdx.x >> 6);
  const float* zr = zf + (size_t)r * 256;
  double z4[4];
#pragma unroll
  for (int j = 0; j < 4; ++j) z4[j] = (double)zr[lane + (j << 6)];
  const float znr = znArr[r];
  // global row-min from the 64 per-block minima
  float bv = bmin[(size_t)r * 64 + lane];
  float m = bv;
#pragma unroll
  for (int off = 32; off > 0; off >>= 1) m = fminf(m, __shfl_down(m, off, 64));
  m = __shfl(m, 0, 64);
  const float thr = m + VQ_MARGIN;
  unsigned long long mask = __ballot(bv <= thr);
  float bestd = 3.4e38f;
  int bestk = 0x7fffffff;
  while (mask) {
    const int nb = (int)__builtin_ctzll(mask);
    mask &= mask - 1;
    const int c = cnt[r * 64 + nb];
    const int nsc = (c <= 2) ? c : 128;
    for (int s2 = 0; s2 < nsc; ++s2) {
      const int k = (c <= 2) ? cand[(size_t)r * 128 + nb * 2 + s2] : (nb * 128 + s2);
      const float* ck = cb + (size_t)k * 256;
      double p = 0.0;
#pragma unroll
      for (int j = 0; j < 4; ++j)
        p = fma(z4[j], (double)ck[lane + (j << 6)], p);
#pragma unroll
      for (int off = 32; off > 0; off >>= 1) p += __shfl_down(p, off, 64);
      if (lane == 0) {
        float mm2 = (float)(2.0 * p);
        float t1 = znr + cnArr[k];
        float d = t1 - mm2;
        if (d < bestd || (d == bestd && k < bestk)) { bestd = d; bestk = k; }
      }
    }
  }
  if (lane == 0) idxOut[r] = bestk;
}

// ---------- commit loss partials + indices-as-float output ----------
__global__ __launch_bounds__(256) void commit_k(
    const float* __restrict__ zf, const float* __restrict__ cb,
    const int* __restrict__ idxArr, float* __restrict__ accum,
    float* __restrict__ outIdxF) {
  __shared__ float wsum[4];
  const int p = blockIdx.x;
  const int t = threadIdx.x;
  const int k = idxArr[p];
  float d = cb[(size_t)k * 256 + t] - zf[(size_t)p * 256 + t];
  float v = d * d;
#pragma unroll
  for (int off = 32; off > 0; off >>= 1) v += __shfl_down(v, off, 64);
  if ((t & 63) == 0) wsum[t >> 6] = v;
  __syncthreads();
  if (t == 0) {
    atomicAdd(accum, wsum[0] + wsum[1] + wsum[2] + wsum[3]);
    outIdxF[p] = (float)k;
  }
}

__global__ void init_k(float* accum) { *accum = 0.0f; }
__global__ void fin_k(const float* __restrict__ accum, float* __restrict__ out) {
  *out = *accum * (1.0f / 4194304.0f);
}

// ---------- projected codebook PC[k][co] = sum_ci cb[k][ci]*pw[co][ci] ----------
__global__ __launch_bounds__(256) void pc_k(const float* __restrict__ cb,
                                            const float* __restrict__ pw,
                                            float* __restrict__ PC) {
  int tid = blockIdx.x * 256 + threadIdx.x;
  int co = tid & 127, k = tid >> 7;
  const float* c = cb + (size_t)k * 256;
  const float* w = pw + (size_t)co * 256;
  float a0 = 0.0f, a1 = 0.0f, a2 = 0.0f, a3 = 0.0f;
  for (int ci = 0; ci < 256; ci += 4) {
    a0 = fmaf(c[ci], w[ci], a0);
    a1 = fmaf(c[ci + 1], w[ci + 1], a1);
    a2 = fmaf(c[ci + 2], w[ci + 2], a2);
    a3 = fmaf(c[ci + 3], w[ci + 3], a3);
  }
  PC[tid] = (a0 + a1) + (a2 + a3);
}

// ---------- q = gather(PC, idx) + bias, padded NCHW [66][66] ----------
__global__ __launch_bounds__(256) void gather_pc_k(
    const float* __restrict__ PC, const int* __restrict__ idxArr,
    const float* __restrict__ pb, float* __restrict__ qp) {
  int tid = blockIdx.x * 256 + threadIdx.x;
  int hw = tid & 4095;
  int co = (tid >> 12) & 127;
  int n  = tid >> 19;
  int p  = (n << 12) + hw;
  int h = hw >> 6, w2 = hw & 63;
  qp[(((size_t)n * 128 + co) * 66 + h + 1) * 66 + w2 + 1] =
      PC[(size_t)idxArr[p] * 128 + co] + pb[co];
}

// ---------- dec conv1: fp32 k=3 s=1 + relu, co x4 ----------
__global__ __launch_bounds__(256) void dconv1_k(
    const float* __restrict__ qp, const float* __restrict__ w,
    const float* __restrict__ bias, float* __restrict__ d1p) {
  int b = blockIdx.x;
  int chunk = b & 15, cog = (b >> 4) & 31, n = b >> 9;
  int t = threadIdx.x;
  int wo = t & 63, ho = chunk * 4 + (t >> 6);
  int co0 = cog * 4;
  const float* xb = qp + (size_t)n * 128 * 4356 + (size_t)ho * 66 + wo;
  float acc[4] = {0.0f, 0.0f, 0.0f, 0.0f};
  for (int ci = 0; ci < 128; ++ci) {
    const float* xc = xb + (size_t)ci * 4356;
    float xv[9];
#pragma unroll
    for (int kh = 0; kh < 3; ++kh)
#pragma unroll
      for (int kw = 0; kw < 3; ++kw) xv[kh * 3 + kw] = xc[kh * 66 + kw];
#pragma unroll
    for (int cc = 0; cc < 4; ++cc) {
      const float* wp = w + (size_t)(co0 + cc) * 1152 + ci * 9;
#pragma unroll
      for (int tp = 0; tp < 9; ++tp)
        acc[cc] = fmaf(xv[tp], wp[tp], acc[cc]);
    }
  }
#pragma unroll
  for (int cc = 0; cc < 4; ++cc)
    d1p[(((size_t)n * 128 + co0 + cc) * 66 + ho + 1) * 66 + wo + 1] =
        fmaxf(bias[co0 + cc] + acc[cc], 0.0f);
}

// ---------- convt2 weight reshape: [ci][co][16] -> wr2[cls][co][ci][4] ----------
__global__ __launch_bounds__(256) void wresh2_k(const float* __restrict__ w,
                                                float* __restrict__ wr) {
  int tid = blockIdx.x * 256 + threadIdx.x;
  int ci = tid & 127, co = (tid >> 7) & 127, cls = tid >> 14;
  int cph = cls >> 1, cpw = cls & 1;
  int kh0 = 1 - cph, kw0 = 1 - cpw;
  const float* s = w + ((size_t)ci * 128 + co) * 16;
  float* d = wr + (size_t)tid * 4;
  d[0] = s[kh0 * 4 + kw0];
  d[1] = s[kh0 * 4 + kw0 + 2];
  d[2] = s[(kh0 + 2) * 4 + kw0];
  d[3] = s[(kh0 + 2) * 4 + kw0 + 2];
}

// ---------- convt3 weight reshape: [ci][3][16] -> wr3[cls][co][ci][4] ----------
__global__ __launch_bounds__(256) void wresh3_k(const float* __restrict__ w,
                                                float* __restrict__ wr) {
  int tid = blockIdx.x * 256 + threadIdx.x;
  if (tid >= 1536) return;
  int ci = tid & 127, co = (tid >> 7) % 3, cls = tid / 384;
  int cph = cls >> 1, cpw = cls & 1;
  int kh0 = 1 - cph, kw0 = 1 - cpw;
  const float* s = w + ((size_t)ci * 3 + co) * 16;
  float* d = wr + (size_t)tid * 4;
  d[0] = s[kh0 * 4 + kw0];
  d[1] = s[kh0 * 4 + kw0 + 2];
  d[2] = s[(kh0 + 2) * 4 + kw0];
  d[3] = s[(kh0 + 2) * 4 + kw0 + 2];
}

// ---------- convt2: parity-specialized, co x4, in d1p[66], out d2p[130] ----------
__global__ __launch_bounds__(256) void convt2_k(
    const float* __restrict__ xp, const float* __restrict__ wr,
    const float* __restrict__ bias, float* __restrict__ y) {
  int b = blockIdx.x;
  int chunk = b & 15, cls = (b >> 4) & 3, cog = (b >> 6) & 31, n = b >> 11;
  int cph = cls >> 1, cpw = cls & 1;
  int t = threadIdx.x;
  int wb = t & 63, i = chunk * 4 + (t >> 6);
  int co0 = cog * 4;
  int ho = 2 * i + cph, wo = 2 * wb + cpw;
  int r0 = i + 1 + cph, r1 = r0 - 1;
  int c0 = wb + 1 + cpw, c1 = c0 - 1;
  const float* xb = xp + (size_t)n * 128 * 4356;
  float acc[4] = {0.0f, 0.0f, 0.0f, 0.0f};
  for (int ci = 0; ci < 128; ++ci) {
    const float* xc = xb + (size_t)ci * 4356;
    float x00 = xc[r0 * 66 + c0], x01 = xc[r0 * 66 + c1];
    float x10 = xc[r1 * 66 + c0], x11 = xc[r1 * 66 + c1];
#pragma unroll
    for (int cc = 0; cc < 4; ++cc) {
      const float* w4 = wr + (((size_t)cls * 128 + co0 + cc) * 128 + ci) * 4;
      acc[cc] = fmaf(x00, w4[0], acc[cc]);
      acc[cc] = fmaf(x01, w4[1], acc[cc]);
      acc[cc] = fmaf(x10, w4[2], acc[cc]);
      acc[cc] = fmaf(x11, w4[3], acc[cc]);
    }
  }
#pragma unroll
  for (int cc = 0; cc < 4; ++cc)
    y[(((size_t)n * 128 + co0 + cc) * 130 + ho + 1) * 130 + wo + 1] =
        fmaxf(bias[co0 + cc] + acc[cc], 0.0f);
}

// ---------- convt3: parity-specialized, 3 co per thread, in d2p[130] ----------
__global__ __launch_bounds__(256) void convt3_k(
    const float* __restrict__ xp, const float* __restrict__ wr,
    const float* __restrict__ bias, float* __restrict__ y) {
  int b = blockIdx.x;
  int chunk = b & 63, cls = (b >> 6) & 3, n = b >> 8;
  int cph = cls >> 1, cpw = cls & 1;
  int t = threadIdx.x;
  int wb = t & 127, i = chunk * 2 + (t >> 7);
  int ho = 2 * i + cph, wo = 2 * wb + cpw;
  int r0 = i + 1 + cph, r1 = r0 - 1;
  int c0 = wb + 1 + cpw, c1 = c0 - 1;
  const float* xb = xp + (size_t)n * 128 * 16900;
  float acc[3] = {0.0f, 0.0f, 0.0f};
  for (int ci = 0; ci < 128; ++ci) {
    const float* xc = xb + (size_t)ci * 16900;
    float x00 = xc[r0 * 130 + c0], x01 = xc[r0 * 130 + c1];
    float x10 = xc[r1 * 130 + c0], x11 = xc[r1 * 130 + c1];
#pragma unroll
    for (int cc = 0; cc < 3; ++cc) {
      const float* w4 = wr + (((size_t)cls * 3 + cc) * 128 + ci) * 4;
      acc[cc] = fmaf(x00, w4[0], acc[cc]);
      acc[cc] = fmaf(x01, w4[1], acc[cc]);
      acc[cc] = fmaf(x10, w4[2], acc[cc]);
      acc[cc] = fmaf(x11, w4[3], acc[cc]);
    }
  }
#pragma unroll
  for (int cc = 0; cc < 3; ++cc)
    y[(((size_t)n * 3 + cc) << 16) + (ho << 8) + wo] = bias[cc] + acc[cc];
}

// ---------------------------------------------------------------------------
extern "C" void kernel_launch(void* const* d_in, const int* in_sizes, int n_in,
                              void* d_out, int out_size, void* d_ws, size_t ws_size,
                              hipStream_t stream) {
  const float* x    = (const float*)d_in[0];
  const float* ew1  = (const float*)d_in[1];
  const float* eb1  = (const float*)d_in[2];
  const float* ew2  = (const float*)d_in[3];
  const float* eb2  = (const float*)d_in[4];
  const float* ew3  = (const float*)d_in[5];
  const float* eb3  = (const float*)d_in[6];
  const float* qw   = (const float*)d_in[7];
  const float* qb   = (const float*)d_in[8];
  const float* cb   = (const float*)d_in[9];
  const float* pw   = (const float*)d_in[10];
  const float* pb   = (const float*)d_in[11];
  const float* dw1  = (const float*)d_in[12];
  const float* db1  = (const float*)d_in[13];
  const float* dtw2 = (const float*)d_in[14];
  const float* dtb2 = (const float*)d_in[15];
  const float* dtw3 = (const float*)d_in[16];
  const float* dtb3 = (const float*)d_in[17];

  char* wsb = (char*)d_ws;
  float* h1p  = (float*)(wsb + OFF_A);
  short* Ap   = (short*)(wsb + OFF_A);
  float* d2p  = (float*)(wsb + OFF_A);
  float* h2p  = (float*)(wsb + OFF_B);
  int*   cand = (int*)(wsb + OFF_B);
  float* qbufp= (float*)(wsb + OFF_B);
  float* xpad = (float*)(wsb + OFF_C);
  float* h3   = (float*)(wsb + OFF_C);
  int*   cntb = (int*)(wsb + OFF_C);
  float* bminb= (float*)(wsb + OFF_BMIN);
  float* d1p  = (float*)(wsb + OFF_C);
  float* zff  = (float*)(wsb + OFF_D);
  short* Bp   = (short*)(wsb + OFF_E);
  float* PC   = (float*)(wsb + OFF_E);
  float* znb  = (float*)(wsb + OFF_ZN);
  float* cnb  = (float*)(wsb + OFF_CN);
  int*   idxb = (int*)(wsb + OFF_IDX);
  float* accum= (float*)(wsb + OFF_ACC);
  float* wr2  = (float*)(wsb + OFF_WR2);
  float* wr3  = (float*)(wsb + OFF_WR3);
  float* qwT  = (float*)(wsb + OFF_QWT);

  float* out      = (float*)d_out;
  float* outLoss  = out + 786432;
  float* outIdxF  = out + 786433;

  // zero pads + weight prep (independent of encoder chain)
  hipMemsetAsync((void*)h1p,  0, 34611200, stream);
  hipMemsetAsync((void*)h2p,  0, 8921088,  stream);
  hipMemsetAsync((void*)xpad, 0, 3195072,  stream);
  hipLaunchKernelGGL(wresh2_k, dim3(256), dim3(256), 0, stream, dtw2, wr2);
  hipLaunchKernelGGL(wresh3_k, dim3(6),   dim3(256), 0, stream, dtw3, wr3);
  hipLaunchKernelGGL(qwT_k,    dim3(128), dim3(256), 0, stream, qw, qwT);

  // encoder: per-op fp32-rounded (f64-exact inside each op)
  hipLaunchKernelGGL(padx_k,       dim3(3072),  dim3(256), 0, stream, x, xpad);
  hipLaunchKernelGGL(conv1_k,      dim3(8192),  dim3(256), 0, stream, xpad, ew1, eb1, h1p);
  hipLaunchKernelGGL(conv2_k,      dim3(2048),  dim3(256), 0, stream, h1p, ew2, eb2, h2p);
  hipLaunchKernelGGL(conv3_k,      dim3(2048),  dim3(256), 0, stream, h2p, ew3, eb3, h3);
  hipLaunchKernelGGL(qconv_z_pr_k, dim3(16384), dim3(256), 0, stream, h3, qwT, qb, zff);

  // VQ: bf16-split MFMA filter + bmin-pruned exact rescore
  hipLaunchKernelGGL(rownorm_k,          dim3(4096),  dim3(256), 0, stream, zff, znb);
  hipLaunchKernelGGL(rownorm_k,          dim3(2048),  dim3(256), 0, stream, cb, cnb);
  hipLaunchKernelGGL((build_split_k<0>), dim3(16384), dim3(256), 0, stream, zff, Ap);
  hipLaunchKernelGGL((build_split_k<1>), dim3(8192),  dim3(256), 0, stream, cb, Bp);
  hipMemsetAsync((void*)cntb, 0, (size_t)16384 * 64 * 4, stream);
  hipLaunchKernelGGL(vq_gemm_k,   dim3(8192),  dim3(256), 0, stream, Ap, Bp, cnb, cntb, cand, bminb);
  hipLaunchKernelGGL(vq_phase3_k, dim3(4096),  dim3(256), 0, stream, zff, cb, znb, cnb, bminb, cntb, cand, idxb);
  hipLaunchKernelGGL(init_k,      dim3(1),     dim3(1),   0, stream, accum);
  hipLaunchKernelGGL(commit_k,    dim3(16384), dim3(256), 0, stream, zff, cb, idxb, accum, outIdxF);
  hipLaunchKernelGGL(fin_k,       dim3(1),     dim3(1),   0, stream, accum, outLoss);

  // decoder fp32 (pqconv folded through codebook: q = PC[idx] + b)
  hipLaunchKernelGGL(pc_k, dim3(4096), dim3(256), 0, stream, cb, pw, PC);
  hipMemsetAsync((void*)qbufp, 0, 8921088,  stream);   // cand dead after phase3
  hipMemsetAsync((void*)d1p,   0, 8921088,  stream);   // cnt/bmin dead after phase3
  hipMemsetAsync((void*)d2p,   0, 34611200, stream);   // Ap dead after vq_gemm
  hipLaunchKernelGGL(gather_pc_k, dim3(8192),  dim3(256), 0, stream, PC, idxb, pb, qbufp);
  hipLaunchKernelGGL(dconv1_k,    dim3(2048),  dim3(256), 0, stream, qbufp, dw1, db1, d1p);
  hipLaunchKernelGGL(convt2_k,    dim3(8192),  dim3(256), 0, stream, d1p, wr2, dtb2, d2p);
  hipLaunchKernelGGL(convt3_k,    dim3(1024),  dim3(256), 0, stream, d2p, wr3, dtb3, out);
}

// Round 8
// 1705.833 us; speedup vs baseline: 4.6955x; 1.0989x over previous
//
#include <hip/hip_runtime.h>

// ---------------------------------------------------------------------------
// VQ-VAE forward, round 8: fp16 K=256 VQ filter GEMM (deterministic margin),
// padded LDS (no bank conflicts), LDS-collected candidates -> one int4 store.
// Numerics contract (validated r3-r7): every reference op = fl32(f64-exact op
// on fp32 operands); d in fp32; first-index argmin.
//
// d_out (float32): recon[786432] | commit_loss[1] | indices[16384]
//
// Workspace regions (BYTE offsets):
//  A [0,34.61M):      h1p f32[4][128][130][130]
//                     -> {Ap f16[16384][256] @A | binfo int4[16384][64] @A+8.4M}
//                     -> d2p f32[4][128][130][130]
//  B [34.61M,43.53M): h2p f32[4][128][66][66] -> qbufp
//  C [43.53M,52.45M): xpad f32[4][3][258][258] -> h3 f32[4][128][64][64] -> d1p
//  D [52.45M,69.23M): zf f32[16384][256]
//  E [69.23M,81.81M): Bp f16[8192][256] -> PC f32[8192][128]
//  tail: zn, cn, idx, acc, wr2 (1MB), wr3 (24KB), qwT (128KB)
#define OFF_A     ((size_t)0)
#define OFF_BINFO ((size_t)8388608)
#define OFF_B     ((size_t)34611200)
#define OFF_C     ((size_t)43532288)
#define OFF_D     ((size_t)52453376)
#define OFF_E     ((size_t)69230592)
#define OFF_ZN    ((size_t)81813504)
#define OFF_CN    ((size_t)81879040)
#define OFF_IDX   ((size_t)81911808)
#define OFF_ACC   ((size_t)81977344)
#define OFF_WR2   ((size_t)81977600)
#define OFF_WR3   ((size_t)83026176)
#define OFF_QWT   ((size_t)83050752)

// margin >= 2*E_filter + 8e-6 d-rounding slack; E_filter <= 2.9e-5 deterministic
#define VQ_MARGIN 1.2e-4f
#define LDSS 40   // LDS row stride in shorts (80 B: 16B-aligned, <=2-way banks)

typedef __attribute__((ext_vector_type(8))) _Float16 f16x8;
typedef __attribute__((ext_vector_type(4))) float f32x4;

// ---------- helpers ----------
__device__ __forceinline__ unsigned fkey(float f) {
  unsigned u = __float_as_uint(f);
  return (u & 0x80000000u) ? ~u : (u | 0x80000000u);
}
__device__ __forceinline__ float funkey(unsigned k) {
  unsigned u = (k & 0x80000000u) ? (k ^ 0x80000000u) : ~k;
  return __uint_as_float(u);
}

// ---------- pad-copy x into [4][3][258][258] ----------
__global__ __launch_bounds__(256) void padx_k(const float* __restrict__ x,
                                              float* __restrict__ xp) {
  int tid = blockIdx.x * 256 + threadIdx.x;
  int wo = tid & 255, ho = (tid >> 8) & 255, c = tid >> 16;
  xp[((size_t)c * 258 + ho + 1) * 258 + wo + 1] = x[tid];
}

// ---------- enc conv1: k=4 s=2 + ReLU, 3ci, co x4, f64 acc ----------
__global__ __launch_bounds__(256) void conv1_k(
    const float* __restrict__ xp, const float* __restrict__ w,
    const float* __restrict__ bias, float* __restrict__ h1p) {
  int b = blockIdx.x;
  int chunk = b & 63, cog = (b >> 6) & 31, n = b >> 11;
  int t = threadIdx.x;
  int wo = t & 127, ho = chunk * 2 + (t >> 7);
  int co0 = cog * 4;
  const float* xb = xp + (size_t)n * 3 * 66564 + (size_t)(2 * ho) * 258 + 2 * wo;
  double acc[4] = {0.0, 0.0, 0.0, 0.0};
  for (int ci = 0; ci < 3; ++ci) {
    const float* xc = xb + (size_t)ci * 66564;
    float xv[16];
#pragma unroll
    for (int kh = 0; kh < 4; ++kh)
#pragma unroll
      for (int kw = 0; kw < 4; ++kw) xv[kh * 4 + kw] = xc[kh * 258 + kw];
#pragma unroll
    for (int cc = 0; cc < 4; ++cc) {
      const float* wp = w + (size_t)(co0 + cc) * 48 + ci * 16;
#pragma unroll
      for (int tp = 0; tp < 16; ++tp)
        acc[cc] = fma((double)xv[tp], (double)wp[tp], acc[cc]);
    }
  }
#pragma unroll
  for (int cc = 0; cc < 4; ++cc) {
    float r = (float)((double)bias[co0 + cc] + acc[cc]);
    h1p[(((size_t)n * 128 + co0 + cc) * 130 + ho + 1) * 130 + wo + 1] = fmaxf(r, 0.0f);
  }
}

// ---------- enc conv2: k=4 s=2 + ReLU, 128ci, co x4, f64 acc ----------
__global__ __launch_bounds__(256) void conv2_k(
    const float* __restrict__ h1p, const float* __restrict__ w,
    const float* __restrict__ bias, float* __restrict__ h2p) {
  int b = blockIdx.x;
  int chunk = b & 15, cog = (b >> 4) & 31, n = b >> 9;
  int t = threadIdx.x;
  int wo = t & 63, ho = chunk * 4 + (t >> 6);
  int co0 = cog * 4;
  const float* xb = h1p + (size_t)n * 128 * 16900 + (size_t)(2 * ho) * 130 + 2 * wo;
  double acc[4] = {0.0, 0.0, 0.0, 0.0};
  for (int ci = 0; ci < 128; ++ci) {
    const float* xc = xb + (size_t)ci * 16900;
    float xv[16];
#pragma unroll
    for (int kh = 0; kh < 4; ++kh)
#pragma unroll
      for (int kw = 0; kw < 4; ++kw) xv[kh * 4 + kw] = xc[kh * 130 + kw];
#pragma unroll
    for (int cc = 0; cc < 4; ++cc) {
      const float* wp = w + (size_t)(co0 + cc) * 2048 + ci * 16;
#pragma unroll
      for (int tp = 0; tp < 16; ++tp)
        acc[cc] = fma((double)xv[tp], (double)wp[tp], acc[cc]);
    }
  }
#pragma unroll
  for (int cc = 0; cc < 4; ++cc) {
    float r = (float)((double)bias[co0 + cc] + acc[cc]);
    h2p[(((size_t)n * 128 + co0 + cc) * 66 + ho + 1) * 66 + wo + 1] = fmaxf(r, 0.0f);
  }
}

// ---------- enc conv3: k=3 s=1 (no relu), co x4, f64 acc ----------
__global__ __launch_bounds__(256) void conv3_k(
    const float* __restrict__ h2p, const float* __restrict__ w,
    const float* __restrict__ bias, float* __restrict__ h3) {
  int b = blockIdx.x;
  int chunk = b & 15, cog = (b >> 4) & 31, n = b >> 9;
  int t = threadIdx.x;
  int wo = t & 63, ho = chunk * 4 + (t >> 6);
  int co0 = cog * 4;
  const float* xb = h2p + (size_t)n * 128 * 4356 + (size_t)ho * 66 + wo;
  double acc[4] = {0.0, 0.0, 0.0, 0.0};
  for (int ci = 0; ci < 128; ++ci) {
    const float* xc = xb + (size_t)ci * 4356;
    float xv[9];
#pragma unroll
    for (int kh = 0; kh < 3; ++kh)
#pragma unroll
      for (int kw = 0; kw < 3; ++kw) xv[kh * 3 + kw] = xc[kh * 66 + kw];
#pragma unroll
    for (int cc = 0; cc < 4; ++cc) {
      const float* wp = w + (size_t)(co0 + cc) * 1152 + ci * 9;
#pragma unroll
      for (int tp = 0; tp < 9; ++tp)
        acc[cc] = fma((double)xv[tp], (double)wp[tp], acc[cc]);
    }
  }
#pragma unroll
  for (int cc = 0; cc < 4; ++cc)
    h3[(((size_t)n * 128 + co0 + cc) << 12) + (ho << 6) + wo] =
        (float)((double)bias[co0 + cc] + acc[cc]);
}

// ---------- qconv weight transpose: qw[co][ci] -> qwT[ci][co] ----------
__global__ __launch_bounds__(256) void qwT_k(const float* __restrict__ qw,
                                             float* __restrict__ wT) {
  int tid = blockIdx.x * 256 + threadIdx.x;
  int co = tid & 255, ci = tid >> 8;
  wT[(size_t)ci * 256 + co] = qw[(size_t)co * 128 + ci];
}

// ---------- 1x1 conv 128->256, f64 acc, coalesced wT, z transposed [p][256] ----------
__global__ __launch_bounds__(256) void qconv_z_pr_k(
    const float* __restrict__ h3, const float* __restrict__ wT,
    const float* __restrict__ bias, float* __restrict__ zf) {
  int p  = blockIdx.x;
  int co = threadIdx.x;
  int n  = p >> 12;
  int hw = p & 4095;
  const float* xp = h3 + ((size_t)n * 128) * 4096 + hw;
  double a[4] = {0.0, 0.0, 0.0, 0.0};
  for (int ci = 0; ci < 128; ci += 4) {
#pragma unroll
    for (int u = 0; u < 4; ++u) {
      float xv = xp[(size_t)(ci + u) * 4096];
      a[u] = fma((double)xv, (double)wT[(size_t)(ci + u) * 256 + co], a[u]);
    }
  }
  double acc = (double)bias[co] + ((a[0] + a[1]) + (a[2] + a[3]));
  zf[(size_t)p * 256 + co] = (float)acc;
}

// ---------- row norms: fl32( f64-sum of fl32(v^2) ) ----------
__global__ __launch_bounds__(256) void rownorm_k(const float* __restrict__ src,
                                                 float* __restrict__ dst) {
  int lane = threadIdx.x & 63;
  int r = blockIdx.x * 4 + (threadIdx.x >> 6);
  const float* v = src + (size_t)r * 256;
  double s = 0.0;
#pragma unroll
  for (int j = 0; j < 4; ++j) {
    float x = v[lane + (j << 6)];
    float xx = x * x;
    s += (double)xx;
  }
#pragma unroll
  for (int off = 32; off > 0; off >>= 1) s += __shfl_down(s, off, 64);
  if (lane == 0) dst[r] = (float)s;
}

// ---------- fp16 builders: A = f16(z), B = f16(512*c) ----------
template<int MODE>   // 0 = z (scale 1), 1 = codebook (scale 512)
__global__ __launch_bounds__(256) void build_f16_k(
    const float* __restrict__ src, _Float16* __restrict__ dst) {
  int tid = blockIdx.x * 256 + threadIdx.x;
  float v = src[tid];
  dst[tid] = (_Float16)(MODE ? v * 512.0f : v);
}

// ---------- VQ filter GEMM: 128x128 tile, 16x16x32 f16 MFMA, K=256 ----------
// s~(p,k) = cn[k] - dot/256 (c scaled x512). Per-(row,colblock) epilogue:
// local min + margin collect in LDS, one int4{cnt,k0,k1,bmin} store.
__global__ __launch_bounds__(256, 2) void vq_gemm_k(
    const _Float16* __restrict__ Ah, const _Float16* __restrict__ Bh,
    const float* __restrict__ cnArr, int4* __restrict__ binfo) {
  __shared__ __align__(16) _Float16 As[128 * LDSS];
  __shared__ __align__(16) _Float16 Bs[128 * LDSS];
  __shared__ unsigned loc[128];
  __shared__ int cnt_sh[128];
  __shared__ int cand_sh[128][2];
  const int t = threadIdx.x;
  const int w = t >> 6, L = t & 63;
  const int mb = blockIdx.x >> 6;
  const int nb = blockIdx.x & 63;
  const int m0 = mb << 7, n0 = nb << 7;
  if (t < 128) { loc[t] = 0xFFFFFFFFu; cnt_sh[t] = 0; }
  f32x4 acc[4][4] = {};
  const int wr = (w >> 1) << 6, wc = (w & 1) << 6;
  const int srow = L >> 2, kg = L & 3;
  const int q = L >> 4, ln = L & 15;
  for (int kk = 0; kk < 256; kk += 32) {
    __syncthreads();
#pragma unroll
    for (int c = 0; c < 2; ++c) {
      const int row = (w << 5) + (c << 4) + srow;
      const f16x8 av = *(const f16x8*)(Ah + (size_t)(m0 + row) * 256 + kk + kg * 8);
      *(f16x8*)(&As[row * LDSS + kg * 8]) = av;
      const f16x8 bv = *(const f16x8*)(Bh + (size_t)(n0 + row) * 256 + kk + kg * 8);
      *(f16x8*)(&Bs[row * LDSS + kg * 8]) = bv;
    }
    __syncthreads();
    f16x8 af[4], bf[4];
#pragma unroll
    for (int i = 0; i < 4; ++i)
      af[i] = *(const f16x8*)(&As[(wr + 16 * i + ln) * LDSS + q * 8]);
#pragma unroll
    for (int j = 0; j < 4; ++j)
      bf[j] = *(const f16x8*)(&Bs[(wc + 16 * j + ln) * LDSS + q * 8]);
#pragma unroll
    for (int i = 0; i < 4; ++i)
#pragma unroll
      for (int j = 0; j < 4; ++j)
        acc[i][j] = __builtin_amdgcn_mfma_f32_16x16x32_f16(af[i], bf[j], acc[i][j], 0, 0, 0);
  }
  // epilogue: s = cn - dot/256 ; local min then margin collect (all in LDS)
  float cnv[4];
#pragma unroll
  for (int j = 0; j < 4; ++j) cnv[j] = cnArr[n0 + wc + 16 * j + ln];
#pragma unroll
  for (int i = 0; i < 4; ++i)
#pragma unroll
    for (int r = 0; r < 4; ++r) {
      float mn = 3.4e38f;
#pragma unroll
      for (int j = 0; j < 4; ++j)
        mn = fminf(mn, fmaf(-0.00390625f, acc[i][j][r], cnv[j]));
      atomicMin(&loc[wr + 16 * i + 4 * q + r], fkey(mn));
    }
  __syncthreads();
#pragma unroll
  for (int i = 0; i < 4; ++i)
#pragma unroll
    for (int r = 0; r < 4; ++r) {
      const int rib = wr + 16 * i + 4 * q + r;
      const float thr = funkey(loc[rib]) + VQ_MARGIN;
#pragma unroll
      for (int j = 0; j < 4; ++j) {
        float s = fmaf(-0.00390625f, acc[i][j][r], cnv[j]);
        if (s <= thr) {
          int slot = atomicAdd(&cnt_sh[rib], 1);
          if (slot < 2) cand_sh[rib][slot] = n0 + wc + 16 * j + ln;
        }
      }
    }
  __syncthreads();
  if (t < 128) {
    int4 v;
    v.x = cnt_sh[t];
    v.y = cand_sh[t][0];
    v.z = cand_sh[t][1];
    v.w = (int)__float_as_uint(funkey(loc[t]));
    binfo[(size_t)(m0 + t) * 64 + nb] = v;
  }
}

// ---------- VQ final: binfo-pruned, fp32-faithful d, lexicographic argmin ----------
__global__ __launch_bounds__(256) void vq_phase3_k(
    const float* __restrict__ zf, const float* __restrict__ cb,
    const float* __restrict__ znArr, const float* __restrict__ cnArr,
    const int4* __restrict__ binfo, int* __restrict__ idxOut) {
  const int lane = threadIdx.x & 63;
  const int r = blockIdx.x * 4 + (threadIdx.x >> 6);
  const float* zr = zf + (size_t)r * 256;
  double z4[4];
#pragma unroll
  for (int j = 0; j < 4; ++j) z4[j] = (double)zr[lane + (j << 6)];
  const float znr = znArr[r];
  int4 b = binfo[(size_t)r * 64 + lane];
  float bv = __uint_as_float((unsigned)b.w);
  float m = bv;
#pragma unroll
  for (int off = 32; off > 0; off >>= 1) m = fminf(m, __shfl_down(m, off, 64));
  m = __shfl(m, 0, 64);
  const float thr = m + VQ_MARGIN;
  unsigned long long mask = __ballot(bv <= thr);
  float bestd = 3.4e38f;
  int bestk = 0x7fffffff;
  while (mask) {
    const int nb = (int)__builtin_ctzll(mask);
    mask &= mask - 1;
    const int c  = __shfl(b.x, nb, 64);
    const int k0 = __shfl(b.y, nb, 64);
    const int k1 = __shfl(b.z, nb, 64);
    const int nsc = (c <= 2) ? c : 128;
    for (int s2 = 0; s2 < nsc; ++s2) {
      const int k = (c <= 2) ? (s2 == 0 ? k0 : k1) : (nb * 128 + s2);
      const float* ck = cb + (size_t)k * 256;
      double p = 0.0;
#pragma unroll
      for (int j = 0; j < 4; ++j)
        p = fma(z4[j], (double)ck[lane + (j << 6)], p);
#pragma unroll
      for (int off = 32; off > 0; off >>= 1) p += __shfl_down(p, off, 64);
      if (lane == 0) {
        float mm2 = (float)(2.0 * p);   // matmul op (x2 folded): fp32-rounded
        float t1 = znr + cnArr[k];      // fp32 add op
        float d = t1 - mm2;             // fp32 sub op
        if (d < bestd || (d == bestd && k < bestk)) { bestd = d; bestk = k; }
      }
    }
  }
  if (lane == 0) idxOut[r] = bestk;
}

// ---------- commit loss partials + indices-as-float output ----------
__global__ __launch_bounds__(256) void commit_k(
    const float* __restrict__ zf, const float* __restrict__ cb,
    const int* __restrict__ idxArr, float* __restrict__ accum,
    float* __restrict__ outIdxF) {
  __shared__ float wsum[4];
  const int p = blockIdx.x;
  const int t = threadIdx.x;
  const int k = idxArr[p];
  float d = cb[(size_t)k * 256 + t] - zf[(size_t)p * 256 + t];
  float v = d * d;
#pragma unroll
  for (int off = 32; off > 0; off >>= 1) v += __shfl_down(v, off, 64);
  if ((t & 63) == 0) wsum[t >> 6] = v;
  __syncthreads();
  if (t == 0) {
    atomicAdd(accum, wsum[0] + wsum[1] + wsum[2] + wsum[3]);
    outIdxF[p] = (float)k;
  }
}

__global__ void init_k(float* accum) { *accum = 0.0f; }
__global__ void fin_k(const float* __restrict__ accum, float* __restrict__ out) {
  *out = *accum * (1.0f / 4194304.0f);
}

// ---------- projected codebook PC[k][co] = sum_ci cb[k][ci]*pw[co][ci] ----------
__global__ __launch_bounds__(256) void pc_k(const float* __restrict__ cb,
                                            const float* __restrict__ pw,
                                            float* __restrict__ PC) {
  int tid = blockIdx.x * 256 + threadIdx.x;
  int co = tid & 127, k = tid >> 7;
  const float* c = cb + (size_t)k * 256;
  const float* w = pw + (size_t)co * 256;
  float a0 = 0.0f, a1 = 0.0f, a2 = 0.0f, a3 = 0.0f;
  for (int ci = 0; ci < 256; ci += 4) {
    a0 = fmaf(c[ci], w[ci], a0);
    a1 = fmaf(c[ci + 1], w[ci + 1], a1);
    a2 = fmaf(c[ci + 2], w[ci + 2], a2);
    a3 = fmaf(c[ci + 3], w[ci + 3], a3);
  }
  PC[tid] = (a0 + a1) + (a2 + a3);
}

// ---------- q = gather(PC, idx) + bias, padded NCHW [66][66] ----------
__global__ __launch_bounds__(256) void gather_pc_k(
    const float* __restrict__ PC, const int* __restrict__ idxArr,
    const float* __restrict__ pb, float* __restrict__ qp) {
  int tid = blockIdx.x * 256 + threadIdx.x;
  int hw = tid & 4095;
  int co = (tid >> 12) & 127;
  int n  = tid >> 19;
  int p  = (n << 12) + hw;
  int h = hw >> 6, w2 = hw & 63;
  qp[(((size_t)n * 128 + co) * 66 + h + 1) * 66 + w2 + 1] =
      PC[(size_t)idxArr[p] * 128 + co] + pb[co];
}

// ---------- dec conv1: fp32 k=3 s=1 + relu, co x4 ----------
__global__ __launch_bounds__(256) void dconv1_k(
    const float* __restrict__ qp, const float* __restrict__ w,
    const float* __restrict__ bias, float* __restrict__ d1p) {
  int b = blockIdx.x;
  int chunk = b & 15, cog = (b >> 4) & 31, n = b >> 9;
  int t = threadIdx.x;
  int wo = t & 63, ho = chunk * 4 + (t >> 6);
  int co0 = cog * 4;
  const float* xb = qp + (size_t)n * 128 * 4356 + (size_t)ho * 66 + wo;
  float acc[4] = {0.0f, 0.0f, 0.0f, 0.0f};
  for (int ci = 0; ci < 128; ++ci) {
    const float* xc = xb + (size_t)ci * 4356;
    float xv[9];
#pragma unroll
    for (int kh = 0; kh < 3; ++kh)
#pragma unroll
      for (int kw = 0; kw < 3; ++kw) xv[kh * 3 + kw] = xc[kh * 66 + kw];
#pragma unroll
    for (int cc = 0; cc < 4; ++cc) {
      const float* wp = w + (size_t)(co0 + cc) * 1152 + ci * 9;
#pragma unroll
      for (int tp = 0; tp < 9; ++tp)
        acc[cc] = fmaf(xv[tp], wp[tp], acc[cc]);
    }
  }
#pragma unroll
  for (int cc = 0; cc < 4; ++cc)
    d1p[(((size_t)n * 128 + co0 + cc) * 66 + ho + 1) * 66 + wo + 1] =
        fmaxf(bias[co0 + cc] + acc[cc], 0.0f);
}

// ---------- convt2 weight reshape: [ci][co][16] -> wr2[cls][co][ci][4] ----------
__global__ __launch_bounds__(256) void wresh2_k(const float* __restrict__ w,
                                                float* __restrict__ wr) {
  int tid = blockIdx.x * 256 + threadIdx.x;
  int ci = tid & 127, co = (tid >> 7) & 127, cls = tid >> 14;
  int cph = cls >> 1, cpw = cls & 1;
  int kh0 = 1 - cph, kw0 = 1 - cpw;
  const float* s = w + ((size_t)ci * 128 + co) * 16;
  float* d = wr + (size_t)tid * 4;
  d[0] = s[kh0 * 4 + kw0];
  d[1] = s[kh0 * 4 + kw0 + 2];
  d[2] = s[(kh0 + 2) * 4 + kw0];
  d[3] = s[(kh0 + 2) * 4 + kw0 + 2];
}

// ---------- convt3 weight reshape: [ci][3][16] -> wr3[cls][co][ci][4] ----------
__global__ __launch_bounds__(256) void wresh3_k(const float* __restrict__ w,
                                                float* __restrict__ wr) {
  int tid = blockIdx.x * 256 + threadIdx.x;
  if (tid >= 1536) return;
  int ci = tid & 127, co = (tid >> 7) % 3, cls = tid / 384;
  int cph = cls >> 1, cpw = cls & 1;
  int kh0 = 1 - cph, kw0 = 1 - cpw;
  const float* s = w + ((size_t)ci * 3 + co) * 16;
  float* d = wr + (size_t)tid * 4;
  d[0] = s[kh0 * 4 + kw0];
  d[1] = s[kh0 * 4 + kw0 + 2];
  d[2] = s[(kh0 + 2) * 4 + kw0];
  d[3] = s[(kh0 + 2) * 4 + kw0 + 2];
}

// ---------- convt2: parity-specialized, co x4, in d1p[66], out d2p[130] ----------
__global__ __launch_bounds__(256) void convt2_k(
    const float* __restrict__ xp, const float* __restrict__ wr,
    const float* __restrict__ bias, float* __restrict__ y) {
  int b = blockIdx.x;
  int chunk = b & 15, cls = (b >> 4) & 3, cog = (b >> 6) & 31, n = b >> 11;
  int cph = cls >> 1, cpw = cls & 1;
  int t = threadIdx.x;
  int wb = t & 63, i = chunk * 4 + (t >> 6);
  int co0 = cog * 4;
  int ho = 2 * i + cph, wo = 2 * wb + cpw;
  int r0 = i + 1 + cph, r1 = r0 - 1;
  int c0 = wb + 1 + cpw, c1 = c0 - 1;
  const float* xb = xp + (size_t)n * 128 * 4356;
  float acc[4] = {0.0f, 0.0f, 0.0f, 0.0f};
  for (int ci = 0; ci < 128; ++ci) {
    const float* xc = xb + (size_t)ci * 4356;
    float x00 = xc[r0 * 66 + c0], x01 = xc[r0 * 66 + c1];
    float x10 = xc[r1 * 66 + c0], x11 = xc[r1 * 66 + c1];
#pragma unroll
    for (int cc = 0; cc < 4; ++cc) {
      const float* w4 = wr + (((size_t)cls * 128 + co0 + cc) * 128 + ci) * 4;
      acc[cc] = fmaf(x00, w4[0], acc[cc]);
      acc[cc] = fmaf(x01, w4[1], acc[cc]);
      acc[cc] = fmaf(x10, w4[2], acc[cc]);
      acc[cc] = fmaf(x11, w4[3], acc[cc]);
    }
  }
#pragma unroll
  for (int cc = 0; cc < 4; ++cc)
    y[(((size_t)n * 128 + co0 + cc) * 130 + ho + 1) * 130 + wo + 1] =
        fmaxf(bias[co0 + cc] + acc[cc], 0.0f);
}

// ---------- convt3: parity-specialized, 3 co per thread, in d2p[130] ----------
__global__ __launch_bounds__(256) void convt3_k(
    const float* __restrict__ xp, const float* __restrict__ wr,
    const float* __restrict__ bias, float* __restrict__ y) {
  int b = blockIdx.x;
  int chunk = b & 63, cls = (b >> 6) & 3, n = b >> 8;
  int cph = cls >> 1, cpw = cls & 1;
  int t = threadIdx.x;
  int wb = t & 127, i = chunk * 2 + (t >> 7);
  int ho = 2 * i + cph, wo = 2 * wb + cpw;
  int r0 = i + 1 + cph, r1 = r0 - 1;
  int c0 = wb + 1 + cpw, c1 = c0 - 1;
  const float* xb = xp + (size_t)n * 128 * 16900;
  float acc[3] = {0.0f, 0.0f, 0.0f};
  for (int ci = 0; ci < 128; ++ci) {
    const float* xc = xb + (size_t)ci * 16900;
    float x00 = xc[r0 * 130 + c0], x01 = xc[r0 * 130 + c1];
    float x10 = xc[r1 * 130 + c0], x11 = xc[r1 * 130 + c1];
#pragma unroll
    for (int cc = 0; cc < 3; ++cc) {
      const float* w4 = wr + (((size_t)cls * 3 + cc) * 128 + ci) * 4;
      acc[cc] = fmaf(x00, w4[0], acc[cc]);
      acc[cc] = fmaf(x01, w4[1], acc[cc]);
      acc[cc] = fmaf(x10, w4[2], acc[cc]);
      acc[cc] = fmaf(x11, w4[3], acc[cc]);
    }
  }
#pragma unroll
  for (int cc = 0; cc < 3; ++cc)
    y[(((size_t)n * 3 + cc) << 16) + (ho << 8) + wo] = bias[cc] + acc[cc];
}

// ---------------------------------------------------------------------------
extern "C" void kernel_launch(void* const* d_in, const int* in_sizes, int n_in,
                              void* d_out, int out_size, void* d_ws, size_t ws_size,
                              hipStream_t stream) {
  const float* x    = (const float*)d_in[0];
  const float* ew1  = (const float*)d_in[1];
  const float* eb1  = (const float*)d_in[2];
  const float* ew2  = (const float*)d_in[3];
  const float* eb2  = (const float*)d_in[4];
  const float* ew3  = (const float*)d_in[5];
  const float* eb3  = (const float*)d_in[6];
  const float* qw   = (const float*)d_in[7];
  const float* qb   = (const float*)d_in[8];
  const float* cb   = (const float*)d_in[9];
  const float* pw   = (const float*)d_in[10];
  const float* pb   = (const float*)d_in[11];
  const float* dw1  = (const float*)d_in[12];
  const float* db1  = (const float*)d_in[13];
  const float* dtw2 = (const float*)d_in[14];
  const float* dtb2 = (const float*)d_in[15];
  const float* dtw3 = (const float*)d_in[16];
  const float* dtb3 = (const float*)d_in[17];

  char* wsb = (char*)d_ws;
  float*    h1p  = (float*)(wsb + OFF_A);
  _Float16* Ap   = (_Float16*)(wsb + OFF_A);
  int4*     binfo= (int4*)(wsb + OFF_BINFO);
  float*    d2p  = (float*)(wsb + OFF_A);
  float*    h2p  = (float*)(wsb + OFF_B);
  float*    qbufp= (float*)(wsb + OFF_B);
  float*    xpad = (float*)(wsb + OFF_C);
  float*    h3   = (float*)(wsb + OFF_C);
  float*    d1p  = (float*)(wsb + OFF_C);
  float*    zff  = (float*)(wsb + OFF_D);
  _Float16* Bp   = (_Float16*)(wsb + OFF_E);
  float*    PC   = (float*)(wsb + OFF_E);
  float*    znb  = (float*)(wsb + OFF_ZN);
  float*    cnb  = (float*)(wsb + OFF_CN);
  int*      idxb = (int*)(wsb + OFF_IDX);
  float*    accum= (float*)(wsb + OFF_ACC);
  float*    wr2  = (float*)(wsb + OFF_WR2);
  float*    wr3  = (float*)(wsb + OFF_WR3);
  float*    qwT  = (float*)(wsb + OFF_QWT);

  float* out      = (float*)d_out;
  float* outLoss  = out + 786432;
  float* outIdxF  = out + 786433;

  // zero pads + weight prep (independent of encoder chain)
  hipMemsetAsync((void*)h1p,  0, 34611200, stream);
  hipMemsetAsync((void*)h2p,  0, 8921088,  stream);
  hipMemsetAsync((void*)xpad, 0, 3195072,  stream);
  hipLaunchKernelGGL(wresh2_k, dim3(256), dim3(256), 0, stream, dtw2, wr2);
  hipLaunchKernelGGL(wresh3_k, dim3(6),   dim3(256), 0, stream, dtw3, wr3);
  hipLaunchKernelGGL(qwT_k,    dim3(128), dim3(256), 0, stream, qw, qwT);

  // encoder: per-op fp32-rounded (f64-exact inside each op)
  hipLaunchKernelGGL(padx_k,       dim3(3072),  dim3(256), 0, stream, x, xpad);
  hipLaunchKernelGGL(conv1_k,      dim3(8192),  dim3(256), 0, stream, xpad, ew1, eb1, h1p);
  hipLaunchKernelGGL(conv2_k,      dim3(2048),  dim3(256), 0, stream, h1p, ew2, eb2, h2p);
  hipLaunchKernelGGL(conv3_k,      dim3(2048),  dim3(256), 0, stream, h2p, ew3, eb3, h3);
  hipLaunchKernelGGL(qconv_z_pr_k, dim3(16384), dim3(256), 0, stream, h3, qwT, qb, zff);

  // VQ: fp16 K=256 MFMA filter + binfo-pruned exact rescore
  hipLaunchKernelGGL(rownorm_k,        dim3(4096),  dim3(256), 0, stream, zff, znb);
  hipLaunchKernelGGL(rownorm_k,        dim3(2048),  dim3(256), 0, stream, cb, cnb);
  hipLaunchKernelGGL((build_f16_k<0>), dim3(16384), dim3(256), 0, stream, zff, Ap);
  hipLaunchKernelGGL((build_f16_k<1>), dim3(8192),  dim3(256), 0, stream, cb, Bp);
  hipLaunchKernelGGL(vq_gemm_k,   dim3(8192),  dim3(256), 0, stream, Ap, Bp, cnb, binfo);
  hipLaunchKernelGGL(vq_phase3_k, dim3(4096),  dim3(256), 0, stream, zff, cb, znb, cnb, binfo, idxb);
  hipLaunchKernelGGL(init_k,      dim3(1),     dim3(1),   0, stream, accum);
  hipLaunchKernelGGL(commit_k,    dim3(16384), dim3(256), 0, stream, zff, cb, idxb, accum, outIdxF);
  hipLaunchKernelGGL(fin_k,       dim3(1),     dim3(1),   0, stream, accum, outLoss);

  // decoder fp32 (pqconv folded through codebook: q = PC[idx] + b)
  hipLaunchKernelGGL(pc_k, dim3(4096), dim3(256), 0, stream, cb, pw, PC);
  hipMemsetAsync((void*)qbufp, 0, 8921088,  stream);
  hipMemsetAsync((void*)d1p,   0, 8921088,  stream);
  hipMemsetAsync((void*)d2p,   0, 34611200, stream);   // Ap/binfo dead after phase3
  hipLaunchKernelGGL(gather_pc_k, dim3(8192),  dim3(256), 0, stream, PC, idxb, pb, qbufp);
  hipLaunchKernelGGL(dconv1_k,    dim3(2048),  dim3(256), 0, stream, qbufp, dw1, db1, d1p);
  hipLaunchKernelGGL(convt2_k,    dim3(8192),  dim3(256), 0, stream, d1p, wr2, dtb2, d2p);
  hipLaunchKernelGGL(convt3_k,    dim3(1024),  dim3(256), 0, stream, d2p, wr3, dtb3, out);
}

// Round 9
// 1627.257 us; speedup vs baseline: 4.9223x; 1.0483x over previous
//
#include <hip/hip_runtime.h>

// ---------------------------------------------------------------------------
// VQ-VAE forward, round 9: cvt-free f64 convs (pre-widened f64 weights +
// one-shot x widening + co x8 blocking). Association order preserved ->
// bitwise-identical encoder vs r8. Numerics contract (validated r3-r8):
// every reference op = fl32(f64-exact op on fp32 operands); d in fp32;
// first-index argmin.
//
// d_out (float32): recon[786432] | commit_loss[1] | indices[16384]
//
// Workspace (BYTE offsets), ~86.5 MB peak:
#define OFF_A     ((size_t)0)
#define OFF_BINFO ((size_t)8388608)
#define OFF_B     ((size_t)34611200)
#define OFF_C     ((size_t)43532288)
#define OFF_D     ((size_t)52453376)
#define OFF_E     ((size_t)69230592)
#define OFF_ZN    ((size_t)81813504)
#define OFF_CN    ((size_t)81879040)
#define OFF_IDX   ((size_t)81911808)
#define OFF_ACC   ((size_t)81977344)
#define OFF_WR2   ((size_t)81977600)
#define OFF_WR3   ((size_t)83026176)
#define OFF_QWT   ((size_t)83050752)
#define OFF_WD2   ((size_t)83181824)   // f64 conv2 weights, 2 MB
#define OFF_WD3   ((size_t)85278976)   // f64 conv3 weights, 1.18 MB

#define VQ_MARGIN 1.2e-4f
#define LDSS 40

typedef __attribute__((ext_vector_type(8))) _Float16 f16x8;
typedef __attribute__((ext_vector_type(4))) float f32x4;

// ---------- helpers ----------
__device__ __forceinline__ unsigned fkey(float f) {
  unsigned u = __float_as_uint(f);
  return (u & 0x80000000u) ? ~u : (u | 0x80000000u);
}
__device__ __forceinline__ float funkey(unsigned k) {
  unsigned u = (k & 0x80000000u) ? (k ^ 0x80000000u) : ~k;
  return __uint_as_float(u);
}

// ---------- f32 -> f64 widen (weights) ----------
__global__ __launch_bounds__(256) void widen_k(const float* __restrict__ s,
                                               double* __restrict__ d, int n) {
  int tid = blockIdx.x * 256 + threadIdx.x;
  if (tid < n) d[tid] = (double)s[tid];
}

// ---------- pad-copy x into [4][3][258][258] ----------
__global__ __launch_bounds__(256) void padx_k(const float* __restrict__ x,
                                              float* __restrict__ xp) {
  int tid = blockIdx.x * 256 + threadIdx.x;
  int wo = tid & 255, ho = (tid >> 8) & 255, c = tid >> 16;
  xp[((size_t)c * 258 + ho + 1) * 258 + wo + 1] = x[tid];
}

// ---------- enc conv1: k=4 s=2 + ReLU, 3ci, co x4, f64 acc ----------
__global__ __launch_bounds__(256) void conv1_k(
    const float* __restrict__ xp, const float* __restrict__ w,
    const float* __restrict__ bias, float* __restrict__ h1p) {
  int b = blockIdx.x;
  int chunk = b & 63, cog = (b >> 6) & 31, n = b >> 11;
  int t = threadIdx.x;
  int wo = t & 127, ho = chunk * 2 + (t >> 7);
  int co0 = cog * 4;
  const float* xb = xp + (size_t)n * 3 * 66564 + (size_t)(2 * ho) * 258 + 2 * wo;
  double acc[4] = {0.0, 0.0, 0.0, 0.0};
  for (int ci = 0; ci < 3; ++ci) {
    const float* xc = xb + (size_t)ci * 66564;
    double xd[16];
#pragma unroll
    for (int kh = 0; kh < 4; ++kh)
#pragma unroll
      for (int kw = 0; kw < 4; ++kw) xd[kh * 4 + kw] = (double)xc[kh * 258 + kw];
#pragma unroll
    for (int cc = 0; cc < 4; ++cc) {
      const float* wp = w + (size_t)(co0 + cc) * 48 + ci * 16;
#pragma unroll
      for (int tp = 0; tp < 16; ++tp)
        acc[cc] = fma(xd[tp], (double)wp[tp], acc[cc]);
    }
  }
#pragma unroll
  for (int cc = 0; cc < 4; ++cc) {
    float r = (float)((double)bias[co0 + cc] + acc[cc]);
    h1p[(((size_t)n * 128 + co0 + cc) * 130 + ho + 1) * 130 + wo + 1] = fmaxf(r, 0.0f);
  }
}

// ---------- enc conv2: k=4 s=2 + ReLU, 128ci, co x8, f64 weights ----------
__global__ __launch_bounds__(256) void conv2_k(
    const float* __restrict__ h1p, const double* __restrict__ wd,
    const float* __restrict__ bias, float* __restrict__ h2p) {
  int b = blockIdx.x;
  int chunk = b & 15, cog = (b >> 4) & 15, n = b >> 8;
  int t = threadIdx.x;
  int wo = t & 63, ho = chunk * 4 + (t >> 6);
  int co0 = cog * 8;
  const float* xb = h1p + (size_t)n * 128 * 16900 + (size_t)(2 * ho) * 130 + 2 * wo;
  double acc[8] = {0.0, 0.0, 0.0, 0.0, 0.0, 0.0, 0.0, 0.0};
  for (int ci = 0; ci < 128; ++ci) {
    const float* xc = xb + (size_t)ci * 16900;
    double xd[16];
#pragma unroll
    for (int kh = 0; kh < 4; ++kh)
#pragma unroll
      for (int kw = 0; kw < 4; ++kw) xd[kh * 4 + kw] = (double)xc[kh * 130 + kw];
#pragma unroll
    for (int cc = 0; cc < 8; ++cc) {
      const double* wp = wd + (size_t)(co0 + cc) * 2048 + ci * 16;
#pragma unroll
      for (int tp = 0; tp < 16; ++tp)
        acc[cc] = fma(xd[tp], wp[tp], acc[cc]);
    }
  }
#pragma unroll
  for (int cc = 0; cc < 8; ++cc) {
    float r = (float)((double)bias[co0 + cc] + acc[cc]);
    h2p[(((size_t)n * 128 + co0 + cc) * 66 + ho + 1) * 66 + wo + 1] = fmaxf(r, 0.0f);
  }
}

// ---------- enc conv3: k=3 s=1 (no relu), co x8, f64 weights ----------
__global__ __launch_bounds__(256) void conv3_k(
    const float* __restrict__ h2p, const double* __restrict__ wd,
    const float* __restrict__ bias, float* __restrict__ h3) {
  int b = blockIdx.x;
  int chunk = b & 15, cog = (b >> 4) & 15, n = b >> 8;
  int t = threadIdx.x;
  int wo = t & 63, ho = chunk * 4 + (t >> 6);
  int co0 = cog * 8;
  const float* xb = h2p + (size_t)n * 128 * 4356 + (size_t)ho * 66 + wo;
  double acc[8] = {0.0, 0.0, 0.0, 0.0, 0.0, 0.0, 0.0, 0.0};
  for (int ci = 0; ci < 128; ++ci) {
    const float* xc = xb + (size_t)ci * 4356;
    double xd[9];
#pragma unroll
    for (int kh = 0; kh < 3; ++kh)
#pragma unroll
      for (int kw = 0; kw < 3; ++kw) xd[kh * 3 + kw] = (double)xc[kh * 66 + kw];
#pragma unroll
    for (int cc = 0; cc < 8; ++cc) {
      const double* wp = wd + (size_t)(co0 + cc) * 1152 + ci * 9;
#pragma unroll
      for (int tp = 0; tp < 9; ++tp)
        acc[cc] = fma(xd[tp], wp[tp], acc[cc]);
    }
  }
#pragma unroll
  for (int cc = 0; cc < 8; ++cc)
    h3[(((size_t)n * 128 + co0 + cc) << 12) + (ho << 6) + wo] =
        (float)((double)bias[co0 + cc] + acc[cc]);
}

// ---------- qconv weight transpose: qw[co][ci] -> qwT[ci][co] ----------
__global__ __launch_bounds__(256) void qwT_k(const float* __restrict__ qw,
                                             float* __restrict__ wT) {
  int tid = blockIdx.x * 256 + threadIdx.x;
  int co = tid & 255, ci = tid >> 8;
  wT[(size_t)ci * 256 + co] = qw[(size_t)co * 128 + ci];
}

// ---------- 1x1 conv 128->256, f64 acc, coalesced wT, z transposed [p][256] ----------
__global__ __launch_bounds__(256) void qconv_z_pr_k(
    const float* __restrict__ h3, const float* __restrict__ wT,
    const float* __restrict__ bias, float* __restrict__ zf) {
  int p  = blockIdx.x;
  int co = threadIdx.x;
  int n  = p >> 12;
  int hw = p & 4095;
  const float* xp = h3 + ((size_t)n * 128) * 4096 + hw;
  double a[4] = {0.0, 0.0, 0.0, 0.0};
  for (int ci = 0; ci < 128; ci += 4) {
#pragma unroll
    for (int u = 0; u < 4; ++u) {
      float xv = xp[(size_t)(ci + u) * 4096];
      a[u] = fma((double)xv, (double)wT[(size_t)(ci + u) * 256 + co], a[u]);
    }
  }
  double acc = (double)bias[co] + ((a[0] + a[1]) + (a[2] + a[3]));
  zf[(size_t)p * 256 + co] = (float)acc;
}

// ---------- row norms: fl32( f64-sum of fl32(v^2) ) ----------
__global__ __launch_bounds__(256) void rownorm_k(const float* __restrict__ src,
                                                 float* __restrict__ dst) {
  int lane = threadIdx.x & 63;
  int r = blockIdx.x * 4 + (threadIdx.x >> 6);
  const float* v = src + (size_t)r * 256;
  double s = 0.0;
#pragma unroll
  for (int j = 0; j < 4; ++j) {
    float x = v[lane + (j << 6)];
    float xx = x * x;
    s += (double)xx;
  }
#pragma unroll
  for (int off = 32; off > 0; off >>= 1) s += __shfl_down(s, off, 64);
  if (lane == 0) dst[r] = (float)s;
}

// ---------- fp16 builders: A = f16(z), B = f16(512*c) ----------
template<int MODE>
__global__ __launch_bounds__(256) void build_f16_k(
    const float* __restrict__ src, _Float16* __restrict__ dst) {
  int tid = blockIdx.x * 256 + threadIdx.x;
  float v = src[tid];
  dst[tid] = (_Float16)(MODE ? v * 512.0f : v);
}

// ---------- VQ filter GEMM: 128x128 tile, 16x16x32 f16 MFMA, K=256 ----------
__global__ __launch_bounds__(256, 2) void vq_gemm_k(
    const _Float16* __restrict__ Ah, const _Float16* __restrict__ Bh,
    const float* __restrict__ cnArr, int4* __restrict__ binfo) {
  __shared__ __align__(16) _Float16 As[128 * LDSS];
  __shared__ __align__(16) _Float16 Bs[128 * LDSS];
  __shared__ unsigned loc[128];
  __shared__ int cnt_sh[128];
  __shared__ int cand_sh[128][2];
  const int t = threadIdx.x;
  const int w = t >> 6, L = t & 63;
  const int mb = blockIdx.x >> 6;
  const int nb = blockIdx.x & 63;
  const int m0 = mb << 7, n0 = nb << 7;
  if (t < 128) { loc[t] = 0xFFFFFFFFu; cnt_sh[t] = 0; }
  f32x4 acc[4][4] = {};
  const int wr = (w >> 1) << 6, wc = (w & 1) << 6;
  const int srow = L >> 2, kg = L & 3;
  const int q = L >> 4, ln = L & 15;
  for (int kk = 0; kk < 256; kk += 32) {
    __syncthreads();
#pragma unroll
    for (int c = 0; c < 2; ++c) {
      const int row = (w << 5) + (c << 4) + srow;
      const f16x8 av = *(const f16x8*)(Ah + (size_t)(m0 + row) * 256 + kk + kg * 8);
      *(f16x8*)(&As[row * LDSS + kg * 8]) = av;
      const f16x8 bv = *(const f16x8*)(Bh + (size_t)(n0 + row) * 256 + kk + kg * 8);
      *(f16x8*)(&Bs[row * LDSS + kg * 8]) = bv;
    }
    __syncthreads();
    f16x8 af[4], bf[4];
#pragma unroll
    for (int i = 0; i < 4; ++i)
      af[i] = *(const f16x8*)(&As[(wr + 16 * i + ln) * LDSS + q * 8]);
#pragma unroll
    for (int j = 0; j < 4; ++j)
      bf[j] = *(const f16x8*)(&Bs[(wc + 16 * j + ln) * LDSS + q * 8]);
#pragma unroll
    for (int i = 0; i < 4; ++i)
#pragma unroll
      for (int j = 0; j < 4; ++j)
        acc[i][j] = __builtin_amdgcn_mfma_f32_16x16x32_f16(af[i], bf[j], acc[i][j], 0, 0, 0);
  }
  float cnv[4];
#pragma unroll
  for (int j = 0; j < 4; ++j) cnv[j] = cnArr[n0 + wc + 16 * j + ln];
#pragma unroll
  for (int i = 0; i < 4; ++i)
#pragma unroll
    for (int r = 0; r < 4; ++r) {
      float mn = 3.4e38f;
#pragma unroll
      for (int j = 0; j < 4; ++j)
        mn = fminf(mn, fmaf(-0.00390625f, acc[i][j][r], cnv[j]));
      atomicMin(&loc[wr + 16 * i + 4 * q + r], fkey(mn));
    }
  __syncthreads();
#pragma unroll
  for (int i = 0; i < 4; ++i)
#pragma unroll
    for (int r = 0; r < 4; ++r) {
      const int rib = wr + 16 * i + 4 * q + r;
      const float thr = funkey(loc[rib]) + VQ_MARGIN;
#pragma unroll
      for (int j = 0; j < 4; ++j) {
        float s = fmaf(-0.00390625f, acc[i][j][r], cnv[j]);
        if (s <= thr) {
          int slot = atomicAdd(&cnt_sh[rib], 1);
          if (slot < 2) cand_sh[rib][slot] = n0 + wc + 16 * j + ln;
        }
      }
    }
  __syncthreads();
  if (t < 128) {
    int4 v;
    v.x = cnt_sh[t];
    v.y = cand_sh[t][0];
    v.z = cand_sh[t][1];
    v.w = (int)__float_as_uint(funkey(loc[t]));
    binfo[(size_t)(m0 + t) * 64 + nb] = v;
  }
}

// ---------- VQ final: binfo-pruned, fp32-faithful d, lexicographic argmin ----------
__global__ __launch_bounds__(256) void vq_phase3_k(
    const float* __restrict__ zf, const float* __restrict__ cb,
    const float* __restrict__ znArr, const float* __restrict__ cnArr,
    const int4* __restrict__ binfo, int* __restrict__ idxOut) {
  const int lane = threadIdx.x & 63;
  const int r = blockIdx.x * 4 + (threadIdx.x >> 6);
  const float* zr = zf + (size_t)r * 256;
  double z4[4];
#pragma unroll
  for (int j = 0; j < 4; ++j) z4[j] = (double)zr[lane + (j << 6)];
  const float znr = znArr[r];
  int4 b = binfo[(size_t)r * 64 + lane];
  float bv = __uint_as_float((unsigned)b.w);
  float m = bv;
#pragma unroll
  for (int off = 32; off > 0; off >>= 1) m = fminf(m, __shfl_down(m, off, 64));
  m = __shfl(m, 0, 64);
  const float thr = m + VQ_MARGIN;
  unsigned long long mask = __ballot(bv <= thr);
  float bestd = 3.4e38f;
  int bestk = 0x7fffffff;
  while (mask) {
    const int nb = (int)__builtin_ctzll(mask);
    mask &= mask - 1;
    const int c  = __shfl(b.x, nb, 64);
    const int k0 = __shfl(b.y, nb, 64);
    const int k1 = __shfl(b.z, nb, 64);
    const int nsc = (c <= 2) ? c : 128;
    for (int s2 = 0; s2 < nsc; ++s2) {
      const int k = (c <= 2) ? (s2 == 0 ? k0 : k1) : (nb * 128 + s2);
      const float* ck = cb + (size_t)k * 256;
      double p = 0.0;
#pragma unroll
      for (int j = 0; j < 4; ++j)
        p = fma(z4[j], (double)ck[lane + (j << 6)], p);
#pragma unroll
      for (int off = 32; off > 0; off >>= 1) p += __shfl_down(p, off, 64);
      if (lane == 0) {
        float mm2 = (float)(2.0 * p);
        float t1 = znr + cnArr[k];
        float d = t1 - mm2;
        if (d < bestd || (d == bestd && k < bestk)) { bestd = d; bestk = k; }
      }
    }
  }
  if (lane == 0) idxOut[r] = bestk;
}

// ---------- commit loss partials + indices-as-float output ----------
__global__ __launch_bounds__(256) void commit_k(
    const float* __restrict__ zf, const float* __restrict__ cb,
    const int* __restrict__ idxArr, float* __restrict__ accum,
    float* __restrict__ outIdxF) {
  __shared__ float wsum[4];
  const int p = blockIdx.x;
  const int t = threadIdx.x;
  const int k = idxArr[p];
  float d = cb[(size_t)k * 256 + t] - zf[(size_t)p * 256 + t];
  float v = d * d;
#pragma unroll
  for (int off = 32; off > 0; off >>= 1) v += __shfl_down(v, off, 64);
  if ((t & 63) == 0) wsum[t >> 6] = v;
  __syncthreads();
  if (t == 0) {
    atomicAdd(accum, wsum[0] + wsum[1] + wsum[2] + wsum[3]);
    outIdxF[p] = (float)k;
  }
}

__global__ void init_k(float* accum) { *accum = 0.0f; }
__global__ void fin_k(const float* __restrict__ accum, float* __restrict__ out) {
  *out = *accum * (1.0f / 4194304.0f);
}

// ---------- projected codebook PC[k][co] = sum_ci cb[k][ci]*pw[co][ci] ----------
__global__ __launch_bounds__(256) void pc_k(const float* __restrict__ cb,
                                            const float* __restrict__ pw,
                                            float* __restrict__ PC) {
  int tid = blockIdx.x * 256 + threadIdx.x;
  int co = tid & 127, k = tid >> 7;
  const float* c = cb + (size_t)k * 256;
  const float* w = pw + (size_t)co * 256;
  float a0 = 0.0f, a1 = 0.0f, a2 = 0.0f, a3 = 0.0f;
  for (int ci = 0; ci < 256; ci += 4) {
    a0 = fmaf(c[ci], w[ci], a0);
    a1 = fmaf(c[ci + 1], w[ci + 1], a1);
    a2 = fmaf(c[ci + 2], w[ci + 2], a2);
    a3 = fmaf(c[ci + 3], w[ci + 3], a3);
  }
  PC[tid] = (a0 + a1) + (a2 + a3);
}

// ---------- q = gather(PC, idx) + bias, padded NCHW [66][66] ----------
__global__ __launch_bounds__(256) void gather_pc_k(
    const float* __restrict__ PC, const int* __restrict__ idxArr,
    const float* __restrict__ pb, float* __restrict__ qp) {
  int tid = blockIdx.x * 256 + threadIdx.x;
  int hw = tid & 4095;
  int co = (tid >> 12) & 127;
  int n  = tid >> 19;
  int p  = (n << 12) + hw;
  int h = hw >> 6, w2 = hw & 63;
  qp[(((size_t)n * 128 + co) * 66 + h + 1) * 66 + w2 + 1] =
      PC[(size_t)idxArr[p] * 128 + co] + pb[co];
}

// ---------- dec conv1: fp32 k=3 s=1 + relu, co x4 ----------
__global__ __launch_bounds__(256) void dconv1_k(
    const float* __restrict__ qp, const float* __restrict__ w,
    const float* __restrict__ bias, float* __restrict__ d1p) {
  int b = blockIdx.x;
  int chunk = b & 15, cog = (b >> 4) & 31, n = b >> 9;
  int t = threadIdx.x;
  int wo = t & 63, ho = chunk * 4 + (t >> 6);
  int co0 = cog * 4;
  const float* xb = qp + (size_t)n * 128 * 4356 + (size_t)ho * 66 + wo;
  float acc[4] = {0.0f, 0.0f, 0.0f, 0.0f};
  for (int ci = 0; ci < 128; ++ci) {
    const float* xc = xb + (size_t)ci * 4356;
    float xv[9];
#pragma unroll
    for (int kh = 0; kh < 3; ++kh)
#pragma unroll
      for (int kw = 0; kw < 3; ++kw) xv[kh * 3 + kw] = xc[kh * 66 + kw];
#pragma unroll
    for (int cc = 0; cc < 4; ++cc) {
      const float* wp = w + (size_t)(co0 + cc) * 1152 + ci * 9;
#pragma unroll
      for (int tp = 0; tp < 9; ++tp)
        acc[cc] = fmaf(xv[tp], wp[tp], acc[cc]);
    }
  }
#pragma unroll
  for (int cc = 0; cc < 4; ++cc)
    d1p[(((size_t)n * 128 + co0 + cc) * 66 + ho + 1) * 66 + wo + 1] =
        fmaxf(bias[co0 + cc] + acc[cc], 0.0f);
}

// ---------- convt2 weight reshape: [ci][co][16] -> wr2[cls][co][ci][4] ----------
__global__ __launch_bounds__(256) void wresh2_k(const float* __restrict__ w,
                                                float* __restrict__ wr) {
  int tid = blockIdx.x * 256 + threadIdx.x;
  int ci = tid & 127, co = (tid >> 7) & 127, cls = tid >> 14;
  int cph = cls >> 1, cpw = cls & 1;
  int kh0 = 1 - cph, kw0 = 1 - cpw;
  const float* s = w + ((size_t)ci * 128 + co) * 16;
  float* d = wr + (size_t)tid * 4;
  d[0] = s[kh0 * 4 + kw0];
  d[1] = s[kh0 * 4 + kw0 + 2];
  d[2] = s[(kh0 + 2) * 4 + kw0];
  d[3] = s[(kh0 + 2) * 4 + kw0 + 2];
}

// ---------- convt3 weight reshape: [ci][3][16] -> wr3[cls][co][ci][4] ----------
__global__ __launch_bounds__(256) void wresh3_k(const float* __restrict__ w,
                                                float* __restrict__ wr) {
  int tid = blockIdx.x * 256 + threadIdx.x;
  if (tid >= 1536) return;
  int ci = tid & 127, co = (tid >> 7) % 3, cls = tid / 384;
  int cph = cls >> 1, cpw = cls & 1;
  int kh0 = 1 - cph, kw0 = 1 - cpw;
  const float* s = w + ((size_t)ci * 3 + co) * 16;
  float* d = wr + (size_t)tid * 4;
  d[0] = s[kh0 * 4 + kw0];
  d[1] = s[kh0 * 4 + kw0 + 2];
  d[2] = s[(kh0 + 2) * 4 + kw0];
  d[3] = s[(kh0 + 2) * 4 + kw0 + 2];
}

// ---------- convt2: parity-specialized, co x4, in d1p[66], out d2p[130] ----------
__global__ __launch_bounds__(256) void convt2_k(
    const float* __restrict__ xp, const float* __restrict__ wr,
    const float* __restrict__ bias, float* __restrict__ y) {
  int b = blockIdx.x;
  int chunk = b & 15, cls = (b >> 4) & 3, cog = (b >> 6) & 31, n = b >> 11;
  int cph = cls >> 1, cpw = cls & 1;
  int t = threadIdx.x;
  int wb = t & 63, i = chunk * 4 + (t >> 6);
  int co0 = cog * 4;
  int ho = 2 * i + cph, wo = 2 * wb + cpw;
  int r0 = i + 1 + cph, r1 = r0 - 1;
  int c0 = wb + 1 + cpw, c1 = c0 - 1;
  const float* xb = xp + (size_t)n * 128 * 4356;
  float acc[4] = {0.0f, 0.0f, 0.0f, 0.0f};
  for (int ci = 0; ci < 128; ++ci) {
    const float* xc = xb + (size_t)ci * 4356;
    float x00 = xc[r0 * 66 + c0], x01 = xc[r0 * 66 + c1];
    float x10 = xc[r1 * 66 + c0], x11 = xc[r1 * 66 + c1];
#pragma unroll
    for (int cc = 0; cc < 4; ++cc) {
      const float* w4 = wr + (((size_t)cls * 128 + co0 + cc) * 128 + ci) * 4;
      acc[cc] = fmaf(x00, w4[0], acc[cc]);
      acc[cc] = fmaf(x01, w4[1], acc[cc]);
      acc[cc] = fmaf(x10, w4[2], acc[cc]);
      acc[cc] = fmaf(x11, w4[3], acc[cc]);
    }
  }
#pragma unroll
  for (int cc = 0; cc < 4; ++cc)
    y[(((size_t)n * 128 + co0 + cc) * 130 + ho + 1) * 130 + wo + 1] =
        fmaxf(bias[co0 + cc] + acc[cc], 0.0f);
}

// ---------- convt3: parity-specialized, 3 co per thread, in d2p[130] ----------
__global__ __launch_bounds__(256) void convt3_k(
    const float* __restrict__ xp, const float* __restrict__ wr,
    const float* __restrict__ bias, float* __restrict__ y) {
  int b = blockIdx.x;
  int chunk = b & 63, cls = (b >> 6) & 3, n = b >> 8;
  int cph = cls >> 1, cpw = cls & 1;
  int t = threadIdx.x;
  int wb = t & 127, i = chunk * 2 + (t >> 7);
  int ho = 2 * i + cph, wo = 2 * wb + cpw;
  int r0 = i + 1 + cph, r1 = r0 - 1;
  int c0 = wb + 1 + cpw, c1 = c0 - 1;
  const float* xb = xp + (size_t)n * 128 * 16900;
  float acc[3] = {0.0f, 0.0f, 0.0f};
  for (int ci = 0; ci < 128; ++ci) {
    const float* xc = xb + (size_t)ci * 16900;
    float x00 = xc[r0 * 130 + c0], x01 = xc[r0 * 130 + c1];
    float x10 = xc[r1 * 130 + c0], x11 = xc[r1 * 130 + c1];
#pragma unroll
    for (int cc = 0; cc < 3; ++cc) {
      const float* w4 = wr + (((size_t)cls * 3 + cc) * 128 + ci) * 4;
      acc[cc] = fmaf(x00, w4[0], acc[cc]);
      acc[cc] = fmaf(x01, w4[1], acc[cc]);
      acc[cc] = fmaf(x10, w4[2], acc[cc]);
      acc[cc] = fmaf(x11, w4[3], acc[cc]);
    }
  }
#pragma unroll
  for (int cc = 0; cc < 3; ++cc)
    y[(((size_t)n * 3 + cc) << 16) + (ho << 8) + wo] = bias[cc] + acc[cc];
}

// ---------------------------------------------------------------------------
extern "C" void kernel_launch(void* const* d_in, const int* in_sizes, int n_in,
                              void* d_out, int out_size, void* d_ws, size_t ws_size,
                              hipStream_t stream) {
  const float* x    = (const float*)d_in[0];
  const float* ew1  = (const float*)d_in[1];
  const float* eb1  = (const float*)d_in[2];
  const float* ew2  = (const float*)d_in[3];
  const float* eb2  = (const float*)d_in[4];
  const float* ew3  = (const float*)d_in[5];
  const float* eb3  = (const float*)d_in[6];
  const float* qw   = (const float*)d_in[7];
  const float* qb   = (const float*)d_in[8];
  const float* cb   = (const float*)d_in[9];
  const float* pw   = (const float*)d_in[10];
  const float* pb   = (const float*)d_in[11];
  const float* dw1  = (const float*)d_in[12];
  const float* db1  = (const float*)d_in[13];
  const float* dtw2 = (const float*)d_in[14];
  const float* dtb2 = (const float*)d_in[15];
  const float* dtw3 = (const float*)d_in[16];
  const float* dtb3 = (const float*)d_in[17];

  char* wsb = (char*)d_ws;
  float*    h1p  = (float*)(wsb + OFF_A);
  _Float16* Ap   = (_Float16*)(wsb + OFF_A);
  int4*     binfo= (int4*)(wsb + OFF_BINFO);
  float*    d2p  = (float*)(wsb + OFF_A);
  float*    h2p  = (float*)(wsb + OFF_B);
  float*    qbufp= (float*)(wsb + OFF_B);
  float*    xpad = (float*)(wsb + OFF_C);
  float*    h3   = (float*)(wsb + OFF_C);
  float*    d1p  = (float*)(wsb + OFF_C);
  float*    zff  = (float*)(wsb + OFF_D);
  _Float16* Bp   = (_Float16*)(wsb + OFF_E);
  float*    PC   = (float*)(wsb + OFF_E);
  float*    znb  = (float*)(wsb + OFF_ZN);
  float*    cnb  = (float*)(wsb + OFF_CN);
  int*      idxb = (int*)(wsb + OFF_IDX);
  float*    accum= (float*)(wsb + OFF_ACC);
  float*    wr2  = (float*)(wsb + OFF_WR2);
  float*    wr3  = (float*)(wsb + OFF_WR3);
  float*    qwT  = (float*)(wsb + OFF_QWT);
  double*   wd2  = (double*)(wsb + OFF_WD2);
  double*   wd3  = (double*)(wsb + OFF_WD3);

  float* out      = (float*)d_out;
  float* outLoss  = out + 786432;
  float* outIdxF  = out + 786433;

  // zero pads + weight prep (independent of encoder chain)
  hipMemsetAsync((void*)h1p,  0, 34611200, stream);
  hipMemsetAsync((void*)h2p,  0, 8921088,  stream);
  hipMemsetAsync((void*)xpad, 0, 3195072,  stream);
  hipLaunchKernelGGL(wresh2_k, dim3(256),  dim3(256), 0, stream, dtw2, wr2);
  hipLaunchKernelGGL(wresh3_k, dim3(6),    dim3(256), 0, stream, dtw3, wr3);
  hipLaunchKernelGGL(qwT_k,    dim3(128),  dim3(256), 0, stream, qw, qwT);
  hipLaunchKernelGGL(widen_k,  dim3(1024), dim3(256), 0, stream, ew2, wd2, 262144);
  hipLaunchKernelGGL(widen_k,  dim3(576),  dim3(256), 0, stream, ew3, wd3, 147456);

  // encoder: per-op fp32-rounded (f64-exact inside each op), cvt-free
  hipLaunchKernelGGL(padx_k,       dim3(3072),  dim3(256), 0, stream, x, xpad);
  hipLaunchKernelGGL(conv1_k,      dim3(8192),  dim3(256), 0, stream, xpad, ew1, eb1, h1p);
  hipLaunchKernelGGL(conv2_k,      dim3(1024),  dim3(256), 0, stream, h1p, wd2, eb2, h2p);
  hipLaunchKernelGGL(conv3_k,      dim3(1024),  dim3(256), 0, stream, h2p, wd3, eb3, h3);
  hipLaunchKernelGGL(qconv_z_pr_k, dim3(16384), dim3(256), 0, stream, h3, qwT, qb, zff);

  // VQ: fp16 K=256 MFMA filter + binfo-pruned exact rescore
  hipLaunchKernelGGL(rownorm_k,        dim3(4096),  dim3(256), 0, stream, zff, znb);
  hipLaunchKernelGGL(rownorm_k,        dim3(2048),  dim3(256), 0, stream, cb, cnb);
  hipLaunchKernelGGL((build_f16_k<0>), dim3(16384), dim3(256), 0, stream, zff, Ap);
  hipLaunchKernelGGL((build_f16_k<1>), dim3(8192),  dim3(256), 0, stream, cb, Bp);
  hipLaunchKernelGGL(vq_gemm_k,   dim3(8192),  dim3(256), 0, stream, Ap, Bp, cnb, binfo);
  hipLaunchKernelGGL(vq_phase3_k, dim3(4096),  dim3(256), 0, stream, zff, cb, znb, cnb, binfo, idxb);
  hipLaunchKernelGGL(init_k,      dim3(1),     dim3(1),   0, stream, accum);
  hipLaunchKernelGGL(commit_k,    dim3(16384), dim3(256), 0, stream, zff, cb, idxb, accum, outIdxF);
  hipLaunchKernelGGL(fin_k,       dim3(1),     dim3(1),   0, stream, accum, outLoss);

  // decoder fp32 (pqconv folded through codebook: q = PC[idx] + b)
  hipLaunchKernelGGL(pc_k, dim3(4096), dim3(256), 0, stream, cb, pw, PC);
  hipMemsetAsync((void*)qbufp, 0, 8921088,  stream);
  hipMemsetAsync((void*)d1p,   0, 8921088,  stream);
  hipMemsetAsync((void*)d2p,   0, 34611200, stream);
  hipLaunchKernelGGL(gather_pc_k, dim3(8192),  dim3(256), 0, stream, PC, idxb, pb, qbufp);
  hipLaunchKernelGGL(dconv1_k,    dim3(2048),  dim3(256), 0, stream, qbufp, dw1, db1, d1p);
  hipLaunchKernelGGL(convt2_k,    dim3(8192),  dim3(256), 0, stream, d1p, wr2, dtb2, d2p);
  hipLaunchKernelGGL(convt3_k,    dim3(1024),  dim3(256), 0, stream, d2p, wr3, dtb3, out);
}

// Round 10
// 1556.353 us; speedup vs baseline: 5.1465x; 1.0456x over previous
//
#include <hip/hip_runtime.h>

// ---------------------------------------------------------------------------
// VQ-VAE forward, round 10: co x4 f64-weight convs (32 waves/CU), fused
// prep/pad/epilogue kernels (16 dispatches total). Numerics contract
// (validated r3-r9): every reference op = fl32(f64-exact op on fp32
// operands); d in fp32; first-index argmin; f64 assoc freedom OK.
//
// d_out (float32): recon[786432] | commit_loss[1] | indices[16384]
//
// Workspace (BYTE offsets), ~86.6 MB peak:
#define OFF_A     ((size_t)0)          // h1p / Ap / d2p
#define OFF_BINFO ((size_t)8388608)
#define OFF_B     ((size_t)34611200)   // h2p / qbufp
#define OFF_C     ((size_t)43532288)   // xpad / h3 / d1p
#define OFF_D     ((size_t)52453376)   // zf
#define OFF_E     ((size_t)69230592)   // Bp / PC
#define OFF_ZN    ((size_t)81813504)
#define OFF_CN    ((size_t)81879040)
#define OFF_IDX   ((size_t)81911808)
#define OFF_ACC   ((size_t)81977344)
#define OFF_WR2   ((size_t)81977600)
#define OFF_WR3   ((size_t)83026176)
#define OFF_QWT   ((size_t)83050752)
#define OFF_WD2   ((size_t)83181824)   // f64 conv2 weights, 2 MB
#define OFF_WD3   ((size_t)85278976)   // f64 conv3 weights, 1.18 MB
#define OFF_WD1   ((size_t)86458624)   // f64 conv1 weights, 48 KB

#define VQ_MARGIN 1.2e-4f
#define LDSS 40

typedef __attribute__((ext_vector_type(8))) _Float16 f16x8;
typedef __attribute__((ext_vector_type(4))) float f32x4;

// ---------- helpers ----------
__device__ __forceinline__ unsigned fkey(float f) {
  unsigned u = __float_as_uint(f);
  return (u & 0x80000000u) ? ~u : (u | 0x80000000u);
}
__device__ __forceinline__ float funkey(unsigned k) {
  unsigned u = (k & 0x80000000u) ? (k ^ 0x80000000u) : ~k;
  return __uint_as_float(u);
}
__device__ __forceinline__ void padzero_img(float* base, int S, int t) {
  // zero the border of an SxS image: 4S-4 elements
  for (int e = t; e < 4 * S - 4; e += 256) {
    int rr, cc;
    if (e < S) { rr = 0; cc = e; }
    else if (e < 2 * S) { rr = S - 1; cc = e - S; }
    else { rr = ((e - 2 * S) >> 1) + 1; cc = (e & 1) ? (S - 1) : 0; }
    base[rr * S + cc] = 0.0f;
  }
}

// ---------- ONE prep kernel: weight reshapes/widens + encoder pad zeros ----------
__global__ __launch_bounds__(256) void prep_k(
    const float* __restrict__ dtw2, float* __restrict__ wr2,
    const float* __restrict__ dtw3, float* __restrict__ wr3,
    const float* __restrict__ qw,   float* __restrict__ qwT,
    const float* __restrict__ ew2,  double* __restrict__ wd2,
    const float* __restrict__ ew3,  double* __restrict__ wd3,
    const float* __restrict__ ew1,  double* __restrict__ wd1,
    float* __restrict__ xpad, float* __restrict__ h1p, float* __restrict__ h2p) {
  int b = blockIdx.x, t = threadIdx.x;
  if (b < 256) {                       // wresh2: [ci][co][16] -> [cls][co][ci][4]
    int tid = b * 256 + t;
    int ci = tid & 127, co = (tid >> 7) & 127, cls = tid >> 14;
    int kh0 = 1 - (cls >> 1), kw0 = 1 - (cls & 1);
    const float* s = dtw2 + ((size_t)ci * 128 + co) * 16;
    float* d = wr2 + (size_t)tid * 4;
    d[0] = s[kh0 * 4 + kw0];       d[1] = s[kh0 * 4 + kw0 + 2];
    d[2] = s[(kh0 + 2) * 4 + kw0]; d[3] = s[(kh0 + 2) * 4 + kw0 + 2];
  } else if (b < 262) {                // wresh3
    int tid = (b - 256) * 256 + t;
    if (tid < 1536) {
      int ci = tid & 127, co = (tid >> 7) % 3, cls = tid / 384;
      int kh0 = 1 - (cls >> 1), kw0 = 1 - (cls & 1);
      const float* s = dtw3 + ((size_t)ci * 3 + co) * 16;
      float* d = wr3 + (size_t)tid * 4;
      d[0] = s[kh0 * 4 + kw0];       d[1] = s[kh0 * 4 + kw0 + 2];
      d[2] = s[(kh0 + 2) * 4 + kw0]; d[3] = s[(kh0 + 2) * 4 + kw0 + 2];
    }
  } else if (b < 390) {                // qwT
    int tid = (b - 262) * 256 + t;
    int co = tid & 255, ci = tid >> 8;
    qwT[(size_t)ci * 256 + co] = qw[(size_t)co * 128 + ci];
  } else if (b < 1414) {               // widen ew2
    int tid = (b - 390) * 256 + t;
    wd2[tid] = (double)ew2[tid];
  } else if (b < 1990) {               // widen ew3
    int tid = (b - 1414) * 256 + t;
    wd3[tid] = (double)ew3[tid];
  } else if (b < 2014) {               // widen ew1
    int tid = (b - 1990) * 256 + t;
    wd1[tid] = (double)ew1[tid];
  } else if (b < 2026) {               // pad-zero xpad (12 imgs of 258)
    padzero_img(xpad + (size_t)(b - 2014) * 66564, 258, t);
  } else if (b < 2538) {               // pad-zero h1p (512 imgs of 130)
    padzero_img(h1p + (size_t)(b - 2026) * 16900, 130, t);
  } else {                             // pad-zero h2p (512 imgs of 66)
    padzero_img(h2p + (size_t)(b - 2538) * 4356, 66, t);
  }
}

// ---------- pad-copy x into [4][3][258][258] ----------
__global__ __launch_bounds__(256) void padx_k(const float* __restrict__ x,
                                              float* __restrict__ xp) {
  int tid = blockIdx.x * 256 + threadIdx.x;
  int wo = tid & 255, ho = (tid >> 8) & 255, c = tid >> 16;
  xp[((size_t)c * 258 + ho + 1) * 258 + wo + 1] = x[tid];
}

// ---------- enc conv1: k=4 s=2 + ReLU, 3ci, co x4, f64 weights ----------
__global__ __launch_bounds__(256) void conv1_k(
    const float* __restrict__ xp, const double* __restrict__ wd,
    const float* __restrict__ bias, float* __restrict__ h1p) {
  int b = blockIdx.x;
  int chunk = b & 63, cog = (b >> 6) & 31, n = b >> 11;
  int t = threadIdx.x;
  int wo = t & 127, ho = chunk * 2 + (t >> 7);
  int co0 = cog * 4;
  const float* xb = xp + (size_t)n * 3 * 66564 + (size_t)(2 * ho) * 258 + 2 * wo;
  double acc[4] = {0.0, 0.0, 0.0, 0.0};
  for (int ci = 0; ci < 3; ++ci) {
    const float* xc = xb + (size_t)ci * 66564;
    double xd[16];
#pragma unroll
    for (int kh = 0; kh < 4; ++kh)
#pragma unroll
      for (int kw = 0; kw < 4; ++kw) xd[kh * 4 + kw] = (double)xc[kh * 258 + kw];
#pragma unroll
    for (int cc = 0; cc < 4; ++cc) {
      const double* wp = wd + (size_t)(co0 + cc) * 48 + ci * 16;
#pragma unroll
      for (int tp = 0; tp < 16; ++tp)
        acc[cc] = fma(xd[tp], wp[tp], acc[cc]);
    }
  }
#pragma unroll
  for (int cc = 0; cc < 4; ++cc) {
    float r = (float)((double)bias[co0 + cc] + acc[cc]);
    h1p[(((size_t)n * 128 + co0 + cc) * 130 + ho + 1) * 130 + wo + 1] = fmaxf(r, 0.0f);
  }
}

// ---------- enc conv2: k=4 s=2 + ReLU, 128ci, co x4, f64 weights ----------
__global__ __launch_bounds__(256) void conv2_k(
    const float* __restrict__ h1p, const double* __restrict__ wd,
    const float* __restrict__ bias, float* __restrict__ h2p) {
  int b = blockIdx.x;
  int chunk = b & 15, cog = (b >> 4) & 31, n = b >> 9;
  int t = threadIdx.x;
  int wo = t & 63, ho = chunk * 4 + (t >> 6);
  int co0 = cog * 4;
  const float* xb = h1p + (size_t)n * 128 * 16900 + (size_t)(2 * ho) * 130 + 2 * wo;
  double acc[4] = {0.0, 0.0, 0.0, 0.0};
  for (int ci = 0; ci < 128; ++ci) {
    const float* xc = xb + (size_t)ci * 16900;
    double xd[16];
#pragma unroll
    for (int kh = 0; kh < 4; ++kh)
#pragma unroll
      for (int kw = 0; kw < 4; ++kw) xd[kh * 4 + kw] = (double)xc[kh * 130 + kw];
#pragma unroll
    for (int cc = 0; cc < 4; ++cc) {
      const double* wp = wd + (size_t)(co0 + cc) * 2048 + ci * 16;
#pragma unroll
      for (int tp = 0; tp < 16; ++tp)
        acc[cc] = fma(xd[tp], wp[tp], acc[cc]);
    }
  }
#pragma unroll
  for (int cc = 0; cc < 4; ++cc) {
    float r = (float)((double)bias[co0 + cc] + acc[cc]);
    h2p[(((size_t)n * 128 + co0 + cc) * 66 + ho + 1) * 66 + wo + 1] = fmaxf(r, 0.0f);
  }
}

// ---------- enc conv3: k=3 s=1 (no relu), co x4, f64 weights ----------
__global__ __launch_bounds__(256) void conv3_k(
    const float* __restrict__ h2p, const double* __restrict__ wd,
    const float* __restrict__ bias, float* __restrict__ h3) {
  int b = blockIdx.x;
  int chunk = b & 15, cog = (b >> 4) & 31, n = b >> 9;
  int t = threadIdx.x;
  int wo = t & 63, ho = chunk * 4 + (t >> 6);
  int co0 = cog * 4;
  const float* xb = h2p + (size_t)n * 128 * 4356 + (size_t)ho * 66 + wo;
  double acc[4] = {0.0, 0.0, 0.0, 0.0};
  for (int ci = 0; ci < 128; ++ci) {
    const float* xc = xb + (size_t)ci * 4356;
    double xd[9];
#pragma unroll
    for (int kh = 0; kh < 3; ++kh)
#pragma unroll
      for (int kw = 0; kw < 3; ++kw) xd[kh * 3 + kw] = (double)xc[kh * 66 + kw];
#pragma unroll
    for (int cc = 0; cc < 4; ++cc) {
      const double* wp = wd + (size_t)(co0 + cc) * 1152 + ci * 9;
#pragma unroll
      for (int tp = 0; tp < 9; ++tp)
        acc[cc] = fma(xd[tp], wp[tp], acc[cc]);
    }
  }
#pragma unroll
  for (int cc = 0; cc < 4; ++cc)
    h3[(((size_t)n * 128 + co0 + cc) << 12) + (ho << 6) + wo] =
        (float)((double)bias[co0 + cc] + acc[cc]);
}

// ---------- 1x1 conv 128->256 fused: zf + Ap(f16) + znorm ----------
__global__ __launch_bounds__(256) void qconv_z_k(
    const float* __restrict__ h3, const float* __restrict__ wT,
    const float* __restrict__ bias, float* __restrict__ zf,
    _Float16* __restrict__ Ap, float* __restrict__ znb) {
  __shared__ double wsum[4];
  int p  = blockIdx.x;
  int co = threadIdx.x;
  int n  = p >> 12;
  int hw = p & 4095;
  const float* xp = h3 + ((size_t)n * 128) * 4096 + hw;
  double a[4] = {0.0, 0.0, 0.0, 0.0};
  for (int ci = 0; ci < 128; ci += 4) {
#pragma unroll
    for (int u = 0; u < 4; ++u) {
      float xv = xp[(size_t)(ci + u) * 4096];
      a[u] = fma((double)xv, (double)wT[(size_t)(ci + u) * 256 + co], a[u]);
    }
  }
  double acc = (double)bias[co] + ((a[0] + a[1]) + (a[2] + a[3]));
  float zv = (float)acc;
  zf[(size_t)p * 256 + co] = zv;
  Ap[(size_t)p * 256 + co] = (_Float16)zv;
  float xx = zv * zv;          // elementwise square op: fp32-rounded
  double s = (double)xx;       // sum op: f64-exact, rounded once
#pragma unroll
  for (int off = 32; off > 0; off >>= 1) s += __shfl_down(s, off, 64);
  if ((co & 63) == 0) wsum[co >> 6] = s;
  __syncthreads();
  if (co == 0) znb[p] = (float)((wsum[0] + wsum[1]) + (wsum[2] + wsum[3]));
}

// ---------- codebook prep fused: Bp(f16 x512) + cnorm ----------
__global__ __launch_bounds__(256) void cbprep_k(
    const float* __restrict__ cb, _Float16* __restrict__ Bp,
    float* __restrict__ cnb) {
  __shared__ double wsum[4];
  int k = blockIdx.x, t = threadIdx.x;
  float c = cb[(size_t)k * 256 + t];
  Bp[(size_t)k * 256 + t] = (_Float16)(c * 512.0f);
  float xx = c * c;
  double s = (double)xx;
#pragma unroll
  for (int off = 32; off > 0; off >>= 1) s += __shfl_down(s, off, 64);
  if ((t & 63) == 0) wsum[t >> 6] = s;
  __syncthreads();
  if (t == 0) cnb[k] = (float)((wsum[0] + wsum[1]) + (wsum[2] + wsum[3]));
}

// ---------- VQ filter GEMM: 128x128 tile, 16x16x32 f16 MFMA, K=256 ----------
__global__ __launch_bounds__(256, 2) void vq_gemm_k(
    const _Float16* __restrict__ Ah, const _Float16* __restrict__ Bh,
    const float* __restrict__ cnArr, int4* __restrict__ binfo) {
  __shared__ __align__(16) _Float16 As[128 * LDSS];
  __shared__ __align__(16) _Float16 Bs[128 * LDSS];
  __shared__ unsigned loc[128];
  __shared__ int cnt_sh[128];
  __shared__ int cand_sh[128][2];
  const int t = threadIdx.x;
  const int w = t >> 6, L = t & 63;
  const int mb = blockIdx.x >> 6;
  const int nb = blockIdx.x & 63;
  const int m0 = mb << 7, n0 = nb << 7;
  if (t < 128) { loc[t] = 0xFFFFFFFFu; cnt_sh[t] = 0; }
  f32x4 acc[4][4] = {};
  const int wr = (w >> 1) << 6, wc = (w & 1) << 6;
  const int srow = L >> 2, kg = L & 3;
  const int q = L >> 4, ln = L & 15;
  for (int kk = 0; kk < 256; kk += 32) {
    __syncthreads();
#pragma unroll
    for (int c = 0; c < 2; ++c) {
      const int row = (w << 5) + (c << 4) + srow;
      const f16x8 av = *(const f16x8*)(Ah + (size_t)(m0 + row) * 256 + kk + kg * 8);
      *(f16x8*)(&As[row * LDSS + kg * 8]) = av;
      const f16x8 bv = *(const f16x8*)(Bh + (size_t)(n0 + row) * 256 + kk + kg * 8);
      *(f16x8*)(&Bs[row * LDSS + kg * 8]) = bv;
    }
    __syncthreads();
    f16x8 af[4], bf[4];
#pragma unroll
    for (int i = 0; i < 4; ++i)
      af[i] = *(const f16x8*)(&As[(wr + 16 * i + ln) * LDSS + q * 8]);
#pragma unroll
    for (int j = 0; j < 4; ++j)
      bf[j] = *(const f16x8*)(&Bs[(wc + 16 * j + ln) * LDSS + q * 8]);
#pragma unroll
    for (int i = 0; i < 4; ++i)
#pragma unroll
      for (int j = 0; j < 4; ++j)
        acc[i][j] = __builtin_amdgcn_mfma_f32_16x16x32_f16(af[i], bf[j], acc[i][j], 0, 0, 0);
  }
  float cnv[4];
#pragma unroll
  for (int j = 0; j < 4; ++j) cnv[j] = cnArr[n0 + wc + 16 * j + ln];
#pragma unroll
  for (int i = 0; i < 4; ++i)
#pragma unroll
    for (int r = 0; r < 4; ++r) {
      float mn = 3.4e38f;
#pragma unroll
      for (int j = 0; j < 4; ++j)
        mn = fminf(mn, fmaf(-0.00390625f, acc[i][j][r], cnv[j]));
      atomicMin(&loc[wr + 16 * i + 4 * q + r], fkey(mn));
    }
  __syncthreads();
#pragma unroll
  for (int i = 0; i < 4; ++i)
#pragma unroll
    for (int r = 0; r < 4; ++r) {
      const int rib = wr + 16 * i + 4 * q + r;
      const float thr = funkey(loc[rib]) + VQ_MARGIN;
#pragma unroll
      for (int j = 0; j < 4; ++j) {
        float s = fmaf(-0.00390625f, acc[i][j][r], cnv[j]);
        if (s <= thr) {
          int slot = atomicAdd(&cnt_sh[rib], 1);
          if (slot < 2) cand_sh[rib][slot] = n0 + wc + 16 * j + ln;
        }
      }
    }
  __syncthreads();
  if (t < 128) {
    int4 v;
    v.x = cnt_sh[t];
    v.y = cand_sh[t][0];
    v.z = cand_sh[t][1];
    v.w = (int)__float_as_uint(funkey(loc[t]));
    binfo[(size_t)(m0 + t) * 64 + nb] = v;
  }
}

// ---------- VQ final: binfo-pruned argmin (also zeroes accum for commit) ----------
__global__ __launch_bounds__(256) void vq_phase3_k(
    const float* __restrict__ zf, const float* __restrict__ cb,
    const float* __restrict__ znArr, const float* __restrict__ cnArr,
    const int4* __restrict__ binfo, int* __restrict__ idxOut,
    float* __restrict__ accum) {
  if (blockIdx.x == 0 && threadIdx.x == 0) *accum = 0.0f;
  const int lane = threadIdx.x & 63;
  const int r = blockIdx.x * 4 + (threadIdx.x >> 6);
  const float* zr = zf + (size_t)r * 256;
  double z4[4];
#pragma unroll
  for (int j = 0; j < 4; ++j) z4[j] = (double)zr[lane + (j << 6)];
  const float znr = znArr[r];
  int4 b = binfo[(size_t)r * 64 + lane];
  float bv = __uint_as_float((unsigned)b.w);
  float m = bv;
#pragma unroll
  for (int off = 32; off > 0; off >>= 1) m = fminf(m, __shfl_down(m, off, 64));
  m = __shfl(m, 0, 64);
  const float thr = m + VQ_MARGIN;
  unsigned long long mask = __ballot(bv <= thr);
  float bestd = 3.4e38f;
  int bestk = 0x7fffffff;
  while (mask) {
    const int nb = (int)__builtin_ctzll(mask);
    mask &= mask - 1;
    const int c  = __shfl(b.x, nb, 64);
    const int k0 = __shfl(b.y, nb, 64);
    const int k1 = __shfl(b.z, nb, 64);
    const int nsc = (c <= 2) ? c : 128;
    for (int s2 = 0; s2 < nsc; ++s2) {
      const int k = (c <= 2) ? (s2 == 0 ? k0 : k1) : (nb * 128 + s2);
      const float* ck = cb + (size_t)k * 256;
      double p = 0.0;
#pragma unroll
      for (int j = 0; j < 4; ++j)
        p = fma(z4[j], (double)ck[lane + (j << 6)], p);
#pragma unroll
      for (int off = 32; off > 0; off >>= 1) p += __shfl_down(p, off, 64);
      if (lane == 0) {
        float mm2 = (float)(2.0 * p);
        float t1 = znr + cnArr[k];
        float d = t1 - mm2;
        if (d < bestd || (d == bestd && k < bestk)) { bestd = d; bestk = k; }
      }
    }
  }
  if (lane == 0) idxOut[r] = bestk;
}

// ---------- commit loss partials + indices-as-float output ----------
__global__ __launch_bounds__(256) void commit_k(
    const float* __restrict__ zf, const float* __restrict__ cb,
    const int* __restrict__ idxArr, float* __restrict__ accum,
    float* __restrict__ outIdxF) {
  __shared__ float wsum[4];
  const int p = blockIdx.x;
  const int t = threadIdx.x;
  const int k = idxArr[p];
  float d = cb[(size_t)k * 256 + t] - zf[(size_t)p * 256 + t];
  float v = d * d;
#pragma unroll
  for (int off = 32; off > 0; off >>= 1) v += __shfl_down(v, off, 64);
  if ((t & 63) == 0) wsum[t >> 6] = v;
  __syncthreads();
  if (t == 0) {
    atomicAdd(accum, wsum[0] + wsum[1] + wsum[2] + wsum[3]);
    outIdxF[p] = (float)k;
  }
}

// ---------- projected codebook PC[k][co] = sum_ci cb[k][ci]*pw[co][ci] ----------
__global__ __launch_bounds__(256) void pc_k(const float* __restrict__ cb,
                                            const float* __restrict__ pw,
                                            float* __restrict__ PC) {
  int tid = blockIdx.x * 256 + threadIdx.x;
  int co = tid & 127, k = tid >> 7;
  const float* c = cb + (size_t)k * 256;
  const float* w = pw + (size_t)co * 256;
  float a0 = 0.0f, a1 = 0.0f, a2 = 0.0f, a3 = 0.0f;
  for (int ci = 0; ci < 256; ci += 4) {
    a0 = fmaf(c[ci], w[ci], a0);
    a1 = fmaf(c[ci + 1], w[ci + 1], a1);
    a2 = fmaf(c[ci + 2], w[ci + 2], a2);
    a3 = fmaf(c[ci + 3], w[ci + 3], a3);
  }
  PC[tid] = (a0 + a1) + (a2 + a3);
}

// ---------- decoder pad zeros (qbufp, d1p: 66; d2p: 130) ----------
__global__ __launch_bounds__(256) void padzero_dec_k(
    float* __restrict__ qbufp, float* __restrict__ d1p, float* __restrict__ d2p) {
  int b = blockIdx.x, t = threadIdx.x;
  if (b < 512)       padzero_img(qbufp + (size_t)b * 4356, 66, t);
  else if (b < 1024) padzero_img(d1p + (size_t)(b - 512) * 4356, 66, t);
  else               padzero_img(d2p + (size_t)(b - 1024) * 16900, 130, t);
}

// ---------- q = gather(PC, idx) + bias, padded NCHW [66][66] ----------
__global__ __launch_bounds__(256) void gather_pc_k(
    const float* __restrict__ PC, const int* __restrict__ idxArr,
    const float* __restrict__ pb, float* __restrict__ qp) {
  int tid = blockIdx.x * 256 + threadIdx.x;
  int hw = tid & 4095;
  int co = (tid >> 12) & 127;
  int n  = tid >> 19;
  int p  = (n << 12) + hw;
  int h = hw >> 6, w2 = hw & 63;
  qp[(((size_t)n * 128 + co) * 66 + h + 1) * 66 + w2 + 1] =
      PC[(size_t)idxArr[p] * 128 + co] + pb[co];
}

// ---------- dec conv1: fp32 k=3 s=1 + relu, co x4 ----------
__global__ __launch_bounds__(256) void dconv1_k(
    const float* __restrict__ qp, const float* __restrict__ w,
    const float* __restrict__ bias, float* __restrict__ d1p) {
  int b = blockIdx.x;
  int chunk = b & 15, cog = (b >> 4) & 31, n = b >> 9;
  int t = threadIdx.x;
  int wo = t & 63, ho = chunk * 4 + (t >> 6);
  int co0 = cog * 4;
  const float* xb = qp + (size_t)n * 128 * 4356 + (size_t)ho * 66 + wo;
  float acc[4] = {0.0f, 0.0f, 0.0f, 0.0f};
  for (int ci = 0; ci < 128; ++ci) {
    const float* xc = xb + (size_t)ci * 4356;
    float xv[9];
#pragma unroll
    for (int kh = 0; kh < 3; ++kh)
#pragma unroll
      for (int kw = 0; kw < 3; ++kw) xv[kh * 3 + kw] = xc[kh * 66 + kw];
#pragma unroll
    for (int cc = 0; cc < 4; ++cc) {
      const float* wp = w + (size_t)(co0 + cc) * 1152 + ci * 9;
#pragma unroll
      for (int tp = 0; tp < 9; ++tp)
        acc[cc] = fmaf(xv[tp], wp[tp], acc[cc]);
    }
  }
#pragma unroll
  for (int cc = 0; cc < 4; ++cc)
    d1p[(((size_t)n * 128 + co0 + cc) * 66 + ho + 1) * 66 + wo + 1] =
        fmaxf(bias[co0 + cc] + acc[cc], 0.0f);
}

// ---------- convt2: parity-specialized, co x4, in d1p[66], out d2p[130] ----------
__global__ __launch_bounds__(256) void convt2_k(
    const float* __restrict__ xp, const float* __restrict__ wr,
    const float* __restrict__ bias, float* __restrict__ y) {
  int b = blockIdx.x;
  int chunk = b & 15, cls = (b >> 4) & 3, cog = (b >> 6) & 31, n = b >> 11;
  int cph = cls >> 1, cpw = cls & 1;
  int t = threadIdx.x;
  int wb = t & 63, i = chunk * 4 + (t >> 6);
  int co0 = cog * 4;
  int ho = 2 * i + cph, wo = 2 * wb + cpw;
  int r0 = i + 1 + cph, r1 = r0 - 1;
  int c0 = wb + 1 + cpw, c1 = c0 - 1;
  const float* xb = xp + (size_t)n * 128 * 4356;
  float acc[4] = {0.0f, 0.0f, 0.0f, 0.0f};
  for (int ci = 0; ci < 128; ++ci) {
    const float* xc = xb + (size_t)ci * 4356;
    float x00 = xc[r0 * 66 + c0], x01 = xc[r0 * 66 + c1];
    float x10 = xc[r1 * 66 + c0], x11 = xc[r1 * 66 + c1];
#pragma unroll
    for (int cc = 0; cc < 4; ++cc) {
      const float* w4 = wr + (((size_t)cls * 128 + co0 + cc) * 128 + ci) * 4;
      acc[cc] = fmaf(x00, w4[0], acc[cc]);
      acc[cc] = fmaf(x01, w4[1], acc[cc]);
      acc[cc] = fmaf(x10, w4[2], acc[cc]);
      acc[cc] = fmaf(x11, w4[3], acc[cc]);
    }
  }
#pragma unroll
  for (int cc = 0; cc < 4; ++cc)
    y[(((size_t)n * 128 + co0 + cc) * 130 + ho + 1) * 130 + wo + 1] =
        fmaxf(bias[co0 + cc] + acc[cc], 0.0f);
}

// ---------- convt3: parity-specialized, 3 co/thread (+ commit-loss finalize) ----------
__global__ __launch_bounds__(256) void convt3_k(
    const float* __restrict__ xp, const float* __restrict__ wr,
    const float* __restrict__ bias, float* __restrict__ y,
    const float* __restrict__ accum, float* __restrict__ outLoss) {
  int b = blockIdx.x;
  if (b == 0 && threadIdx.x == 0) *outLoss = *accum * (1.0f / 4194304.0f);
  int chunk = b & 63, cls = (b >> 6) & 3, n = b >> 8;
  int cph = cls >> 1, cpw = cls & 1;
  int t = threadIdx.x;
  int wb = t & 127, i = chunk * 2 + (t >> 7);
  int ho = 2 * i + cph, wo = 2 * wb + cpw;
  int r0 = i + 1 + cph, r1 = r0 - 1;
  int c0 = wb + 1 + cpw, c1 = c0 - 1;
  const float* xb = xp + (size_t)n * 128 * 16900;
  float acc[3] = {0.0f, 0.0f, 0.0f};
  for (int ci = 0; ci < 128; ++ci) {
    const float* xc = xb + (size_t)ci * 16900;
    float x00 = xc[r0 * 130 + c0], x01 = xc[r0 * 130 + c1];
    float x10 = xc[r1 * 130 + c0], x11 = xc[r1 * 130 + c1];
#pragma unroll
    for (int cc = 0; cc < 3; ++cc) {
      const float* w4 = wr + (((size_t)cls * 3 + cc) * 128 + ci) * 4;
      acc[cc] = fmaf(x00, w4[0], acc[cc]);
      acc[cc] = fmaf(x01, w4[1], acc[cc]);
      acc[cc] = fmaf(x10, w4[2], acc[cc]);
      acc[cc] = fmaf(x11, w4[3], acc[cc]);
    }
  }
#pragma unroll
  for (int cc = 0; cc < 3; ++cc)
    y[(((size_t)n * 3 + cc) << 16) + (ho << 8) + wo] = bias[cc] + acc[cc];
}

// ---------------------------------------------------------------------------
extern "C" void kernel_launch(void* const* d_in, const int* in_sizes, int n_in,
                              void* d_out, int out_size, void* d_ws, size_t ws_size,
                              hipStream_t stream) {
  const float* x    = (const float*)d_in[0];
  const float* ew1  = (const float*)d_in[1];
  const float* eb1  = (const float*)d_in[2];
  const float* ew2  = (const float*)d_in[3];
  const float* eb2  = (const float*)d_in[4];
  const float* ew3  = (const float*)d_in[5];
  const float* eb3  = (const float*)d_in[6];
  const float* qw   = (const float*)d_in[7];
  const float* qb   = (const float*)d_in[8];
  const float* cb   = (const float*)d_in[9];
  const float* pw   = (const float*)d_in[10];
  const float* pb   = (const float*)d_in[11];
  const float* dw1  = (const float*)d_in[12];
  const float* db1  = (const float*)d_in[13];
  const float* dtw2 = (const float*)d_in[14];
  const float* dtb2 = (const float*)d_in[15];
  const float* dtw3 = (const float*)d_in[16];
  const float* dtb3 = (const float*)d_in[17];

  char* wsb = (char*)d_ws;
  float*    h1p  = (float*)(wsb + OFF_A);
  _Float16* Ap   = (_Float16*)(wsb + OFF_A);
  int4*     binfo= (int4*)(wsb + OFF_BINFO);
  float*    d2p  = (float*)(wsb + OFF_A);
  float*    h2p  = (float*)(wsb + OFF_B);
  float*    qbufp= (float*)(wsb + OFF_B);
  float*    xpad = (float*)(wsb + OFF_C);
  float*    h3   = (float*)(wsb + OFF_C);
  float*    d1p  = (float*)(wsb + OFF_C);
  float*    zff  = (float*)(wsb + OFF_D);
  _Float16* Bp   = (_Float16*)(wsb + OFF_E);
  float*    PC   = (float*)(wsb + OFF_E);
  float*    znb  = (float*)(wsb + OFF_ZN);
  float*    cnb  = (float*)(wsb + OFF_CN);
  int*      idxb = (int*)(wsb + OFF_IDX);
  float*    accum= (float*)(wsb + OFF_ACC);
  float*    wr2  = (float*)(wsb + OFF_WR2);
  float*    wr3  = (float*)(wsb + OFF_WR3);
  float*    qwT  = (float*)(wsb + OFF_QWT);
  double*   wd2  = (double*)(wsb + OFF_WD2);
  double*   wd3  = (double*)(wsb + OFF_WD3);
  double*   wd1  = (double*)(wsb + OFF_WD1);

  float* out      = (float*)d_out;
  float* outLoss  = out + 786432;
  float* outIdxF  = out + 786433;

  // all prep (weight reshape/widen + encoder pad zeros) in one kernel
  hipLaunchKernelGGL(prep_k, dim3(3050), dim3(256), 0, stream,
                     dtw2, wr2, dtw3, wr3, qw, qwT, ew2, wd2, ew3, wd3,
                     ew1, wd1, xpad, h1p, h2p);

  // encoder: per-op fp32-rounded (f64-exact inside each op)
  hipLaunchKernelGGL(padx_k,    dim3(3072),  dim3(256), 0, stream, x, xpad);
  hipLaunchKernelGGL(conv1_k,   dim3(8192),  dim3(256), 0, stream, xpad, wd1, eb1, h1p);
  hipLaunchKernelGGL(conv2_k,   dim3(2048),  dim3(256), 0, stream, h1p, wd2, eb2, h2p);
  hipLaunchKernelGGL(conv3_k,   dim3(2048),  dim3(256), 0, stream, h2p, wd3, eb3, h3);
  hipLaunchKernelGGL(qconv_z_k, dim3(16384), dim3(256), 0, stream, h3, qwT, qb, zff, Ap, znb);

  // VQ: fp16 K=256 MFMA filter + binfo-pruned exact rescore
  hipLaunchKernelGGL(cbprep_k,    dim3(8192),  dim3(256), 0, stream, cb, Bp, cnb);
  hipLaunchKernelGGL(vq_gemm_k,   dim3(8192),  dim3(256), 0, stream, Ap, Bp, cnb, binfo);
  hipLaunchKernelGGL(vq_phase3_k, dim3(4096),  dim3(256), 0, stream, zff, cb, znb, cnb, binfo, idxb, accum);
  hipLaunchKernelGGL(commit_k,    dim3(16384), dim3(256), 0, stream, zff, cb, idxb, accum, outIdxF);

  // decoder fp32 (pqconv folded through codebook: q = PC[idx] + b)
  hipLaunchKernelGGL(pc_k,          dim3(4096), dim3(256), 0, stream, cb, pw, PC);
  hipLaunchKernelGGL(padzero_dec_k, dim3(1536), dim3(256), 0, stream, qbufp, d1p, d2p);
  hipLaunchKernelGGL(gather_pc_k,   dim3(8192), dim3(256), 0, stream, PC, idxb, pb, qbufp);
  hipLaunchKernelGGL(dconv1_k,      dim3(2048), dim3(256), 0, stream, qbufp, dw1, db1, d1p);
  hipLaunchKernelGGL(convt2_k,      dim3(8192), dim3(256), 0, stream, d1p, wr2, dtb2, d2p);
  hipLaunchKernelGGL(convt3_k,      dim3(1024), dim3(256), 0, stream, d2p, wr3, dtb3, out, accum, outLoss);
}